// Round 4
// baseline (874.314 us; speedup 1.0000x reference)
//
#include <hip/hip_runtime.h>
#include <cmath>

#define BB 8
#define NN 2048
#define CC 512
#define HH 8
#define DD 64
#define FF 1536
#define MM (BB*NN)   // 16384

typedef _Float16 half_t;
typedef __attribute__((ext_vector_type(8))) _Float16 half8;
typedef __attribute__((ext_vector_type(4))) _Float16 half4;
typedef __attribute__((ext_vector_type(4))) float floatx4;
typedef __attribute__((ext_vector_type(16))) float floatx16;
typedef __attribute__((ext_vector_type(4))) float fx4;

#define LOG2E 1.44269504088896f

// async global->LDS, 16 B per lane; LDS dest must be wave-uniform base (+lane*16)
typedef const __attribute__((address_space(1))) unsigned int* gas_ptr;
typedef __attribute__((address_space(3))) unsigned int* las_ptr;
__device__ __forceinline__ void gld16(const half_t* g, half_t* l) {
  __builtin_amdgcn_global_load_lds((gas_ptr)g, (las_ptr)l, 16, 0, 0);
}

// ---------------------------------------------------------------------------
// fp32 -> fp16 convert (8 elems/thread)
// ---------------------------------------------------------------------------
__global__ __launch_bounds__(256) void cvt_kernel(
    const float* __restrict__ s, half_t* __restrict__ d, int n8) {
  int i = blockIdx.x * 256 + threadIdx.x;
  if (i < n8) {
    float4 a = ((const float4*)s)[i * 2], b = ((const float4*)s)[i * 2 + 1];
    half8 h;
    h[0] = (half_t)a.x; h[1] = (half_t)a.y; h[2] = (half_t)a.z; h[3] = (half_t)a.w;
    h[4] = (half_t)b.x; h[5] = (half_t)b.y; h[6] = (half_t)b.z; h[7] = (half_t)b.w;
    ((half8*)d)[i] = h;
  }
}

// ---------------------------------------------------------------------------
// RoPE cos/sin table: tab[p][j] = (cos, sin)(p * 10000^(-2j/64)), p<2048, j<32
// ---------------------------------------------------------------------------
__global__ __launch_bounds__(256) void rope_tab_kernel(float2* __restrict__ tab) {
  int i = blockIdx.x * 256 + threadIdx.x;       // 65536 entries
  int p = i >> 5, j = i & 31;
  float ang = (float)p * __powf(10000.0f, -(float)(2 * j) * (1.0f / 64.0f));
  float sv, cv;
  __sincosf(ang, &sv, &cv);
  tab[i] = make_float2(cv, sv);
}

// ---------------------------------------------------------------------------
// Kernel 1: qkv = x @ W_qkv^T  (fp16 MFMA, 128x128 tile, BK=32, 4 waves)
// Fused epilogue: RoPE via precomputed table (+ q scale incl. log2e)
// -> Qh/Kh fp16 (B,H,N,D); V -> LDS transpose -> Vt fp16 (B,H,D,N).
// ---------------------------------------------------------------------------
__global__ __launch_bounds__(256) void qkv_mfma_kernel(
    const half_t* __restrict__ Ah,   // (16384, 512)
    const half_t* __restrict__ Bh,   // (1536, 512)
    const int*   __restrict__ ncp,
    const float2* __restrict__ tab,  // (2048, 32) cos/sin
    half_t* __restrict__ Qh, half_t* __restrict__ Kh, half_t* __restrict__ Vt)
{
  __shared__ union {
    struct { half_t A[128 * 32]; half_t B[128 * 32]; } s;   // 16 KB
    half_t T[4][64 * 68];                                   // 34.8 KB (V epilogue)
  } sm;

  const int tid  = threadIdx.x;
  const int wave = tid >> 6, lane = tid & 63;
  const int L15  = lane & 15, quad = lane >> 4;
  const int wm = (wave & 1) * 64, wn = (wave >> 1) * 64;
  const int m0 = blockIdx.x * 128;
  const int f0 = blockIdx.y * 128;

  const int srow = lane >> 2;            // 0..15
  const int scolh = (lane & 3) * 8;      // half offset within row
  const half_t* Ag = Ah + (size_t)(m0 + wave * 16 + srow) * CC + scolh;
  const half_t* Bg = Bh + (size_t)(f0 + wave * 16 + srow) * CC + scolh;
  half_t* Al = &sm.s.A[(wave * 16) * 32];
  half_t* Bl = &sm.s.B[(wave * 16) * 32];

  floatx4 acc[4][4];
#pragma unroll
  for (int i = 0; i < 4; ++i)
#pragma unroll
    for (int j = 0; j < 4; ++j) acc[i][j] = (floatx4){0.f, 0.f, 0.f, 0.f};

  for (int k0 = 0; k0 < CC; k0 += 32) {
    __syncthreads();
    gld16(Ag + k0,            Al);
    gld16(Ag + k0 + 64 * CC,  Al + 64 * 32);
    gld16(Bg + k0,            Bl);
    gld16(Bg + k0 + 64 * CC,  Bl + 64 * 32);
    __syncthreads();
    half8 af[4], bf[4];
#pragma unroll
    for (int mi = 0; mi < 4; ++mi)
      af[mi] = *(const half8*)&sm.s.A[(wm + mi * 16 + L15) * 32 + quad * 8];
#pragma unroll
    for (int ni = 0; ni < 4; ++ni)
      bf[ni] = *(const half8*)&sm.s.B[(wn + ni * 16 + L15) * 32 + quad * 8];
#pragma unroll
    for (int mi = 0; mi < 4; ++mi)
#pragma unroll
      for (int ni = 0; ni < 4; ++ni)
        acc[mi][ni] = __builtin_amdgcn_mfma_f32_16x16x32_f16(af[mi], bf[ni], acc[mi][ni], 0, 0, 0);
  }

  const int which = f0 >> 9;         // block-uniform (128 | 512)
  const int b     = m0 >> 11;        // block-uniform
  const int n_base = (m0 & 2047) + wm;

  if (which < 2) {
    const int nc = *ncp;
    half_t* dst = which ? Kh : Qh;
    const float qscale = which ? 1.0f : (0.125f * LOG2E);
#pragma unroll
    for (int ni = 0; ni < 4; ++ni) {
      const int f = f0 + wn + ni * 16 + L15;
      const int h = (f >> 6) & 7;
      const int d = f & 63;
      const float sgn = (d & 1) ? 1.0f : -1.0f;
      const float2* tj = tab + (d >> 1);
#pragma unroll
      for (int mi = 0; mi < 4; ++mi)
#pragma unroll
        for (int r = 0; r < 4; ++r) {
          const int n = n_base + mi * 16 + quad * 4 + r;
          float v = acc[mi][ni][r];
          float p = __shfl_xor(v, 1, 64);   // RoPE partner (d ^ 1)
          if (n >= nc) {
            float2 cs = tj[(size_t)(n - nc) * 32];
            v = v * cs.x + sgn * p * cs.y;
          }
          dst[(((size_t)(b * HH + h) * NN + n) << 6) + d] = (half_t)(v * qscale);
        }
    }
  } else {
    // V: per-wave 64x64 transpose through LDS -> (B,H,D,N)
    __syncthreads();   // all waves done reading sm.s (union overwrite)
#pragma unroll
    for (int ni = 0; ni < 4; ++ni)
#pragma unroll
      for (int mi = 0; mi < 4; ++mi)
#pragma unroll
        for (int r = 0; r < 4; ++r)
          sm.T[wave][(ni * 16 + L15) * 68 + mi * 16 + quad * 4 + r] = (half_t)acc[mi][ni][r];
    __syncthreads();
    const int h = ((f0 + wn) >> 6) & 7;
    const size_t gbase = ((size_t)(b * HH + h) * DD + lane) * NN + n_base;
#pragma unroll
    for (int c = 0; c < 8; ++c)
      *(half8*)(Vt + gbase + c * 8) = *(const half8*)&sm.T[wave][lane * 68 + c * 8];
  }
}

// ---------------------------------------------------------------------------
// Kernel 2: flash attention, swapped-operand 32x32x16 MFMA.
// This round: 64 q-rows/block, 4 waves = 2 q-sets x 2 k-groups; each group
// single-buffers a 32-k K/V tile (16 KB total LDS). Grid 2048 -> 8 blocks/CU,
// VGPR capped at 64 via __launch_bounds__(256,8) -> 32 waves/CU.
// Per-wave inner body identical to round-2's per-t phase (known 64-VGPR fit).
// k-groups interleave tiles (2s+grp); partial (acc,l) merged via LDS at end
// (fixed-offset softmax is additive).
// ---------------------------------------------------------------------------
#define EXP2_OFF 4.3280851f   // 3 * log2(e)
__global__ __launch_bounds__(256, 8) void flash_mfma_kernel(
    const half_t* __restrict__ Qh,   // (B,H,N,D)  (q pre-scaled by 0.125*log2e)
    const half_t* __restrict__ Kh,   // (B,H,N,D)
    const half_t* __restrict__ Vt,   // (B,H,D,N)
    const float*  __restrict__ mask, // (B,N)
    half_t* __restrict__ O)          // (B,N,C) fp16
{
  // halfs 0..4095: K[grp][32 rows][64 d]; 4096..8191: V[grp][64 d][32 k]
  __shared__ __align__(16) half_t KVs[8192];   // 16 KB
  __shared__ float Ll[64];

  const int tid  = threadIdx.x;
  const int wave = tid >> 6;            // 0..3
  const int qs   = wave & 1;            // q-set (32 rows)
  const int grp  = wave >> 1;           // k-group 0/1
  const int lane = tid & 63;
  const int l31  = lane & 31;
  const int hi   = lane >> 5;           // 0/1
  const int l7   = lane & 7;

  // XCD-aware decode (grid 2048, %8==0 -> bijective)
  const int bid  = blockIdx.x;
  const int xcd  = bid & 7;
  const int slot = bid >> 3;            // 0..255
  const int qt   = slot & 31;           // 32 q-tiles of 64 rows
  const int head = (slot >> 5) * 8 + xcd;   // 0..63
  const int b    = head >> 3;
  const int h    = head & 7;

  const half_t* Kt_base = Kh + ((((size_t)b * HH + h) * NN) << 6);
  const half_t* Vt_base = Vt + (((size_t)b * HH + h) * DD) * NN;

  // Q B-fragments: q = qt*64 + qs*32 + l31 ; d elem = kd*16 + hi*8 + j
  half8 qf[4];
  {
    const half_t* Qp =
        Qh + ((((size_t)b * HH + h) * NN + qt * 64 + qs * 32 + l31) << 6) + hi * 8;
#pragma unroll
    for (int kd = 0; kd < 4; ++kd) qf[kd] = *(const half8*)(Qp + kd * 16);
  }

  // --- staging (source pre-swizzled; LDS dest linear for gld16) ---
  // K tile [32][64]: wave qs stages rows 16qs..16qs+15 (2 calls of 8 rows).
  //   row = 16qs + 8c + (lane>>3); slot = lane&7; src slot' = slot ^ (row&7).
  const int r8 = lane >> 3;
  const half_t* kbase = Kt_base + (size_t)(grp * 32 + qs * 16 + r8) * 64
                        + ((l7 ^ r8) << 3);
  // V tile [64 d][32 k]: wave qs stages d = 32qs..32qs+31 (2 calls of 16 d).
  //   d = 32qs + 16c + (lane>>2); slot = lane&3; src slot' = slot ^ (d&3).
  const half_t* vbase = Vt_base + (size_t)(qs * 32 + (lane >> 2)) * NN
                        + grp * 32 + (((lane & 3) ^ ((lane >> 2) & 3)) << 3);
  half_t* Kl0 = &KVs[grp * 2048 + qs * 1024];
  half_t* Vl0 = &KVs[4096 + grp * 2048 + qs * 1024];

  // LDS read addrs (bytes)
  int adK[4], adV[2];
#pragma unroll
  for (int kd = 0; kd < 4; ++kd)
    adK[kd] = grp * 4096 + l31 * 128 + ((((kd << 1) | hi) ^ l7) << 4);
#pragma unroll
  for (int ks = 0; ks < 2; ++ks)
    adV[ks] = 8192 + grp * 4096 + l31 * 64 + ((((ks << 1) | hi) ^ (l31 & 3)) << 4);
  const char* L = (const char*)KVs;

  floatx16 acc[2];
#pragma unroll
  for (int dt = 0; dt < 2; ++dt)
#pragma unroll
    for (int r = 0; r < 16; ++r) acc[dt][r] = 0.f;
  float l_part = 0.f;

  const float* mkb = mask + (size_t)b * NN + grp * 32 + hi * 4;

#define STAGE_KV()                                                            \
  {                                                                           \
    gld16(kbase,           Kl0);                                              \
    gld16(kbase + 512,     Kl0 + 512);                                        \
    gld16(vbase,           Vl0);                                              \
    gld16(vbase + 16 * NN, Vl0 + 512);                                        \
    kbase += 4096; vbase += 64;                                               \
  }

#define COMPUTE()                                                             \
  {                                                                           \
    fx4 m4[4];                                                                \
    _Pragma("unroll")                                                         \
    for (int r2 = 0; r2 < 4; ++r2) m4[r2] = *(const fx4*)(mkb + r2 * 8);      \
    floatx16 S;                                                               \
    _Pragma("unroll") for (int r = 0; r < 16; ++r) S[r] = 0.f;                \
    __builtin_amdgcn_s_setprio(1);                                            \
    _Pragma("unroll")                                                         \
    for (int kd = 0; kd < 4; ++kd) {                                          \
      half8 kf = *(const half8*)(L + adK[kd]);                                \
      S = __builtin_amdgcn_mfma_f32_32x32x16_f16(kf, qf[kd], S, 0, 0, 0);     \
    }                                                                         \
    __builtin_amdgcn_s_setprio(0);                                            \
    _Pragma("unroll")                                                         \
    for (int r = 0; r < 16; ++r) {                                            \
      float p = __builtin_amdgcn_exp2f(fmaf(m4[r >> 2][r & 3], LOG2E, S[r] - EXP2_OFF)); \
      l_part += p;                                                            \
      S[r] = p;                                                               \
    }                                                                         \
    unsigned W[4][2];                                                         \
    _Pragma("unroll")                                                         \
    for (int r2 = 0; r2 < 4; ++r2)                                            \
      _Pragma("unroll")                                                       \
      for (int u = 0; u < 2; ++u) {                                           \
        union { half_t hh[2]; unsigned w; } pk;                               \
        pk.hh[0] = (half_t)S[r2 * 4 + 2 * u];                                 \
        pk.hh[1] = (half_t)S[r2 * 4 + 2 * u + 1];                             \
        W[r2][u] = pk.w;                                                      \
      }                                                                       \
    _Pragma("unroll")                                                         \
    for (int ksl = 0; ksl < 2; ++ksl) {                                       \
      unsigned A0 = W[2 * ksl][0],     A1 = W[2 * ksl][1];                    \
      unsigned B0 = W[2 * ksl + 1][0], B1 = W[2 * ksl + 1][1];                \
      unsigned pA0 = __shfl_xor(A0, 32, 64), pA1 = __shfl_xor(A1, 32, 64);    \
      unsigned pB0 = __shfl_xor(B0, 32, 64), pB1 = __shfl_xor(B1, 32, 64);    \
      union { unsigned u4[4]; half8 v; } pw;                                  \
      pw.u4[0] = hi ? pB0 : A0;                                               \
      pw.u4[1] = hi ? pB1 : A1;                                               \
      pw.u4[2] = hi ? B0 : pA0;                                               \
      pw.u4[3] = hi ? B1 : pA1;                                               \
      __builtin_amdgcn_s_setprio(1);                                          \
      _Pragma("unroll")                                                       \
      for (int dt = 0; dt < 2; ++dt) {                                        \
        half8 vf = *(const half8*)(L + (adV[ksl] + dt * 2048));               \
        acc[dt] = __builtin_amdgcn_mfma_f32_32x32x16_f16(pw.v, vf, acc[dt], 0, 0, 0); \
      }                                                                       \
      __builtin_amdgcn_s_setprio(0);                                          \
    }                                                                         \
  }

  // prologue: each group stages its first tile (tile index grp)
  STAGE_KV()
  asm volatile("s_waitcnt vmcnt(0)");
  __builtin_amdgcn_s_barrier();
  __builtin_amdgcn_sched_barrier(0);

#pragma unroll 1
  for (int s = 0; s < 31; ++s) {       // group g computes tiles 2s+g (32 k each)
    COMPUTE()
    __builtin_amdgcn_sched_barrier(0);
    __builtin_amdgcn_s_barrier();      // all waves done reading KVs
    STAGE_KV()                         // tile 2(s+1)+g -> own buffer
    asm volatile("s_waitcnt vmcnt(0)");
    __builtin_amdgcn_s_barrier();      // all stages visible
    __builtin_amdgcn_sched_barrier(0);
    mkb += 64;
  }
  COMPUTE()                            // tiles 62 (grp 0) / 63 (grp 1)

#undef STAGE_KV
#undef COMPUTE

  // ---- cross-group merge (fixed-offset softmax is additive) ----
  __builtin_amdgcn_s_barrier();        // KVs reads done before overwrite
  l_part += __shfl_xor(l_part, 32, 64);   // merge hi-halves: l for q=l31

  float* Lf = (float*)KVs;             // 4096 floats == 16 KB (exact fit)
  if (grp) {
#pragma unroll
    for (int dt = 0; dt < 2; ++dt)
#pragma unroll
      for (int r = 0; r < 16; ++r) {
        const int ql = (r & 3) + 8 * (r >> 2) + 4 * hi;
        Lf[qs * 2048 + ql * 64 + dt * 32 + l31] = acc[dt][r];
      }
    if (!hi) Ll[qs * 32 + l31] = l_part;
  }
  __builtin_amdgcn_s_barrier();
  if (!grp) {
    const float lt = l_part + Ll[qs * 32 + l31];
    const size_t orow = (size_t)b * NN + qt * 64 + qs * 32;
#pragma unroll
    for (int r = 0; r < 16; ++r) {
      const int ql  = (r & 3) + 8 * (r >> 2) + 4 * hi;   // 0..31
      const float iv = 1.0f / __shfl(lt, ql, 64);
      const float a0 = acc[0][r] + Lf[qs * 2048 + ql * 64 + l31];
      const float a1 = acc[1][r] + Lf[qs * 2048 + ql * 64 + 32 + l31];
      const size_t ro = ((orow + ql) << 9) + (h << 6) + l31;
      O[ro]      = (half_t)(a0 * iv);
      O[ro + 32] = (half_t)(a1 * iv);
    }
  }
}

// ---------------------------------------------------------------------------
// Kernel 3: out = O @ W_proj^T + b_proj  (fp16 MFMA, fp32 out)  [unchanged]
// ---------------------------------------------------------------------------
__global__ __launch_bounds__(256) void proj_mfma_kernel(
    const half_t* __restrict__ Ah,   // (16384, 512) fp16
    const half_t* __restrict__ Bh,   // (512, 512) fp16
    const float* __restrict__ bias,  // (512,)
    float* __restrict__ out)         // (16384, 512)
{
  __shared__ half_t As[128 * 32];
  __shared__ half_t Bs[128 * 32];

  const int tid  = threadIdx.x;
  const int wave = tid >> 6, lane = tid & 63;
  const int L15  = lane & 15, quad = lane >> 4;
  const int wm = (wave & 1) * 64, wn = (wave >> 1) * 64;
  const int m0 = blockIdx.x * 128;
  const int f0 = blockIdx.y * 128;

  const int srow = lane >> 2;
  const int scolh = (lane & 3) * 8;
  const half_t* Ag = Ah + (size_t)(m0 + wave * 16 + srow) * CC + scolh;
  const half_t* Bg = Bh + (size_t)(f0 + wave * 16 + srow) * CC + scolh;
  half_t* Al = &As[(wave * 16) * 32];
  half_t* Bl = &Bs[(wave * 16) * 32];

  floatx4 acc[4][4];
#pragma unroll
  for (int i = 0; i < 4; ++i)
#pragma unroll
    for (int j = 0; j < 4; ++j) acc[i][j] = (floatx4){0.f, 0.f, 0.f, 0.f};

  for (int k0 = 0; k0 < CC; k0 += 32) {
    __syncthreads();
    gld16(Ag + k0,           Al);
    gld16(Ag + k0 + 64 * CC, Al + 64 * 32);
    gld16(Bg + k0,           Bl);
    gld16(Bg + k0 + 64 * CC, Bl + 64 * 32);
    __syncthreads();
    half8 af[4], bf[4];
#pragma unroll
    for (int mi = 0; mi < 4; ++mi)
      af[mi] = *(const half8*)&As[(wm + mi * 16 + L15) * 32 + quad * 8];
#pragma unroll
    for (int ni = 0; ni < 4; ++ni)
      bf[ni] = *(const half8*)&Bs[(wn + ni * 16 + L15) * 32 + quad * 8];
#pragma unroll
    for (int mi = 0; mi < 4; ++mi)
#pragma unroll
      for (int ni = 0; ni < 4; ++ni)
        acc[mi][ni] = __builtin_amdgcn_mfma_f32_16x16x32_f16(af[mi], bf[ni], acc[mi][ni], 0, 0, 0);
  }

#pragma unroll
  for (int ni = 0; ni < 4; ++ni) {
    const int f = f0 + wn + ni * 16 + L15;
    const float bv = bias[f];
#pragma unroll
    for (int mi = 0; mi < 4; ++mi)
#pragma unroll
      for (int r = 0; r < 4; ++r)
        out[(size_t)(m0 + wm + mi * 16 + quad * 4 + r) * CC + f] = acc[mi][ni][r] + bv;
  }
}

// ---------------------------------------------------------------------------
extern "C" void kernel_launch(void* const* d_in, const int* in_sizes, int n_in,
                              void* d_out, int out_size, void* d_ws, size_t ws_size,
                              hipStream_t stream) {
  const float* x     = (const float*)d_in[0];
  const float* mask  = (const float*)d_in[1];
  const float* Wqkv  = (const float*)d_in[2];
  const float* Wproj = (const float*)d_in[3];
  const float* bproj = (const float*)d_in[4];
  const int*   ncp   = (const int*)d_in[5];
  float* out = (float*)d_out;

  const size_t per = (size_t)BB * HH * NN * DD;   // 8,388,608
  half_t* xh  = (half_t*)d_ws;
  half_t* Wqh = xh + (size_t)MM * CC;
  half_t* Wph = Wqh + (size_t)FF * CC;
  half_t* Qh  = Wph + (size_t)CC * CC;
  half_t* Kh  = Qh + per;
  half_t* Vt  = Kh + per;
  half_t* Oh  = Vt + per;
  float2* tab = (float2*)(Oh + per);              // 2048*32*8B = 512 KB

  rope_tab_kernel<<<dim3(NN * 32 / 256), 256, 0, stream>>>(tab);
  cvt_kernel<<<dim3(MM * CC / 8 / 256), 256, 0, stream>>>(x, xh, MM * CC / 8);
  cvt_kernel<<<dim3(FF * CC / 8 / 256), 256, 0, stream>>>(Wqkv, Wqh, FF * CC / 8);
  cvt_kernel<<<dim3(CC * CC / 8 / 256), 256, 0, stream>>>(Wproj, Wph, CC * CC / 8);

  qkv_mfma_kernel<<<dim3(MM / 128, FF / 128), 256, 0, stream>>>(xh, Wqh, ncp, tab, Qh, Kh, Vt);
  flash_mfma_kernel<<<dim3(BB * HH * (NN / 64)), 256, 0, stream>>>(Qh, Kh, Vt, mask, Oh);
  proj_mfma_kernel<<<dim3(MM / 128, CC / 128), 256, 0, stream>>>(Oh, Wph, bproj, out);
}

// Round 5
// 396.789 us; speedup vs baseline: 2.2035x; 2.2035x over previous
//
#include <hip/hip_runtime.h>
#include <cmath>

#define BB 8
#define NN 2048
#define CC 512
#define HH 8
#define DD 64
#define FF 1536
#define MM (BB*NN)   // 16384

typedef _Float16 half_t;
typedef __attribute__((ext_vector_type(8))) _Float16 half8;
typedef __attribute__((ext_vector_type(4))) _Float16 half4;
typedef __attribute__((ext_vector_type(4))) float floatx4;
typedef __attribute__((ext_vector_type(16))) float floatx16;
typedef __attribute__((ext_vector_type(4))) float fx4;

#define LOG2E 1.44269504088896f
#define EXP2_OFF 4.3280851f   // 3 * log2(e)

// async global->LDS, 16 B per lane; LDS dest must be wave-uniform base (+lane*16)
typedef const __attribute__((address_space(1))) unsigned int* gas_ptr;
typedef __attribute__((address_space(3))) unsigned int* las_ptr;
__device__ __forceinline__ void gld16(const half_t* g, half_t* l) {
  __builtin_amdgcn_global_load_lds((gas_ptr)g, (las_ptr)l, 16, 0, 0);
}

// ---------------------------------------------------------------------------
// fp32 -> fp16 convert (8 elems/thread)
// ---------------------------------------------------------------------------
__global__ __launch_bounds__(256) void cvt_kernel(
    const float* __restrict__ s, half_t* __restrict__ d, int n8) {
  int i = blockIdx.x * 256 + threadIdx.x;
  if (i < n8) {
    float4 a = ((const float4*)s)[i * 2], b = ((const float4*)s)[i * 2 + 1];
    half8 h;
    h[0] = (half_t)a.x; h[1] = (half_t)a.y; h[2] = (half_t)a.z; h[3] = (half_t)a.w;
    h[4] = (half_t)b.x; h[5] = (half_t)b.y; h[6] = (half_t)b.z; h[7] = (half_t)b.w;
    ((half8*)d)[i] = h;
  }
}

// ---------------------------------------------------------------------------
// mask prep: ms[i] = mask[i]*log2e - EXP2_OFF  (16384 elems)
// ---------------------------------------------------------------------------
__global__ __launch_bounds__(256) void mask_prep_kernel(
    const float* __restrict__ m, float* __restrict__ d) {
  int i = blockIdx.x * 256 + threadIdx.x;
  d[i] = m[i] * LOG2E - EXP2_OFF;
}

// ---------------------------------------------------------------------------
// RoPE cos/sin table: tab[p][j] = (cos, sin)(p * 10000^(-2j/64)), p<2048, j<32
// ---------------------------------------------------------------------------
__global__ __launch_bounds__(256) void rope_tab_kernel(float2* __restrict__ tab) {
  int i = blockIdx.x * 256 + threadIdx.x;       // 65536 entries
  int p = i >> 5, j = i & 31;
  float ang = (float)p * __powf(10000.0f, -(float)(2 * j) * (1.0f / 64.0f));
  float sv, cv;
  __sincosf(ang, &sv, &cv);
  tab[i] = make_float2(cv, sv);
}

// ---------------------------------------------------------------------------
// Kernel 1: qkv = x @ W_qkv^T  (fp16 MFMA, 128x128 tile, BK=32, 4 waves)
// Fused epilogue: RoPE via precomputed table (+ q scale incl. log2e)
// -> Qh/Kh fp16 (B,H,N,D); V -> LDS transpose -> Vt fp16 (B,H,D,N).
// ---------------------------------------------------------------------------
__global__ __launch_bounds__(256) void qkv_mfma_kernel(
    const half_t* __restrict__ Ah,   // (16384, 512)
    const half_t* __restrict__ Bh,   // (1536, 512)
    const int*   __restrict__ ncp,
    const float2* __restrict__ tab,  // (2048, 32) cos/sin
    half_t* __restrict__ Qh, half_t* __restrict__ Kh, half_t* __restrict__ Vt)
{
  __shared__ union {
    struct { half_t A[128 * 32]; half_t B[128 * 32]; } s;   // 16 KB
    half_t T[4][64 * 68];                                   // 34.8 KB (V epilogue)
  } sm;

  const int tid  = threadIdx.x;
  const int wave = tid >> 6, lane = tid & 63;
  const int L15  = lane & 15, quad = lane >> 4;
  const int wm = (wave & 1) * 64, wn = (wave >> 1) * 64;
  const int m0 = blockIdx.x * 128;
  const int f0 = blockIdx.y * 128;

  const int srow = lane >> 2;            // 0..15
  const int scolh = (lane & 3) * 8;      // half offset within row
  const half_t* Ag = Ah + (size_t)(m0 + wave * 16 + srow) * CC + scolh;
  const half_t* Bg = Bh + (size_t)(f0 + wave * 16 + srow) * CC + scolh;
  half_t* Al = &sm.s.A[(wave * 16) * 32];
  half_t* Bl = &sm.s.B[(wave * 16) * 32];

  floatx4 acc[4][4];
#pragma unroll
  for (int i = 0; i < 4; ++i)
#pragma unroll
    for (int j = 0; j < 4; ++j) acc[i][j] = (floatx4){0.f, 0.f, 0.f, 0.f};

  for (int k0 = 0; k0 < CC; k0 += 32) {
    __syncthreads();
    gld16(Ag + k0,            Al);
    gld16(Ag + k0 + 64 * CC,  Al + 64 * 32);
    gld16(Bg + k0,            Bl);
    gld16(Bg + k0 + 64 * CC,  Bl + 64 * 32);
    __syncthreads();
    half8 af[4], bf[4];
#pragma unroll
    for (int mi = 0; mi < 4; ++mi)
      af[mi] = *(const half8*)&sm.s.A[(wm + mi * 16 + L15) * 32 + quad * 8];
#pragma unroll
    for (int ni = 0; ni < 4; ++ni)
      bf[ni] = *(const half8*)&sm.s.B[(wn + ni * 16 + L15) * 32 + quad * 8];
#pragma unroll
    for (int mi = 0; mi < 4; ++mi)
#pragma unroll
      for (int ni = 0; ni < 4; ++ni)
        acc[mi][ni] = __builtin_amdgcn_mfma_f32_16x16x32_f16(af[mi], bf[ni], acc[mi][ni], 0, 0, 0);
  }

  const int which = f0 >> 9;         // block-uniform (128 | 512)
  const int b     = m0 >> 11;        // block-uniform
  const int n_base = (m0 & 2047) + wm;

  if (which < 2) {
    const int nc = *ncp;
    half_t* dst = which ? Kh : Qh;
    const float qscale = which ? 1.0f : (0.125f * LOG2E);
#pragma unroll
    for (int ni = 0; ni < 4; ++ni) {
      const int f = f0 + wn + ni * 16 + L15;
      const int h = (f >> 6) & 7;
      const int d = f & 63;
      const float sgn = (d & 1) ? 1.0f : -1.0f;
      const float2* tj = tab + (d >> 1);
#pragma unroll
      for (int mi = 0; mi < 4; ++mi)
#pragma unroll
        for (int r = 0; r < 4; ++r) {
          const int n = n_base + mi * 16 + quad * 4 + r;
          float v = acc[mi][ni][r];
          float p = __shfl_xor(v, 1, 64);   // RoPE partner (d ^ 1)
          if (n >= nc) {
            float2 cs = tj[(size_t)(n - nc) * 32];
            v = v * cs.x + sgn * p * cs.y;
          }
          dst[(((size_t)(b * HH + h) * NN + n) << 6) + d] = (half_t)(v * qscale);
        }
    }
  } else {
    // V: per-wave 64x64 transpose through LDS -> (B,H,D,N)
    __syncthreads();   // all waves done reading sm.s (union overwrite)
#pragma unroll
    for (int ni = 0; ni < 4; ++ni)
#pragma unroll
      for (int mi = 0; mi < 4; ++mi)
#pragma unroll
        for (int r = 0; r < 4; ++r)
          sm.T[wave][(ni * 16 + L15) * 68 + mi * 16 + quad * 4 + r] = (half_t)acc[mi][ni][r];
    __syncthreads();
    const int h = ((f0 + wn) >> 6) & 7;
    const size_t gbase = ((size_t)(b * HH + h) * DD + lane) * NN + n_base;
#pragma unroll
    for (int c = 0; c < 8; ++c)
      *(half8*)(Vt + gbase + c * 8) = *(const half8*)&sm.T[wave][lane * 68 + c * 8];
  }
}

// ---------------------------------------------------------------------------
// Kernel 2: flash attention, swapped-operand 32x32x16 MFMA.
// Round-2 geometry restored (128 q-rows/block, 4 waves, double-buffered K/V,
// counted vmcnt(4), grid 1024, launch_bounds(256,4) -> 64 VGPR, no spill).
// Surgical changes this round:
//  - mask (pre-scaled by log2e - OFF) folded into MFMA C-init (no adds)
//  - permlane32_swap routing: 8 ds_bpermute + 8 cndmask -> 4 VALU permlanes
//  - l partials split into 4 accumulators (dep chain 16 -> 4)
// ---------------------------------------------------------------------------
__global__ __launch_bounds__(256, 4) void flash_mfma_kernel(
    const half_t* __restrict__ Qh,   // (B,H,N,D)  (q pre-scaled by 0.125*log2e)
    const half_t* __restrict__ Kh,   // (B,H,N,D)
    const half_t* __restrict__ Vt,   // (B,H,D,N)
    const float*  __restrict__ ms,   // (B,N) pre-scaled mask
    half_t* __restrict__ O)          // (B,N,C) fp16
{
  __shared__ half_t KV[2][2][64 * 64];   // [buf][K|V][row*64 + e]  32 KB

  const int tid  = threadIdx.x;
  const int wave = tid >> 6;            // 0..3
  const int lane = tid & 63;
  const int l31  = lane & 31;
  const int hi   = lane >> 5;           // 0/1
  const int l7   = lane & 7;

  // XCD-aware decode: blocks with the same head share blockIdx%8 (same XCD)
  const int bid  = blockIdx.x;          // 0..1023
  const int xcd  = bid & 7;
  const int slot = bid >> 3;            // 0..127
  const int qt   = slot & 15;           // 16 q-tiles of 128 rows
  const int head = (slot >> 4) * 8 + xcd;   // 0..63
  const int b    = head >> 3;
  const int h    = head & 7;

  const half_t* Kt_base = Kh + ((((size_t)b * HH + h) * NN) << 6);
  const half_t* Vt_base = Vt + (((size_t)b * HH + h) * DD) * NN;

  // Q B-fragments: q = qt*128 + wave*32 + l31 ; k-dim elem = kd*16 + hi*8 + j
  half8 qf[4];
  {
    const half_t* Qp =
        Qh + ((((size_t)b * HH + h) * NN + qt * 128 + wave * 32 + l31) << 6) + hi * 8;
#pragma unroll
    for (int kd = 0; kd < 4; ++kd) qf[kd] = *(const half8*)(Qp + kd * 16);
  }

  // staging source pointers, pre-swizzled: LDS linear slot sl of row holds
  // source 16B-group (sl ^ (row&7)); row&7 == lane>>3 here.
  const int r8  = lane >> 3;                 // 0..7
  const int dof = ((l7 ^ r8) << 3);          // halfs
  const half_t* kbase = Kt_base + (((size_t)(wave * 16 + r8)) << 6) + dof;
  const half_t* vbase = Vt_base + (size_t)(wave * 16 + r8) * NN + dof;

  // LDS read addrs (bytes), buffer/t offsets added as immediates at use.
  int adK[4], adV[4];
#pragma unroll
  for (int c = 0; c < 4; ++c) {
    adK[c] = l31 * 128 + ((((c << 1) | hi) ^ l7) << 4);
    adV[c] = 8192 + l31 * 128 + ((((c << 1) | hi) ^ l7) << 4);
  }
  const char* L = (const char*)KV;

  floatx16 acc[2];
#pragma unroll
  for (int dt = 0; dt < 2; ++dt)
#pragma unroll
    for (int r = 0; r < 16; ++r) acc[dt][r] = 0.f;
  float l4[4] = {0.f, 0.f, 0.f, 0.f};

  const float* mkb = ms + (size_t)b * NN + hi * 4;

#define STAGE(c, koff, voff)                                                  \
  {                                                                           \
    gld16(kbase + (koff),          &KV[c][0][wave * 1024]);                   \
    gld16(kbase + (koff) + 512,    &KV[c][0][wave * 1024 + 512]);             \
    gld16(vbase + (voff),          &KV[c][1][wave * 1024]);                   \
    gld16(vbase + (voff) + 8 * NN, &KV[c][1][wave * 1024 + 512]);             \
  }

#define COMPUTE(c, moff)                                                      \
  _Pragma("unroll")                                                           \
  for (int t = 0; t < 2; ++t) {                                               \
    floatx16 S;                                                               \
    _Pragma("unroll")                                                         \
    for (int r2 = 0; r2 < 4; ++r2) {                                          \
      fx4 mv = *(const fx4*)(mkb + (moff) + t * 32 + r2 * 8);                 \
      S[r2 * 4 + 0] = mv[0]; S[r2 * 4 + 1] = mv[1];                           \
      S[r2 * 4 + 2] = mv[2]; S[r2 * 4 + 3] = mv[3];                           \
    }                                                                         \
    __builtin_amdgcn_s_setprio(1);                                            \
    _Pragma("unroll")                                                         \
    for (int kd = 0; kd < 4; ++kd) {                                          \
      half8 kf = *(const half8*)(L + (adK[kd] + (c) * 16384 + t * 4096));     \
      S = __builtin_amdgcn_mfma_f32_32x32x16_f16(kf, qf[kd], S, 0, 0, 0);     \
    }                                                                         \
    __builtin_amdgcn_s_setprio(0);                                            \
    _Pragma("unroll")                                                         \
    for (int r = 0; r < 16; ++r) {                                            \
      float p = __builtin_amdgcn_exp2f(S[r]);                                 \
      l4[r & 3] += p;                                                         \
      S[r] = p;                                                               \
    }                                                                         \
    unsigned W[4][2];                                                         \
    _Pragma("unroll")                                                         \
    for (int r2 = 0; r2 < 4; ++r2)                                            \
      _Pragma("unroll")                                                       \
      for (int u = 0; u < 2; ++u) {                                           \
        union { half_t hh[2]; unsigned w; } pk;                               \
        pk.hh[0] = (half_t)S[r2 * 4 + 2 * u];                                 \
        pk.hh[1] = (half_t)S[r2 * 4 + 2 * u + 1];                             \
        W[r2][u] = pk.w;                                                      \
      }                                                                       \
    _Pragma("unroll")                                                         \
    for (int ksl = 0; ksl < 2; ++ksl) {                                       \
      union { unsigned u4[4]; half8 v; } pw;                                  \
      _Pragma("unroll")                                                       \
      for (int u = 0; u < 2; ++u) {                                           \
        auto rr = __builtin_amdgcn_permlane32_swap(                           \
            (int)W[2 * ksl][u], (int)W[2 * ksl + 1][u], false, false);        \
        pw.u4[u]     = (unsigned)rr[0];                                       \
        pw.u4[2 + u] = (unsigned)rr[1];                                       \
      }                                                                       \
      const int ks = t * 2 + ksl;                                             \
      __builtin_amdgcn_s_setprio(1);                                          \
      _Pragma("unroll")                                                       \
      for (int dt = 0; dt < 2; ++dt) {                                        \
        half8 vf = *(const half8*)(L + (adV[ks] + (c) * 16384 + dt * 4096));  \
        acc[dt] = __builtin_amdgcn_mfma_f32_32x32x16_f16(pw.v, vf, acc[dt], 0, 0, 0); \
      }                                                                       \
      __builtin_amdgcn_s_setprio(0);                                          \
    }                                                                         \
  }

  // prologue: stage tiles 0 and 1; wait only for tile 0; barrier.
  STAGE(0, 0, 0)
  STAGE(1, 4096, 64)
  asm volatile("s_waitcnt vmcnt(4)");
  __builtin_amdgcn_s_barrier();
  __builtin_amdgcn_sched_barrier(0);
  kbase += 8192; vbase += 128;   // now pointing at tile 2

#pragma unroll 1
  for (int kt2 = 0; kt2 < 15; ++kt2) {   // tiles 0..29; stages tiles 2..31
    COMPUTE(0, 0)
    __builtin_amdgcn_sched_barrier(0);
    __builtin_amdgcn_s_barrier();        // all waves done reading buf 0
    STAGE(0, 0, 0)                       // tile 2*kt2+2 -> buf 0
    asm volatile("s_waitcnt vmcnt(4)");  // stage(2*kt2+1) landed; fresh 4 in flight
    __builtin_amdgcn_s_barrier();
    __builtin_amdgcn_sched_barrier(0);

    COMPUTE(1, 64)
    __builtin_amdgcn_sched_barrier(0);
    __builtin_amdgcn_s_barrier();        // all waves done reading buf 1
    STAGE(1, 4096, 64)                   // tile 2*kt2+3 -> buf 1
    asm volatile("s_waitcnt vmcnt(4)");  // stage(2*kt2+2) landed
    __builtin_amdgcn_s_barrier();
    __builtin_amdgcn_sched_barrier(0);

    kbase += 8192; vbase += 128;
    mkb += 128;
  }

  // tail: tiles 30 (buf 0) and 31 (buf 1); no more staging
  COMPUTE(0, 0)
  asm volatile("s_waitcnt vmcnt(0)");    // stage(31) fully landed
  __builtin_amdgcn_s_barrier();
  __builtin_amdgcn_sched_barrier(0);
  COMPUTE(1, 64)

#undef STAGE
#undef COMPUTE

  // l: combine 4 partials, then sum the two lane-halves (q = lane&31)
  float l_part = (l4[0] + l4[1]) + (l4[2] + l4[3]);
  l_part += __shfl_xor(l_part, 32, 64);

  const size_t orow = (size_t)b * NN + qt * 128 + wave * 32;
#pragma unroll
  for (int r = 0; r < 16; ++r) {
    const int ql  = (r & 3) + 8 * (r >> 2) + 4 * hi;   // 0..31
    const float iv = 1.0f / __shfl(l_part, ql, 64);
    const size_t ro = ((orow + ql) << 9) + (h << 6) + l31;
    O[ro]      = (half_t)(acc[0][r] * iv);
    O[ro + 32] = (half_t)(acc[1][r] * iv);
  }
}

// ---------------------------------------------------------------------------
// Kernel 3: out = O @ W_proj^T + b_proj  (fp16 MFMA, fp32 out)  [unchanged]
// ---------------------------------------------------------------------------
__global__ __launch_bounds__(256) void proj_mfma_kernel(
    const half_t* __restrict__ Ah,   // (16384, 512) fp16
    const half_t* __restrict__ Bh,   // (512, 512) fp16
    const float* __restrict__ bias,  // (512,)
    float* __restrict__ out)         // (16384, 512)
{
  __shared__ half_t As[128 * 32];
  __shared__ half_t Bs[128 * 32];

  const int tid  = threadIdx.x;
  const int wave = tid >> 6, lane = tid & 63;
  const int L15  = lane & 15, quad = lane >> 4;
  const int wm = (wave & 1) * 64, wn = (wave >> 1) * 64;
  const int m0 = blockIdx.x * 128;
  const int f0 = blockIdx.y * 128;

  const int srow = lane >> 2;
  const int scolh = (lane & 3) * 8;
  const half_t* Ag = Ah + (size_t)(m0 + wave * 16 + srow) * CC + scolh;
  const half_t* Bg = Bh + (size_t)(f0 + wave * 16 + srow) * CC + scolh;
  half_t* Al = &As[(wave * 16) * 32];
  half_t* Bl = &Bs[(wave * 16) * 32];

  floatx4 acc[4][4];
#pragma unroll
  for (int i = 0; i < 4; ++i)
#pragma unroll
    for (int j = 0; j < 4; ++j) acc[i][j] = (floatx4){0.f, 0.f, 0.f, 0.f};

  for (int k0 = 0; k0 < CC; k0 += 32) {
    __syncthreads();
    gld16(Ag + k0,           Al);
    gld16(Ag + k0 + 64 * CC, Al + 64 * 32);
    gld16(Bg + k0,           Bl);
    gld16(Bg + k0 + 64 * CC, Bl + 64 * 32);
    __syncthreads();
    half8 af[4], bf[4];
#pragma unroll
    for (int mi = 0; mi < 4; ++mi)
      af[mi] = *(const half8*)&As[(wm + mi * 16 + L15) * 32 + quad * 8];
#pragma unroll
    for (int ni = 0; ni < 4; ++ni)
      bf[ni] = *(const half8*)&Bs[(wn + ni * 16 + L15) * 32 + quad * 8];
#pragma unroll
    for (int mi = 0; mi < 4; ++mi)
#pragma unroll
      for (int ni = 0; ni < 4; ++ni)
        acc[mi][ni] = __builtin_amdgcn_mfma_f32_16x16x32_f16(af[mi], bf[ni], acc[mi][ni], 0, 0, 0);
  }

#pragma unroll
  for (int ni = 0; ni < 4; ++ni) {
    const int f = f0 + wn + ni * 16 + L15;
    const float bv = bias[f];
#pragma unroll
    for (int mi = 0; mi < 4; ++mi)
#pragma unroll
      for (int r = 0; r < 4; ++r)
        out[(size_t)(m0 + wm + mi * 16 + quad * 4 + r) * CC + f] = acc[mi][ni][r] + bv;
  }
}

// ---------------------------------------------------------------------------
extern "C" void kernel_launch(void* const* d_in, const int* in_sizes, int n_in,
                              void* d_out, int out_size, void* d_ws, size_t ws_size,
                              hipStream_t stream) {
  const float* x     = (const float*)d_in[0];
  const float* mask  = (const float*)d_in[1];
  const float* Wqkv  = (const float*)d_in[2];
  const float* Wproj = (const float*)d_in[3];
  const float* bproj = (const float*)d_in[4];
  const int*   ncp   = (const int*)d_in[5];
  float* out = (float*)d_out;

  const size_t per = (size_t)BB * HH * NN * DD;   // 8,388,608
  half_t* xh  = (half_t*)d_ws;
  half_t* Wqh = xh + (size_t)MM * CC;
  half_t* Wph = Wqh + (size_t)FF * CC;
  half_t* Qh  = Wph + (size_t)CC * CC;
  half_t* Kh  = Qh + per;
  half_t* Vt  = Kh + per;
  half_t* Oh  = Vt + per;
  float2* tab = (float2*)(Oh + per);              // 2048*32*8B = 512 KB
  float*  msb = (float*)(tab + (size_t)NN * 32);  // 16384*4B = 64 KB

  rope_tab_kernel<<<dim3(NN * 32 / 256), 256, 0, stream>>>(tab);
  mask_prep_kernel<<<dim3(MM / 256), 256, 0, stream>>>(mask, msb);
  cvt_kernel<<<dim3(MM * CC / 8 / 256), 256, 0, stream>>>(x, xh, MM * CC / 8);
  cvt_kernel<<<dim3(FF * CC / 8 / 256), 256, 0, stream>>>(Wqkv, Wqh, FF * CC / 8);
  cvt_kernel<<<dim3(CC * CC / 8 / 256), 256, 0, stream>>>(Wproj, Wph, CC * CC / 8);

  qkv_mfma_kernel<<<dim3(MM / 128, FF / 128), 256, 0, stream>>>(xh, Wqh, ncp, tab, Qh, Kh, Vt);
  flash_mfma_kernel<<<dim3(BB * HH * (NN / 128)), 256, 0, stream>>>(Qh, Kh, Vt, msb, Oh);
  proj_mfma_kernel<<<dim3(MM / 128, CC / 128), 256, 0, stream>>>(Oh, Wph, bproj, out);
}

// Round 6
// 337.293 us; speedup vs baseline: 2.5921x; 1.1764x over previous
//
#include <hip/hip_runtime.h>
#include <cmath>

#define BB 8
#define NN 2048
#define CC 512
#define HH 8
#define DD 64
#define FF 1536
#define MM (BB*NN)   // 16384

typedef _Float16 half_t;
typedef __attribute__((ext_vector_type(8))) _Float16 half8;
typedef __attribute__((ext_vector_type(4))) _Float16 half4;
typedef __attribute__((ext_vector_type(4))) float floatx4;
typedef __attribute__((ext_vector_type(16))) float floatx16;
typedef __attribute__((ext_vector_type(4))) float fx4;

#define LOG2E 1.44269504088896f
#define EXP2_OFF 4.3280851f   // 3 * log2(e)

// async global->LDS, 16 B per lane; LDS dest must be wave-uniform base (+lane*16)
typedef const __attribute__((address_space(1))) unsigned int* gas_ptr;
typedef __attribute__((address_space(3))) unsigned int* las_ptr;
__device__ __forceinline__ void gld16(const half_t* g, half_t* l) {
  __builtin_amdgcn_global_load_lds((gas_ptr)g, (las_ptr)l, 16, 0, 0);
}

// ---------------------------------------------------------------------------
// fused fp32 -> fp16 convert for x, W_qkv, W_proj (dest regions contiguous)
// ---------------------------------------------------------------------------
#define N1 (MM * CC / 8)          // 1,048,576 half8 groups (x)
#define N2 (FF * CC / 8)          // 98,304 (W_qkv)
#define N3 (CC * CC / 8)          // 32,768 (W_proj)
__global__ __launch_bounds__(256) void cvt_all_kernel(
    const float* __restrict__ x, const float* __restrict__ wq,
    const float* __restrict__ wp, half_t* __restrict__ d) {
  int i = blockIdx.x * 256 + threadIdx.x;      // < N1+N2+N3 = 1,179,648
  const float* s;
  if (i < N1)            s = x  + (size_t)i * 8;
  else if (i < N1 + N2)  s = wq + (size_t)(i - N1) * 8;
  else                   s = wp + (size_t)(i - N1 - N2) * 8;
  float4 a = ((const float4*)s)[0], b = ((const float4*)s)[1];
  half8 h;
  h[0] = (half_t)a.x; h[1] = (half_t)a.y; h[2] = (half_t)a.z; h[3] = (half_t)a.w;
  h[4] = (half_t)b.x; h[5] = (half_t)b.y; h[6] = (half_t)b.z; h[7] = (half_t)b.w;
  ((half8*)d)[i] = h;
}

// ---------------------------------------------------------------------------
// RoPE cos/sin table: tab[p][j] = (cos, sin)(p * 10000^(-2j/64)), p<2048, j<32
// ---------------------------------------------------------------------------
__global__ __launch_bounds__(256) void rope_tab_kernel(float2* __restrict__ tab) {
  int i = blockIdx.x * 256 + threadIdx.x;       // 65536 entries
  int p = i >> 5, j = i & 31;
  float ang = (float)p * __powf(10000.0f, -(float)(2 * j) * (1.0f / 64.0f));
  float sv, cv;
  __sincosf(ang, &sv, &cv);
  tab[i] = make_float2(cv, sv);
}

// ---------------------------------------------------------------------------
// Kernel 1: qkv = x @ W_qkv^T  (fp16 MFMA, 128x128 tile, BK=32, 4 waves)
// Fused epilogue: RoPE via precomputed table (+ q scale incl. log2e)
// -> Qh/Kh fp16 (B,H,N,D); V -> LDS transpose -> Vt fp16 (B,H,D,N).
// ---------------------------------------------------------------------------
__global__ __launch_bounds__(256) void qkv_mfma_kernel(
    const half_t* __restrict__ Ah,   // (16384, 512)
    const half_t* __restrict__ Bh,   // (1536, 512)
    const int*   __restrict__ ncp,
    const float2* __restrict__ tab,  // (2048, 32) cos/sin
    half_t* __restrict__ Qh, half_t* __restrict__ Kh, half_t* __restrict__ Vt)
{
  __shared__ union {
    struct { half_t A[128 * 32]; half_t B[128 * 32]; } s;   // 16 KB
    half_t T[4][64 * 68];                                   // 34.8 KB (V epilogue)
  } sm;

  const int tid  = threadIdx.x;
  const int wave = tid >> 6, lane = tid & 63;
  const int L15  = lane & 15, quad = lane >> 4;
  const int wm = (wave & 1) * 64, wn = (wave >> 1) * 64;
  const int m0 = blockIdx.x * 128;
  const int f0 = blockIdx.y * 128;

  const int srow = lane >> 2;            // 0..15
  const int scolh = (lane & 3) * 8;      // half offset within row
  const half_t* Ag = Ah + (size_t)(m0 + wave * 16 + srow) * CC + scolh;
  const half_t* Bg = Bh + (size_t)(f0 + wave * 16 + srow) * CC + scolh;
  half_t* Al = &sm.s.A[(wave * 16) * 32];
  half_t* Bl = &sm.s.B[(wave * 16) * 32];

  floatx4 acc[4][4];
#pragma unroll
  for (int i = 0; i < 4; ++i)
#pragma unroll
    for (int j = 0; j < 4; ++j) acc[i][j] = (floatx4){0.f, 0.f, 0.f, 0.f};

  for (int k0 = 0; k0 < CC; k0 += 32) {
    __syncthreads();
    gld16(Ag + k0,            Al);
    gld16(Ag + k0 + 64 * CC,  Al + 64 * 32);
    gld16(Bg + k0,            Bl);
    gld16(Bg + k0 + 64 * CC,  Bl + 64 * 32);
    __syncthreads();
    half8 af[4], bf[4];
#pragma unroll
    for (int mi = 0; mi < 4; ++mi)
      af[mi] = *(const half8*)&sm.s.A[(wm + mi * 16 + L15) * 32 + quad * 8];
#pragma unroll
    for (int ni = 0; ni < 4; ++ni)
      bf[ni] = *(const half8*)&sm.s.B[(wn + ni * 16 + L15) * 32 + quad * 8];
#pragma unroll
    for (int mi = 0; mi < 4; ++mi)
#pragma unroll
      for (int ni = 0; ni < 4; ++ni)
        acc[mi][ni] = __builtin_amdgcn_mfma_f32_16x16x32_f16(af[mi], bf[ni], acc[mi][ni], 0, 0, 0);
  }

  const int which = f0 >> 9;         // block-uniform (128 | 512)
  const int b     = m0 >> 11;        // block-uniform
  const int n_base = (m0 & 2047) + wm;

  if (which < 2) {
    const int nc = *ncp;
    half_t* dst = which ? Kh : Qh;
    const float qscale = which ? 1.0f : (0.125f * LOG2E);
#pragma unroll
    for (int ni = 0; ni < 4; ++ni) {
      const int f = f0 + wn + ni * 16 + L15;
      const int h = (f >> 6) & 7;
      const int d = f & 63;
      const float sgn = (d & 1) ? 1.0f : -1.0f;
      const float2* tj = tab + (d >> 1);
#pragma unroll
      for (int mi = 0; mi < 4; ++mi)
#pragma unroll
        for (int r = 0; r < 4; ++r) {
          const int n = n_base + mi * 16 + quad * 4 + r;
          float v = acc[mi][ni][r];
          float p = __shfl_xor(v, 1, 64);   // RoPE partner (d ^ 1)
          if (n >= nc) {
            float2 cs = tj[(size_t)(n - nc) * 32];
            v = v * cs.x + sgn * p * cs.y;
          }
          dst[(((size_t)(b * HH + h) * NN + n) << 6) + d] = (half_t)(v * qscale);
        }
    }
  } else {
    // V: per-wave 64x64 transpose through LDS -> (B,H,D,N)
    __syncthreads();   // all waves done reading sm.s (union overwrite)
#pragma unroll
    for (int ni = 0; ni < 4; ++ni)
#pragma unroll
      for (int mi = 0; mi < 4; ++mi)
#pragma unroll
        for (int r = 0; r < 4; ++r)
          sm.T[wave][(ni * 16 + L15) * 68 + mi * 16 + quad * 4 + r] = (half_t)acc[mi][ni][r];
    __syncthreads();
    const int h = ((f0 + wn) >> 6) & 7;
    const size_t gbase = ((size_t)(b * HH + h) * DD + lane) * NN + n_base;
#pragma unroll
    for (int c = 0; c < 8; ++c)
      *(half8*)(Vt + gbase + c * 8) = *(const half8*)&sm.T[wave][lane * 68 + c * 8];
  }
}

// ---------------------------------------------------------------------------
// Kernel 2: flash attention, swapped-operand 32x32x16 MFMA.
// EXACT restore of the round-2-benched body (115 us, 64 VGPR, no spill):
// counted-vmcnt double-buffer pipeline, shfl_xor P-routing, raw-mask fmaf.
// ---------------------------------------------------------------------------
__global__ __launch_bounds__(256, 4) void flash_mfma_kernel(
    const half_t* __restrict__ Qh,   // (B,H,N,D)  (q pre-scaled by 0.125*log2e)
    const half_t* __restrict__ Kh,   // (B,H,N,D)
    const half_t* __restrict__ Vt,   // (B,H,D,N)
    const float*  __restrict__ mask, // (B,N)
    half_t* __restrict__ O)          // (B,N,C) fp16
{
  __shared__ half_t KV[2][2][64 * 64];   // [buf][K|V][row*64 + e]  32 KB

  const int tid  = threadIdx.x;
  const int wave = tid >> 6;            // 0..3
  const int lane = tid & 63;
  const int l31  = lane & 31;
  const int hi   = lane >> 5;           // 0/1
  const int l7   = lane & 7;

  // XCD-aware decode: blocks with the same head share blockIdx%8 (same XCD)
  const int bid  = blockIdx.x;          // 0..1023
  const int xcd  = bid & 7;
  const int slot = bid >> 3;            // 0..127
  const int qt   = slot & 15;           // 16 q-tiles of 128 rows
  const int head = (slot >> 4) * 8 + xcd;   // 0..63
  const int b    = head >> 3;
  const int h    = head & 7;

  const half_t* Kt_base = Kh + ((((size_t)b * HH + h) * NN) << 6);
  const half_t* Vt_base = Vt + (((size_t)b * HH + h) * DD) * NN;

  // Q B-fragments: q = qt*128 + wave*32 + l31 ; k-dim elem = kd*16 + hi*8 + j
  half8 qf[4];
  {
    const half_t* Qp =
        Qh + ((((size_t)b * HH + h) * NN + qt * 128 + wave * 32 + l31) << 6) + hi * 8;
#pragma unroll
    for (int kd = 0; kd < 4; ++kd) qf[kd] = *(const half8*)(Qp + kd * 16);
  }

  // staging source pointers, pre-swizzled: LDS linear slot sl of row holds
  // source 16B-group (sl ^ (row&7)); row&7 == lane>>3 here.
  const int r8  = lane >> 3;                 // 0..7
  const int dof = ((l7 ^ r8) << 3);          // halfs
  const half_t* kbase = Kt_base + (((size_t)(wave * 16 + r8)) << 6) + dof;
  const half_t* vbase = Vt_base + (size_t)(wave * 16 + r8) * NN + dof;

  // LDS read addrs (bytes), buffer/t offsets added as immediates at use.
  int adK[4], adV[4];
#pragma unroll
  for (int c = 0; c < 4; ++c) {
    adK[c] = l31 * 128 + ((((c << 1) | hi) ^ l7) << 4);
    adV[c] = 8192 + l31 * 128 + ((((c << 1) | hi) ^ l7) << 4);
  }
  const char* L = (const char*)KV;

  floatx16 acc[2];
#pragma unroll
  for (int dt = 0; dt < 2; ++dt)
#pragma unroll
    for (int r = 0; r < 16; ++r) acc[dt][r] = 0.f;
  float l_part = 0.f;

  const float* mkb = mask + (size_t)b * NN + hi * 4;

#define STAGE(c, koff, voff)                                                  \
  {                                                                           \
    gld16(kbase + (koff),          &KV[c][0][wave * 1024]);                   \
    gld16(kbase + (koff) + 512,    &KV[c][0][wave * 1024 + 512]);             \
    gld16(vbase + (voff),          &KV[c][1][wave * 1024]);                   \
    gld16(vbase + (voff) + 8 * NN, &KV[c][1][wave * 1024 + 512]);             \
  }

#define COMPUTE(c, moff)                                                      \
  _Pragma("unroll")                                                           \
  for (int t = 0; t < 2; ++t) {                                               \
    fx4 m4[4];                                                                \
    _Pragma("unroll")                                                         \
    for (int r2 = 0; r2 < 4; ++r2)                                            \
      m4[r2] = *(const fx4*)(mkb + (moff) + t * 32 + r2 * 8);                 \
    floatx16 S;                                                               \
    _Pragma("unroll") for (int r = 0; r < 16; ++r) S[r] = 0.f;                \
    __builtin_amdgcn_s_setprio(1);                                            \
    _Pragma("unroll")                                                         \
    for (int kd = 0; kd < 4; ++kd) {                                          \
      half8 kf = *(const half8*)(L + (adK[kd] + (c) * 16384 + t * 4096));     \
      S = __builtin_amdgcn_mfma_f32_32x32x16_f16(kf, qf[kd], S, 0, 0, 0);     \
    }                                                                         \
    __builtin_amdgcn_s_setprio(0);                                            \
    _Pragma("unroll")                                                         \
    for (int r = 0; r < 16; ++r) {                                            \
      float p = __builtin_amdgcn_exp2f(fmaf(m4[r >> 2][r & 3], LOG2E, S[r] - EXP2_OFF)); \
      l_part += p;                                                            \
      S[r] = p;                                                               \
    }                                                                         \
    unsigned W[4][2];                                                         \
    _Pragma("unroll")                                                         \
    for (int r2 = 0; r2 < 4; ++r2)                                            \
      _Pragma("unroll")                                                       \
      for (int u = 0; u < 2; ++u) {                                           \
        union { half_t hh[2]; unsigned w; } pk;                               \
        pk.hh[0] = (half_t)S[r2 * 4 + 2 * u];                                 \
        pk.hh[1] = (half_t)S[r2 * 4 + 2 * u + 1];                             \
        W[r2][u] = pk.w;                                                      \
      }                                                                       \
    _Pragma("unroll")                                                         \
    for (int ksl = 0; ksl < 2; ++ksl) {                                       \
      unsigned A0 = W[2 * ksl][0],     A1 = W[2 * ksl][1];                    \
      unsigned B0 = W[2 * ksl + 1][0], B1 = W[2 * ksl + 1][1];                \
      unsigned pA0 = __shfl_xor(A0, 32, 64), pA1 = __shfl_xor(A1, 32, 64);    \
      unsigned pB0 = __shfl_xor(B0, 32, 64), pB1 = __shfl_xor(B1, 32, 64);    \
      union { unsigned u4[4]; half8 v; } pw;                                  \
      pw.u4[0] = hi ? pB0 : A0;                                               \
      pw.u4[1] = hi ? pB1 : A1;                                               \
      pw.u4[2] = hi ? B0 : pA0;                                               \
      pw.u4[3] = hi ? B1 : pA1;                                               \
      const int ks = t * 2 + ksl;                                             \
      __builtin_amdgcn_s_setprio(1);                                          \
      _Pragma("unroll")                                                       \
      for (int dt = 0; dt < 2; ++dt) {                                        \
        half8 vf = *(const half8*)(L + (adV[ks] + (c) * 16384 + dt * 4096));  \
        acc[dt] = __builtin_amdgcn_mfma_f32_32x32x16_f16(pw.v, vf, acc[dt], 0, 0, 0); \
      }                                                                       \
      __builtin_amdgcn_s_setprio(0);                                          \
    }                                                                         \
  }

  // prologue: stage tiles 0 and 1; wait only for tile 0; barrier.
  STAGE(0, 0, 0)
  STAGE(1, 4096, 64)
  asm volatile("s_waitcnt vmcnt(4)");
  __builtin_amdgcn_s_barrier();
  __builtin_amdgcn_sched_barrier(0);
  kbase += 8192; vbase += 128;   // now pointing at tile 2

#pragma unroll 1
  for (int kt2 = 0; kt2 < 15; ++kt2) {   // tiles 0..29; stages tiles 2..31
    COMPUTE(0, 0)
    __builtin_amdgcn_sched_barrier(0);
    __builtin_amdgcn_s_barrier();        // all waves done reading buf 0
    STAGE(0, 0, 0)                       // tile 2*kt2+2 -> buf 0
    asm volatile("s_waitcnt vmcnt(4)");  // stage(2*kt2+1) landed; fresh 4 in flight
    __builtin_amdgcn_s_barrier();
    __builtin_amdgcn_sched_barrier(0);

    COMPUTE(1, 64)
    __builtin_amdgcn_sched_barrier(0);
    __builtin_amdgcn_s_barrier();        // all waves done reading buf 1
    STAGE(1, 4096, 64)                   // tile 2*kt2+3 -> buf 1
    asm volatile("s_waitcnt vmcnt(4)");  // stage(2*kt2+2) landed
    __builtin_amdgcn_s_barrier();
    __builtin_amdgcn_sched_barrier(0);

    kbase += 8192; vbase += 128;
    mkb += 128;
  }

  // tail: tiles 30 (buf 0) and 31 (buf 1); no more staging
  COMPUTE(0, 0)
  asm volatile("s_waitcnt vmcnt(0)");    // stage(31) fully landed
  __builtin_amdgcn_s_barrier();
  __builtin_amdgcn_sched_barrier(0);
  COMPUTE(1, 64)

#undef STAGE
#undef COMPUTE

  // l: sum the two lane-halves (each lane holds partials for q = lane&31)
  l_part += __shfl_xor(l_part, 32, 64);

  const size_t orow = (size_t)b * NN + qt * 128 + wave * 32;
#pragma unroll
  for (int r = 0; r < 16; ++r) {
    const int ql  = (r & 3) + 8 * (r >> 2) + 4 * hi;   // 0..31
    const float iv = 1.0f / __shfl(l_part, ql, 64);
    const size_t ro = ((orow + ql) << 9) + (h << 6) + l31;
    O[ro]      = (half_t)(acc[0][r] * iv);
    O[ro + 32] = (half_t)(acc[1][r] * iv);
  }
}

// ---------------------------------------------------------------------------
// Kernel 3: out = O @ W_proj^T + b_proj  (fp16 MFMA, fp32 out)
// This round: 128x64 tile (grid 1024 = 4 blocks/CU, 16 waves/CU vs 8).
// ---------------------------------------------------------------------------
__global__ __launch_bounds__(256) void proj_mfma_kernel(
    const half_t* __restrict__ Ah,   // (16384, 512) fp16
    const half_t* __restrict__ Bh,   // (512, 512) fp16
    const float* __restrict__ bias,  // (512,)
    float* __restrict__ out)         // (16384, 512)
{
  __shared__ half_t As[128 * 32];   // 8 KB
  __shared__ half_t Bs[64 * 32];    // 4 KB

  const int tid  = threadIdx.x;
  const int wave = tid >> 6, lane = tid & 63;
  const int L15  = lane & 15, quad = lane >> 4;
  const int wm = (wave & 1) * 64, wn = (wave >> 1) * 32;
  const int m0 = blockIdx.x * 128;
  const int f0 = blockIdx.y * 64;

  const int srow = lane >> 2;
  const int scolh = (lane & 3) * 8;
  const half_t* Ag = Ah + (size_t)(m0 + wave * 16 + srow) * CC + scolh;
  const half_t* Bg = Bh + (size_t)(f0 + wave * 16 + srow) * CC + scolh;
  half_t* Al = &As[(wave * 16) * 32];
  half_t* Bl = &Bs[(wave * 16) * 32];

  floatx4 acc[4][2];
#pragma unroll
  for (int i = 0; i < 4; ++i)
#pragma unroll
    for (int j = 0; j < 2; ++j) acc[i][j] = (floatx4){0.f, 0.f, 0.f, 0.f};

  for (int k0 = 0; k0 < CC; k0 += 32) {
    __syncthreads();
    gld16(Ag + k0,           Al);
    gld16(Ag + k0 + 64 * CC, Al + 64 * 32);
    gld16(Bg + k0,           Bl);
    __syncthreads();
    half8 af[4], bf[2];
#pragma unroll
    for (int mi = 0; mi < 4; ++mi)
      af[mi] = *(const half8*)&As[(wm + mi * 16 + L15) * 32 + quad * 8];
#pragma unroll
    for (int ni = 0; ni < 2; ++ni)
      bf[ni] = *(const half8*)&Bs[(wn + ni * 16 + L15) * 32 + quad * 8];
#pragma unroll
    for (int mi = 0; mi < 4; ++mi)
#pragma unroll
      for (int ni = 0; ni < 2; ++ni)
        acc[mi][ni] = __builtin_amdgcn_mfma_f32_16x16x32_f16(af[mi], bf[ni], acc[mi][ni], 0, 0, 0);
  }

#pragma unroll
  for (int ni = 0; ni < 2; ++ni) {
    const int f = f0 + wn + ni * 16 + L15;
    const float bv = bias[f];
#pragma unroll
    for (int mi = 0; mi < 4; ++mi)
#pragma unroll
      for (int r = 0; r < 4; ++r)
        out[(size_t)(m0 + wm + mi * 16 + quad * 4 + r) * CC + f] = acc[mi][ni][r] + bv;
  }
}

// ---------------------------------------------------------------------------
extern "C" void kernel_launch(void* const* d_in, const int* in_sizes, int n_in,
                              void* d_out, int out_size, void* d_ws, size_t ws_size,
                              hipStream_t stream) {
  const float* x     = (const float*)d_in[0];
  const float* mask  = (const float*)d_in[1];
  const float* Wqkv  = (const float*)d_in[2];
  const float* Wproj = (const float*)d_in[3];
  const float* bproj = (const float*)d_in[4];
  const int*   ncp   = (const int*)d_in[5];
  float* out = (float*)d_out;

  const size_t per = (size_t)BB * HH * NN * DD;   // 8,388,608
  half_t* xh  = (half_t*)d_ws;
  half_t* Wqh = xh + (size_t)MM * CC;
  half_t* Wph = Wqh + (size_t)FF * CC;
  half_t* Qh  = Wph + (size_t)CC * CC;
  half_t* Kh  = Qh + per;
  half_t* Vt  = Kh + per;
  half_t* Oh  = Vt + per;
  float2* tab = (float2*)(Oh + per);              // 2048*32*8B = 512 KB

  rope_tab_kernel<<<dim3(NN * 32 / 256), 256, 0, stream>>>(tab);
  cvt_all_kernel<<<dim3((N1 + N2 + N3) / 256), 256, 0, stream>>>(x, Wqkv, Wproj, xh);

  qkv_mfma_kernel<<<dim3(MM / 128, FF / 128), 256, 0, stream>>>(xh, Wqh, ncp, tab, Qh, Kh, Vt);
  flash_mfma_kernel<<<dim3(BB * HH * (NN / 128)), 256, 0, stream>>>(Qh, Kh, Vt, mask, Oh);
  proj_mfma_kernel<<<dim3(MM / 128, CC / 64), 256, 0, stream>>>(Oh, Wph, bproj, out);
}

// Round 7
// 276.506 us; speedup vs baseline: 3.1620x; 1.2198x over previous
//
#include <hip/hip_runtime.h>
#include <cmath>

#define BB 8
#define NN 2048
#define CC 512
#define HH 8
#define DD 64
#define FF 1536
#define MM (BB*NN)   // 16384

typedef _Float16 half_t;
typedef __attribute__((ext_vector_type(8))) _Float16 half8;
typedef __attribute__((ext_vector_type(4))) _Float16 half4;
typedef __attribute__((ext_vector_type(4))) float floatx4;
typedef __attribute__((ext_vector_type(16))) float floatx16;
typedef __attribute__((ext_vector_type(4))) float fx4;

#define LOG2E 1.44269504088896f
#define EXP2_OFF 4.3280851f   // 3 * log2(e)

// async global->LDS, 16 B per lane; LDS dest must be wave-uniform base (+lane*16)
typedef const __attribute__((address_space(1))) unsigned int* gas_ptr;
typedef __attribute__((address_space(3))) unsigned int* las_ptr;
__device__ __forceinline__ void gld16(const half_t* g, half_t* l) {
  __builtin_amdgcn_global_load_lds((gas_ptr)g, (las_ptr)l, 16, 0, 0);
}

// ---------------------------------------------------------------------------
// fused fp32 -> fp16 convert for x, W_qkv, W_proj (dest regions contiguous)
// ---------------------------------------------------------------------------
#define N1 (MM * CC / 8)          // 1,048,576 half8 groups (x)
#define N2 (FF * CC / 8)          // 98,304 (W_qkv)
#define N3 (CC * CC / 8)          // 32,768 (W_proj)
__global__ __launch_bounds__(256) void cvt_all_kernel(
    const float* __restrict__ x, const float* __restrict__ wq,
    const float* __restrict__ wp, half_t* __restrict__ d) {
  int i = blockIdx.x * 256 + threadIdx.x;      // < N1+N2+N3 = 1,179,648
  const float* s;
  if (i < N1)            s = x  + (size_t)i * 8;
  else if (i < N1 + N2)  s = wq + (size_t)(i - N1) * 8;
  else                   s = wp + (size_t)(i - N1 - N2) * 8;
  float4 a = ((const float4*)s)[0], b = ((const float4*)s)[1];
  half8 h;
  h[0] = (half_t)a.x; h[1] = (half_t)a.y; h[2] = (half_t)a.z; h[3] = (half_t)a.w;
  h[4] = (half_t)b.x; h[5] = (half_t)b.y; h[6] = (half_t)b.z; h[7] = (half_t)b.w;
  ((half8*)d)[i] = h;
}

// ---------------------------------------------------------------------------
// RoPE cos/sin table: tab[p][j] = (cos, sin)(p * 10000^(-2j/64)), p<2048, j<32
// ---------------------------------------------------------------------------
__global__ __launch_bounds__(256) void rope_tab_kernel(float2* __restrict__ tab) {
  int i = blockIdx.x * 256 + threadIdx.x;       // 65536 entries
  int p = i >> 5, j = i & 31;
  float ang = (float)p * __powf(10000.0f, -(float)(2 * j) * (1.0f / 64.0f));
  float sv, cv;
  __sincosf(ang, &sv, &cv);
  tab[i] = make_float2(cv, sv);
}

// ---------------------------------------------------------------------------
// Kernel 1: qkv = x @ W_qkv^T  (fp16 MFMA, 128x128 tile, BK=32, 4 waves)
// SWAPPED-operand MFMA: acc = mfma(bf, af) -> col(L15)=n, row(quad*4+r)=f.
// Epilogue per lane: one n-row per mi, RoPE pairs adjacent in-register
// (no shfl), 16B contiguous tab loads, half4 stores (4x wider than before).
// V -> LDS transpose (T[d][n]) -> Vt fp16 (B,H,D,N).
// ---------------------------------------------------------------------------
__global__ __launch_bounds__(256) void qkv_mfma_kernel(
    const half_t* __restrict__ Ah,   // (16384, 512)
    const half_t* __restrict__ Bh,   // (1536, 512)
    const int*   __restrict__ ncp,
    const float2* __restrict__ tab,  // (2048, 32) cos/sin
    half_t* __restrict__ Qh, half_t* __restrict__ Kh, half_t* __restrict__ Vt)
{
  __shared__ union {
    struct { half_t A[128 * 32]; half_t B[128 * 32]; } s;   // 16 KB
    half_t T[4][64 * 68];                                   // 34.8 KB (V epilogue)
  } sm;

  const int tid  = threadIdx.x;
  const int wave = tid >> 6, lane = tid & 63;
  const int L15  = lane & 15, quad = lane >> 4;
  const int wm = (wave & 1) * 64, wn = (wave >> 1) * 64;
  const int m0 = blockIdx.x * 128;
  const int f0 = blockIdx.y * 128;

  const int srow = lane >> 2;            // 0..15
  const int scolh = (lane & 3) * 8;      // half offset within row
  const half_t* Ag = Ah + (size_t)(m0 + wave * 16 + srow) * CC + scolh;
  const half_t* Bg = Bh + (size_t)(f0 + wave * 16 + srow) * CC + scolh;
  half_t* Al = &sm.s.A[(wave * 16) * 32];
  half_t* Bl = &sm.s.B[(wave * 16) * 32];

  floatx4 acc[4][4];
#pragma unroll
  for (int i = 0; i < 4; ++i)
#pragma unroll
    for (int j = 0; j < 4; ++j) acc[i][j] = (floatx4){0.f, 0.f, 0.f, 0.f};

  for (int k0 = 0; k0 < CC; k0 += 32) {
    __syncthreads();
    gld16(Ag + k0,            Al);
    gld16(Ag + k0 + 64 * CC,  Al + 64 * 32);
    gld16(Bg + k0,            Bl);
    gld16(Bg + k0 + 64 * CC,  Bl + 64 * 32);
    __syncthreads();
    half8 af[4], bf[4];
#pragma unroll
    for (int mi = 0; mi < 4; ++mi)
      af[mi] = *(const half8*)&sm.s.A[(wm + mi * 16 + L15) * 32 + quad * 8];
#pragma unroll
    for (int ni = 0; ni < 4; ++ni)
      bf[ni] = *(const half8*)&sm.s.B[(wn + ni * 16 + L15) * 32 + quad * 8];
#pragma unroll
    for (int mi = 0; mi < 4; ++mi)
#pragma unroll
      for (int ni = 0; ni < 4; ++ni)
        acc[mi][ni] = __builtin_amdgcn_mfma_f32_16x16x32_f16(bf[ni], af[mi], acc[mi][ni], 0, 0, 0);
  }
  // acc[mi][ni][r] = out[n = m0+wm+mi*16+L15][f = f0+wn+ni*16+quad*4+r]

  const int which = f0 >> 9;         // block-uniform (128 | 512)
  const int b     = m0 >> 11;        // block-uniform
  const int n_base = (m0 & 2047) + wm;
  const int h     = ((f0 + wn) >> 6) & 7;   // wave-uniform head

  if (which < 2) {
    const int nc = *ncp;
    half_t* dst = which ? Kh : Qh;
    const float qscale = which ? 1.0f : (0.125f * LOG2E);
    const float* tabf = (const float*)tab;
#pragma unroll
    for (int mi = 0; mi < 4; ++mi) {
      const int n = n_base + mi * 16 + L15;
      const int p = n - nc;
      const size_t rbase = (((size_t)(b * HH + h) * NN + n) << 6) + quad * 4;
#pragma unroll
      for (int ni = 0; ni < 4; ++ni) {
        float o0 = acc[mi][ni][0], o1 = acc[mi][ni][1];
        float o2 = acc[mi][ni][2], o3 = acc[mi][ni][3];
        if (p >= 0) {
          // d = ni*16 + quad*4 + r ; j = d>>1 = ni*8 + quad*2 + (r>>1)
          const fx4 c4 = *(const fx4*)(tabf + p * 64 + ni * 16 + quad * 4);
          const float e0 = o0, e1 = o1, e2 = o2, e3 = o3;
          o0 = e0 * c4[0] - e1 * c4[1];   // even d: cos*v_e - sin*v_o
          o1 = e0 * c4[1] + e1 * c4[0];   // odd  d: sin*v_e + cos*v_o
          o2 = e2 * c4[2] - e3 * c4[3];
          o3 = e2 * c4[3] + e3 * c4[2];
        }
        half4 hv;
        hv[0] = (half_t)(o0 * qscale); hv[1] = (half_t)(o1 * qscale);
        hv[2] = (half_t)(o2 * qscale); hv[3] = (half_t)(o3 * qscale);
        *(half4*)(dst + rbase + ni * 16) = hv;
      }
    }
  } else {
    // V: per-wave 64x64 transpose through LDS -> (B,H,D,N)
    __syncthreads();   // all waves done reading sm.s (union overwrite)
#pragma unroll
    for (int ni = 0; ni < 4; ++ni)
#pragma unroll
      for (int mi = 0; mi < 4; ++mi)
#pragma unroll
        for (int r = 0; r < 4; ++r)
          sm.T[wave][(ni * 16 + quad * 4 + r) * 68 + mi * 16 + L15] = (half_t)acc[mi][ni][r];
    __syncthreads();
    const size_t gbase = ((size_t)(b * HH + h) * DD + lane) * NN + n_base;
#pragma unroll
    for (int c = 0; c < 8; ++c)
      *(half8*)(Vt + gbase + c * 8) = *(const half8*)&sm.T[wave][lane * 68 + c * 8];
  }
}

// ---------------------------------------------------------------------------
// Kernel 2: flash attention, swapped-operand 32x32x16 MFMA.
// EXACT round-2-benched body (115 us, 64 VGPR, no spill): counted-vmcnt
// double-buffer pipeline, shfl_xor P-routing, raw-mask fmaf.  [unchanged]
// ---------------------------------------------------------------------------
__global__ __launch_bounds__(256, 4) void flash_mfma_kernel(
    const half_t* __restrict__ Qh,   // (B,H,N,D)  (q pre-scaled by 0.125*log2e)
    const half_t* __restrict__ Kh,   // (B,H,N,D)
    const half_t* __restrict__ Vt,   // (B,H,D,N)
    const float*  __restrict__ mask, // (B,N)
    half_t* __restrict__ O)          // (B,N,C) fp16
{
  __shared__ half_t KV[2][2][64 * 64];   // [buf][K|V][row*64 + e]  32 KB

  const int tid  = threadIdx.x;
  const int wave = tid >> 6;            // 0..3
  const int lane = tid & 63;
  const int l31  = lane & 31;
  const int hi   = lane >> 5;           // 0/1
  const int l7   = lane & 7;

  // XCD-aware decode: blocks with the same head share blockIdx%8 (same XCD)
  const int bid  = blockIdx.x;          // 0..1023
  const int xcd  = bid & 7;
  const int slot = bid >> 3;            // 0..127
  const int qt   = slot & 15;           // 16 q-tiles of 128 rows
  const int head = (slot >> 4) * 8 + xcd;   // 0..63
  const int b    = head >> 3;
  const int h    = head & 7;

  const half_t* Kt_base = Kh + ((((size_t)b * HH + h) * NN) << 6);
  const half_t* Vt_base = Vt + (((size_t)b * HH + h) * DD) * NN;

  // Q B-fragments: q = qt*128 + wave*32 + l31 ; k-dim elem = kd*16 + hi*8 + j
  half8 qf[4];
  {
    const half_t* Qp =
        Qh + ((((size_t)b * HH + h) * NN + qt * 128 + wave * 32 + l31) << 6) + hi * 8;
#pragma unroll
    for (int kd = 0; kd < 4; ++kd) qf[kd] = *(const half8*)(Qp + kd * 16);
  }

  // staging source pointers, pre-swizzled: LDS linear slot sl of row holds
  // source 16B-group (sl ^ (row&7)); row&7 == lane>>3 here.
  const int r8  = lane >> 3;                 // 0..7
  const int dof = ((l7 ^ r8) << 3);          // halfs
  const half_t* kbase = Kt_base + (((size_t)(wave * 16 + r8)) << 6) + dof;
  const half_t* vbase = Vt_base + (size_t)(wave * 16 + r8) * NN + dof;

  // LDS read addrs (bytes), buffer/t offsets added as immediates at use.
  int adK[4], adV[4];
#pragma unroll
  for (int c = 0; c < 4; ++c) {
    adK[c] = l31 * 128 + ((((c << 1) | hi) ^ l7) << 4);
    adV[c] = 8192 + l31 * 128 + ((((c << 1) | hi) ^ l7) << 4);
  }
  const char* L = (const char*)KV;

  floatx16 acc[2];
#pragma unroll
  for (int dt = 0; dt < 2; ++dt)
#pragma unroll
    for (int r = 0; r < 16; ++r) acc[dt][r] = 0.f;
  float l_part = 0.f;

  const float* mkb = mask + (size_t)b * NN + hi * 4;

#define STAGE(c, koff, voff)                                                  \
  {                                                                           \
    gld16(kbase + (koff),          &KV[c][0][wave * 1024]);                   \
    gld16(kbase + (koff) + 512,    &KV[c][0][wave * 1024 + 512]);             \
    gld16(vbase + (voff),          &KV[c][1][wave * 1024]);                   \
    gld16(vbase + (voff) + 8 * NN, &KV[c][1][wave * 1024 + 512]);             \
  }

#define COMPUTE(c, moff)                                                      \
  _Pragma("unroll")                                                           \
  for (int t = 0; t < 2; ++t) {                                               \
    fx4 m4[4];                                                                \
    _Pragma("unroll")                                                         \
    for (int r2 = 0; r2 < 4; ++r2)                                            \
      m4[r2] = *(const fx4*)(mkb + (moff) + t * 32 + r2 * 8);                 \
    floatx16 S;                                                               \
    _Pragma("unroll") for (int r = 0; r < 16; ++r) S[r] = 0.f;                \
    __builtin_amdgcn_s_setprio(1);                                            \
    _Pragma("unroll")                                                         \
    for (int kd = 0; kd < 4; ++kd) {                                          \
      half8 kf = *(const half8*)(L + (adK[kd] + (c) * 16384 + t * 4096));     \
      S = __builtin_amdgcn_mfma_f32_32x32x16_f16(kf, qf[kd], S, 0, 0, 0);     \
    }                                                                         \
    __builtin_amdgcn_s_setprio(0);                                            \
    _Pragma("unroll")                                                         \
    for (int r = 0; r < 16; ++r) {                                            \
      float p = __builtin_amdgcn_exp2f(fmaf(m4[r >> 2][r & 3], LOG2E, S[r] - EXP2_OFF)); \
      l_part += p;                                                            \
      S[r] = p;                                                               \
    }                                                                         \
    unsigned W[4][2];                                                         \
    _Pragma("unroll")                                                         \
    for (int r2 = 0; r2 < 4; ++r2)                                            \
      _Pragma("unroll")                                                       \
      for (int u = 0; u < 2; ++u) {                                           \
        union { half_t hh[2]; unsigned w; } pk;                               \
        pk.hh[0] = (half_t)S[r2 * 4 + 2 * u];                                 \
        pk.hh[1] = (half_t)S[r2 * 4 + 2 * u + 1];                             \
        W[r2][u] = pk.w;                                                      \
      }                                                                       \
    _Pragma("unroll")                                                         \
    for (int ksl = 0; ksl < 2; ++ksl) {                                       \
      unsigned A0 = W[2 * ksl][0],     A1 = W[2 * ksl][1];                    \
      unsigned B0 = W[2 * ksl + 1][0], B1 = W[2 * ksl + 1][1];                \
      unsigned pA0 = __shfl_xor(A0, 32, 64), pA1 = __shfl_xor(A1, 32, 64);    \
      unsigned pB0 = __shfl_xor(B0, 32, 64), pB1 = __shfl_xor(B1, 32, 64);    \
      union { unsigned u4[4]; half8 v; } pw;                                  \
      pw.u4[0] = hi ? pB0 : A0;                                               \
      pw.u4[1] = hi ? pB1 : A1;                                               \
      pw.u4[2] = hi ? B0 : pA0;                                               \
      pw.u4[3] = hi ? B1 : pA1;                                               \
      const int ks = t * 2 + ksl;                                             \
      __builtin_amdgcn_s_setprio(1);                                          \
      _Pragma("unroll")                                                       \
      for (int dt = 0; dt < 2; ++dt) {                                        \
        half8 vf = *(const half8*)(L + (adV[ks] + (c) * 16384 + dt * 4096));  \
        acc[dt] = __builtin_amdgcn_mfma_f32_32x32x16_f16(pw.v, vf, acc[dt], 0, 0, 0); \
      }                                                                       \
      __builtin_amdgcn_s_setprio(0);                                          \
    }                                                                         \
  }

  // prologue: stage tiles 0 and 1; wait only for tile 0; barrier.
  STAGE(0, 0, 0)
  STAGE(1, 4096, 64)
  asm volatile("s_waitcnt vmcnt(4)");
  __builtin_amdgcn_s_barrier();
  __builtin_amdgcn_sched_barrier(0);
  kbase += 8192; vbase += 128;   // now pointing at tile 2

#pragma unroll 1
  for (int kt2 = 0; kt2 < 15; ++kt2) {   // tiles 0..29; stages tiles 2..31
    COMPUTE(0, 0)
    __builtin_amdgcn_sched_barrier(0);
    __builtin_amdgcn_s_barrier();        // all waves done reading buf 0
    STAGE(0, 0, 0)                       // tile 2*kt2+2 -> buf 0
    asm volatile("s_waitcnt vmcnt(4)");  // stage(2*kt2+1) landed; fresh 4 in flight
    __builtin_amdgcn_s_barrier();
    __builtin_amdgcn_sched_barrier(0);

    COMPUTE(1, 64)
    __builtin_amdgcn_sched_barrier(0);
    __builtin_amdgcn_s_barrier();        // all waves done reading buf 1
    STAGE(1, 4096, 64)                   // tile 2*kt2+3 -> buf 1
    asm volatile("s_waitcnt vmcnt(4)");  // stage(2*kt2+2) landed
    __builtin_amdgcn_s_barrier();
    __builtin_amdgcn_sched_barrier(0);

    kbase += 8192; vbase += 128;
    mkb += 128;
  }

  // tail: tiles 30 (buf 0) and 31 (buf 1); no more staging
  COMPUTE(0, 0)
  asm volatile("s_waitcnt vmcnt(0)");    // stage(31) fully landed
  __builtin_amdgcn_s_barrier();
  __builtin_amdgcn_sched_barrier(0);
  COMPUTE(1, 64)

#undef STAGE
#undef COMPUTE

  // l: sum the two lane-halves (each lane holds partials for q = lane&31)
  l_part += __shfl_xor(l_part, 32, 64);

  const size_t orow = (size_t)b * NN + qt * 128 + wave * 32;
#pragma unroll
  for (int r = 0; r < 16; ++r) {
    const int ql  = (r & 3) + 8 * (r >> 2) + 4 * hi;   // 0..31
    const float iv = 1.0f / __shfl(l_part, ql, 64);
    const size_t ro = ((orow + ql) << 9) + (h << 6) + l31;
    O[ro]      = (half_t)(acc[0][r] * iv);
    O[ro + 32] = (half_t)(acc[1][r] * iv);
  }
}

// ---------------------------------------------------------------------------
// Kernel 3: out = O @ W_proj^T + b_proj  (fp16 MFMA, fp32 out)
// 128x64 tile (grid 1024 = 4 blocks/CU, 16 waves/CU).  [unchanged]
// ---------------------------------------------------------------------------
__global__ __launch_bounds__(256) void proj_mfma_kernel(
    const half_t* __restrict__ Ah,   // (16384, 512) fp16
    const half_t* __restrict__ Bh,   // (512, 512) fp16
    const float* __restrict__ bias,  // (512,)
    float* __restrict__ out)         // (16384, 512)
{
  __shared__ half_t As[128 * 32];   // 8 KB
  __shared__ half_t Bs[64 * 32];    // 4 KB

  const int tid  = threadIdx.x;
  const int wave = tid >> 6, lane = tid & 63;
  const int L15  = lane & 15, quad = lane >> 4;
  const int wm = (wave & 1) * 64, wn = (wave >> 1) * 32;
  const int m0 = blockIdx.x * 128;
  const int f0 = blockIdx.y * 64;

  const int srow = lane >> 2;
  const int scolh = (lane & 3) * 8;
  const half_t* Ag = Ah + (size_t)(m0 + wave * 16 + srow) * CC + scolh;
  const half_t* Bg = Bh + (size_t)(f0 + wave * 16 + srow) * CC + scolh;
  half_t* Al = &As[(wave * 16) * 32];
  half_t* Bl = &Bs[(wave * 16) * 32];

  floatx4 acc[4][2];
#pragma unroll
  for (int i = 0; i < 4; ++i)
#pragma unroll
    for (int j = 0; j < 2; ++j) acc[i][j] = (floatx4){0.f, 0.f, 0.f, 0.f};

  for (int k0 = 0; k0 < CC; k0 += 32) {
    __syncthreads();
    gld16(Ag + k0,           Al);
    gld16(Ag + k0 + 64 * CC, Al + 64 * 32);
    gld16(Bg + k0,           Bl);
    __syncthreads();
    half8 af[4], bf[2];
#pragma unroll
    for (int mi = 0; mi < 4; ++mi)
      af[mi] = *(const half8*)&As[(wm + mi * 16 + L15) * 32 + quad * 8];
#pragma unroll
    for (int ni = 0; ni < 2; ++ni)
      bf[ni] = *(const half8*)&Bs[(wn + ni * 16 + L15) * 32 + quad * 8];
#pragma unroll
    for (int mi = 0; mi < 4; ++mi)
#pragma unroll
      for (int ni = 0; ni < 2; ++ni)
        acc[mi][ni] = __builtin_amdgcn_mfma_f32_16x16x32_f16(af[mi], bf[ni], acc[mi][ni], 0, 0, 0);
  }

#pragma unroll
  for (int ni = 0; ni < 2; ++ni) {
    const int f = f0 + wn + ni * 16 + L15;
    const float bv = bias[f];
#pragma unroll
    for (int mi = 0; mi < 4; ++mi)
#pragma unroll
      for (int r = 0; r < 4; ++r)
        out[(size_t)(m0 + wm + mi * 16 + quad * 4 + r) * CC + f] = acc[mi][ni][r] + bv;
  }
}

// ---------------------------------------------------------------------------
extern "C" void kernel_launch(void* const* d_in, const int* in_sizes, int n_in,
                              void* d_out, int out_size, void* d_ws, size_t ws_size,
                              hipStream_t stream) {
  const float* x     = (const float*)d_in[0];
  const float* mask  = (const float*)d_in[1];
  const float* Wqkv  = (const float*)d_in[2];
  const float* Wproj = (const float*)d_in[3];
  const float* bproj = (const float*)d_in[4];
  const int*   ncp   = (const int*)d_in[5];
  float* out = (float*)d_out;

  const size_t per = (size_t)BB * HH * NN * DD;   // 8,388,608
  half_t* xh  = (half_t*)d_ws;
  half_t* Wqh = xh + (size_t)MM * CC;
  half_t* Wph = Wqh + (size_t)FF * CC;
  half_t* Qh  = Wph + (size_t)CC * CC;
  half_t* Kh  = Qh + per;
  half_t* Vt  = Kh + per;
  half_t* Oh  = Vt + per;
  float2* tab = (float2*)(Oh + per);              // 2048*32*8B = 512 KB

  rope_tab_kernel<<<dim3(NN * 32 / 256), 256, 0, stream>>>(tab);
  cvt_all_kernel<<<dim3((N1 + N2 + N3) / 256), 256, 0, stream>>>(x, Wqkv, Wproj, xh);

  qkv_mfma_kernel<<<dim3(MM / 128, FF / 128), 256, 0, stream>>>(xh, Wqh, ncp, tab, Qh, Kh, Vt);
  flash_mfma_kernel<<<dim3(BB * HH * (NN / 128)), 256, 0, stream>>>(Qh, Kh, Vt, mask, Oh);
  proj_mfma_kernel<<<dim3(MM / 128, CC / 64), 256, 0, stream>>>(Oh, Wph, bproj, out);
}

// Round 8
// 256.858 us; speedup vs baseline: 3.4039x; 1.0765x over previous
//
#include <hip/hip_runtime.h>
#include <cmath>

#define BB 8
#define NN 2048
#define CC 512
#define HH 8
#define DD 64
#define FF 1536
#define MM (BB*NN)   // 16384

typedef _Float16 half_t;
typedef __attribute__((ext_vector_type(8))) _Float16 half8;
typedef __attribute__((ext_vector_type(4))) _Float16 half4;
typedef __attribute__((ext_vector_type(4))) float floatx4;
typedef __attribute__((ext_vector_type(16))) float floatx16;
typedef __attribute__((ext_vector_type(4))) float fx4;

#define LOG2E 1.44269504088896f
#define EXP2_OFF 4.3280851f   // 3 * log2(e)

// async global->LDS, 16 B per lane; LDS dest must be wave-uniform base (+lane*16)
typedef const __attribute__((address_space(1))) unsigned int* gas_ptr;
typedef __attribute__((address_space(3))) unsigned int* las_ptr;
__device__ __forceinline__ void gld16(const half_t* g, half_t* l) {
  __builtin_amdgcn_global_load_lds((gas_ptr)g, (las_ptr)l, 16, 0, 0);
}

// ---------------------------------------------------------------------------
// fused prep: fp32->fp16 cvt (x, W_qkv, W_proj) + RoPE table + mask pre-scale
// ---------------------------------------------------------------------------
#define N1 (MM * CC / 8)          // 1,048,576 half8 groups (x)
#define N2 (FF * CC / 8)          // 98,304 (W_qkv)
#define N3 (CC * CC / 8)          // 32,768 (W_proj)
#define NC (N1 + N2 + N3)         // 1,179,648
#define NR (NN * 32)              // 65,536 rope entries
#define NPREP (NC + NR + MM)      // 1,261,568  (/256 = 4928 blocks exactly)
__global__ __launch_bounds__(256) void prep_kernel(
    const float* __restrict__ x, const float* __restrict__ wq,
    const float* __restrict__ wp, const float* __restrict__ mask,
    half_t* __restrict__ d, float2* __restrict__ tab, float* __restrict__ msb) {
  int i = blockIdx.x * 256 + threadIdx.x;
  if (i < NC) {
    const float* s;
    if (i < N1)            s = x  + (size_t)i * 8;
    else if (i < N1 + N2)  s = wq + (size_t)(i - N1) * 8;
    else                   s = wp + (size_t)(i - N1 - N2) * 8;
    float4 a = ((const float4*)s)[0], b = ((const float4*)s)[1];
    half8 h;
    h[0] = (half_t)a.x; h[1] = (half_t)a.y; h[2] = (half_t)a.z; h[3] = (half_t)a.w;
    h[4] = (half_t)b.x; h[5] = (half_t)b.y; h[6] = (half_t)b.z; h[7] = (half_t)b.w;
    ((half8*)d)[i] = h;
  } else if (i < NC + NR) {
    int e = i - NC;
    int p = e >> 5, j = e & 31;
    float ang = (float)p * __powf(10000.0f, -(float)(2 * j) * (1.0f / 64.0f));
    float sv, cv;
    __sincosf(ang, &sv, &cv);
    tab[e] = make_float2(cv, sv);
  } else {
    int k = i - NC - NR;
    msb[k] = mask[k] * LOG2E - EXP2_OFF;
  }
}

// ---------------------------------------------------------------------------
// Kernel 1: qkv = x @ W_qkv^T  (fp16 MFMA, 128x128 tile, BK=32, 4 waves)
// SWAPPED-operand MFMA: acc = mfma(bf, af) -> col(L15)=n, row(quad*4+r)=f.
// Epilogue: RoPE pairs adjacent in-register, 16B tab loads, half4 stores.
// V -> LDS transpose (T[d][n]) -> Vt fp16 (B,H,D,N).   [unchanged]
// ---------------------------------------------------------------------------
__global__ __launch_bounds__(256) void qkv_mfma_kernel(
    const half_t* __restrict__ Ah,   // (16384, 512)
    const half_t* __restrict__ Bh,   // (1536, 512)
    const int*   __restrict__ ncp,
    const float2* __restrict__ tab,  // (2048, 32) cos/sin
    half_t* __restrict__ Qh, half_t* __restrict__ Kh, half_t* __restrict__ Vt)
{
  __shared__ union {
    struct { half_t A[128 * 32]; half_t B[128 * 32]; } s;   // 16 KB
    half_t T[4][64 * 68];                                   // 34.8 KB (V epilogue)
  } sm;

  const int tid  = threadIdx.x;
  const int wave = tid >> 6, lane = tid & 63;
  const int L15  = lane & 15, quad = lane >> 4;
  const int wm = (wave & 1) * 64, wn = (wave >> 1) * 64;
  const int m0 = blockIdx.x * 128;
  const int f0 = blockIdx.y * 128;

  const int srow = lane >> 2;            // 0..15
  const int scolh = (lane & 3) * 8;      // half offset within row
  const half_t* Ag = Ah + (size_t)(m0 + wave * 16 + srow) * CC + scolh;
  const half_t* Bg = Bh + (size_t)(f0 + wave * 16 + srow) * CC + scolh;
  half_t* Al = &sm.s.A[(wave * 16) * 32];
  half_t* Bl = &sm.s.B[(wave * 16) * 32];

  floatx4 acc[4][4];
#pragma unroll
  for (int i = 0; i < 4; ++i)
#pragma unroll
    for (int j = 0; j < 4; ++j) acc[i][j] = (floatx4){0.f, 0.f, 0.f, 0.f};

  for (int k0 = 0; k0 < CC; k0 += 32) {
    __syncthreads();
    gld16(Ag + k0,            Al);
    gld16(Ag + k0 + 64 * CC,  Al + 64 * 32);
    gld16(Bg + k0,            Bl);
    gld16(Bg + k0 + 64 * CC,  Bl + 64 * 32);
    __syncthreads();
    half8 af[4], bf[4];
#pragma unroll
    for (int mi = 0; mi < 4; ++mi)
      af[mi] = *(const half8*)&sm.s.A[(wm + mi * 16 + L15) * 32 + quad * 8];
#pragma unroll
    for (int ni = 0; ni < 4; ++ni)
      bf[ni] = *(const half8*)&sm.s.B[(wn + ni * 16 + L15) * 32 + quad * 8];
#pragma unroll
    for (int mi = 0; mi < 4; ++mi)
#pragma unroll
      for (int ni = 0; ni < 4; ++ni)
        acc[mi][ni] = __builtin_amdgcn_mfma_f32_16x16x32_f16(bf[ni], af[mi], acc[mi][ni], 0, 0, 0);
  }
  // acc[mi][ni][r] = out[n = m0+wm+mi*16+L15][f = f0+wn+ni*16+quad*4+r]

  const int which = f0 >> 9;         // block-uniform (128 | 512)
  const int b     = m0 >> 11;        // block-uniform
  const int n_base = (m0 & 2047) + wm;
  const int h     = ((f0 + wn) >> 6) & 7;   // wave-uniform head

  if (which < 2) {
    const int nc = *ncp;
    half_t* dst = which ? Kh : Qh;
    const float qscale = which ? 1.0f : (0.125f * LOG2E);
    const float* tabf = (const float*)tab;
#pragma unroll
    for (int mi = 0; mi < 4; ++mi) {
      const int n = n_base + mi * 16 + L15;
      const int p = n - nc;
      const size_t rbase = (((size_t)(b * HH + h) * NN + n) << 6) + quad * 4;
#pragma unroll
      for (int ni = 0; ni < 4; ++ni) {
        float o0 = acc[mi][ni][0], o1 = acc[mi][ni][1];
        float o2 = acc[mi][ni][2], o3 = acc[mi][ni][3];
        if (p >= 0) {
          const fx4 c4 = *(const fx4*)(tabf + p * 64 + ni * 16 + quad * 4);
          const float e0 = o0, e1 = o1, e2 = o2, e3 = o3;
          o0 = e0 * c4[0] - e1 * c4[1];
          o1 = e0 * c4[1] + e1 * c4[0];
          o2 = e2 * c4[2] - e3 * c4[3];
          o3 = e2 * c4[3] + e3 * c4[2];
        }
        half4 hv;
        hv[0] = (half_t)(o0 * qscale); hv[1] = (half_t)(o1 * qscale);
        hv[2] = (half_t)(o2 * qscale); hv[3] = (half_t)(o3 * qscale);
        *(half4*)(dst + rbase + ni * 16) = hv;
      }
    }
  } else {
    // V: per-wave 64x64 transpose through LDS -> (B,H,D,N)
    __syncthreads();   // all waves done reading sm.s (union overwrite)
#pragma unroll
    for (int ni = 0; ni < 4; ++ni)
#pragma unroll
      for (int mi = 0; mi < 4; ++mi)
#pragma unroll
        for (int r = 0; r < 4; ++r)
          sm.T[wave][(ni * 16 + quad * 4 + r) * 68 + mi * 16 + L15] = (half_t)acc[mi][ni][r];
    __syncthreads();
    const size_t gbase = ((size_t)(b * HH + h) * DD + lane) * NN + n_base;
#pragma unroll
    for (int c = 0; c < 8; ++c)
      *(half8*)(Vt + gbase + c * 8) = *(const half8*)&sm.T[wave][lane * 68 + c * 8];
  }
}

// ---------------------------------------------------------------------------
// Kernel 2: flash attention, swapped-operand 32x32x16 MFMA.
// Round-2 pipeline; SINGLE change this round: pre-scaled mask loaded directly
// as the QK MFMA C-operand (deletes 16 movs + 16 fmafs per t-phase).
// shfl_xor routing kept (permlane32_swap suspected of scratch round-trip).
// ---------------------------------------------------------------------------
__global__ __launch_bounds__(256, 4) void flash_mfma_kernel(
    const half_t* __restrict__ Qh,   // (B,H,N,D)  (q pre-scaled by 0.125*log2e)
    const half_t* __restrict__ Kh,   // (B,H,N,D)
    const half_t* __restrict__ Vt,   // (B,H,D,N)
    const float*  __restrict__ ms,   // (B,N) pre-scaled: m*log2e - EXP2_OFF
    half_t* __restrict__ O)          // (B,N,C) fp16
{
  __shared__ half_t KV[2][2][64 * 64];   // [buf][K|V][row*64 + e]  32 KB

  const int tid  = threadIdx.x;
  const int wave = tid >> 6;            // 0..3
  const int lane = tid & 63;
  const int l31  = lane & 31;
  const int hi   = lane >> 5;           // 0/1
  const int l7   = lane & 7;

  // XCD-aware decode: blocks with the same head share blockIdx%8 (same XCD)
  const int bid  = blockIdx.x;          // 0..1023
  const int xcd  = bid & 7;
  const int slot = bid >> 3;            // 0..127
  const int qt   = slot & 15;           // 16 q-tiles of 128 rows
  const int head = (slot >> 4) * 8 + xcd;   // 0..63
  const int b    = head >> 3;
  const int h    = head & 7;

  const half_t* Kt_base = Kh + ((((size_t)b * HH + h) * NN) << 6);
  const half_t* Vt_base = Vt + (((size_t)b * HH + h) * DD) * NN;

  // Q B-fragments: q = qt*128 + wave*32 + l31 ; k-dim elem = kd*16 + hi*8 + j
  half8 qf[4];
  {
    const half_t* Qp =
        Qh + ((((size_t)b * HH + h) * NN + qt * 128 + wave * 32 + l31) << 6) + hi * 8;
#pragma unroll
    for (int kd = 0; kd < 4; ++kd) qf[kd] = *(const half8*)(Qp + kd * 16);
  }

  // staging source pointers, pre-swizzled: LDS linear slot sl of row holds
  // source 16B-group (sl ^ (row&7)); row&7 == lane>>3 here.
  const int r8  = lane >> 3;                 // 0..7
  const int dof = ((l7 ^ r8) << 3);          // halfs
  const half_t* kbase = Kt_base + (((size_t)(wave * 16 + r8)) << 6) + dof;
  const half_t* vbase = Vt_base + (size_t)(wave * 16 + r8) * NN + dof;

  // LDS read addrs (bytes), buffer/t offsets added as immediates at use.
  int adK[4], adV[4];
#pragma unroll
  for (int c = 0; c < 4; ++c) {
    adK[c] = l31 * 128 + ((((c << 1) | hi) ^ l7) << 4);
    adV[c] = 8192 + l31 * 128 + ((((c << 1) | hi) ^ l7) << 4);
  }
  const char* L = (const char*)KV;

  floatx16 acc[2];
#pragma unroll
  for (int dt = 0; dt < 2; ++dt)
#pragma unroll
    for (int r = 0; r < 16; ++r) acc[dt][r] = 0.f;
  float l_part = 0.f;

  const float* mkb = ms + (size_t)b * NN + hi * 4;

#define STAGE(c, koff, voff)                                                  \
  {                                                                           \
    gld16(kbase + (koff),          &KV[c][0][wave * 1024]);                   \
    gld16(kbase + (koff) + 512,    &KV[c][0][wave * 1024 + 512]);             \
    gld16(vbase + (voff),          &KV[c][1][wave * 1024]);                   \
    gld16(vbase + (voff) + 8 * NN, &KV[c][1][wave * 1024 + 512]);             \
  }

#define COMPUTE(c, moff)                                                      \
  _Pragma("unroll")                                                           \
  for (int t = 0; t < 2; ++t) {                                               \
    floatx16 S;                                                               \
    _Pragma("unroll")                                                         \
    for (int r2 = 0; r2 < 4; ++r2) {                                          \
      fx4 mv = *(const fx4*)(mkb + (moff) + t * 32 + r2 * 8);                 \
      S[r2 * 4 + 0] = mv[0]; S[r2 * 4 + 1] = mv[1];                           \
      S[r2 * 4 + 2] = mv[2]; S[r2 * 4 + 3] = mv[3];                           \
    }                                                                         \
    __builtin_amdgcn_s_setprio(1);                                            \
    _Pragma("unroll")                                                         \
    for (int kd = 0; kd < 4; ++kd) {                                          \
      half8 kf = *(const half8*)(L + (adK[kd] + (c) * 16384 + t * 4096));     \
      S = __builtin_amdgcn_mfma_f32_32x32x16_f16(kf, qf[kd], S, 0, 0, 0);     \
    }                                                                         \
    __builtin_amdgcn_s_setprio(0);                                            \
    _Pragma("unroll")                                                         \
    for (int r = 0; r < 16; ++r) {                                            \
      float p = __builtin_amdgcn_exp2f(S[r]);                                 \
      l_part += p;                                                            \
      S[r] = p;                                                               \
    }                                                                         \
    unsigned W[4][2];                                                         \
    _Pragma("unroll")                                                         \
    for (int r2 = 0; r2 < 4; ++r2)                                            \
      _Pragma("unroll")                                                       \
      for (int u = 0; u < 2; ++u) {                                           \
        union { half_t hh[2]; unsigned w; } pk;                               \
        pk.hh[0] = (half_t)S[r2 * 4 + 2 * u];                                 \
        pk.hh[1] = (half_t)S[r2 * 4 + 2 * u + 1];                             \
        W[r2][u] = pk.w;                                                      \
      }                                                                       \
    _Pragma("unroll")                                                         \
    for (int ksl = 0; ksl < 2; ++ksl) {                                       \
      unsigned A0 = W[2 * ksl][0],     A1 = W[2 * ksl][1];                    \
      unsigned B0 = W[2 * ksl + 1][0], B1 = W[2 * ksl + 1][1];                \
      unsigned pA0 = __shfl_xor(A0, 32, 64), pA1 = __shfl_xor(A1, 32, 64);    \
      unsigned pB0 = __shfl_xor(B0, 32, 64), pB1 = __shfl_xor(B1, 32, 64);    \
      union { unsigned u4[4]; half8 v; } pw;                                  \
      pw.u4[0] = hi ? pB0 : A0;                                               \
      pw.u4[1] = hi ? pB1 : A1;                                               \
      pw.u4[2] = hi ? B0 : pA0;                                               \
      pw.u4[3] = hi ? B1 : pA1;                                               \
      const int ks = t * 2 + ksl;                                             \
      __builtin_amdgcn_s_setprio(1);                                          \
      _Pragma("unroll")                                                       \
      for (int dt = 0; dt < 2; ++dt) {                                        \
        half8 vf = *(const half8*)(L + (adV[ks] + (c) * 16384 + dt * 4096));  \
        acc[dt] = __builtin_amdgcn_mfma_f32_32x32x16_f16(pw.v, vf, acc[dt], 0, 0, 0); \
      }                                                                       \
      __builtin_amdgcn_s_setprio(0);                                          \
    }                                                                         \
  }

  // prologue: stage tiles 0 and 1; wait only for tile 0; barrier.
  STAGE(0, 0, 0)
  STAGE(1, 4096, 64)
  asm volatile("s_waitcnt vmcnt(4)");
  __builtin_amdgcn_s_barrier();
  __builtin_amdgcn_sched_barrier(0);
  kbase += 8192; vbase += 128;   // now pointing at tile 2

#pragma unroll 1
  for (int kt2 = 0; kt2 < 15; ++kt2) {   // tiles 0..29; stages tiles 2..31
    COMPUTE(0, 0)
    __builtin_amdgcn_sched_barrier(0);
    __builtin_amdgcn_s_barrier();        // all waves done reading buf 0
    STAGE(0, 0, 0)                       // tile 2*kt2+2 -> buf 0
    asm volatile("s_waitcnt vmcnt(4)");  // stage(2*kt2+1) landed; fresh 4 in flight
    __builtin_amdgcn_s_barrier();
    __builtin_amdgcn_sched_barrier(0);

    COMPUTE(1, 64)
    __builtin_amdgcn_sched_barrier(0);
    __builtin_amdgcn_s_barrier();        // all waves done reading buf 1
    STAGE(1, 4096, 64)                   // tile 2*kt2+3 -> buf 1
    asm volatile("s_waitcnt vmcnt(4)");  // stage(2*kt2+2) landed
    __builtin_amdgcn_s_barrier();
    __builtin_amdgcn_sched_barrier(0);

    kbase += 8192; vbase += 128;
    mkb += 128;
  }

  // tail: tiles 30 (buf 0) and 31 (buf 1); no more staging
  COMPUTE(0, 0)
  asm volatile("s_waitcnt vmcnt(0)");    // stage(31) fully landed
  __builtin_amdgcn_s_barrier();
  __builtin_amdgcn_sched_barrier(0);
  COMPUTE(1, 64)

#undef STAGE
#undef COMPUTE

  // l: sum the two lane-halves (each lane holds partials for q = lane&31)
  l_part += __shfl_xor(l_part, 32, 64);

  const size_t orow = (size_t)b * NN + qt * 128 + wave * 32;
#pragma unroll
  for (int r = 0; r < 16; ++r) {
    const int ql  = (r & 3) + 8 * (r >> 2) + 4 * hi;   // 0..31
    const float iv = 1.0f / __shfl(l_part, ql, 64);
    const size_t ro = ((orow + ql) << 9) + (h << 6) + l31;
    O[ro]      = (half_t)(acc[0][r] * iv);
    O[ro + 32] = (half_t)(acc[1][r] * iv);
  }
}

// ---------------------------------------------------------------------------
// Kernel 3: out = O @ W_proj^T + b_proj  (fp16 MFMA, fp32 out)
// 128x64 tile (grid 1024 = 4 blocks/CU, 16 waves/CU).  [unchanged]
// ---------------------------------------------------------------------------
__global__ __launch_bounds__(256) void proj_mfma_kernel(
    const half_t* __restrict__ Ah,   // (16384, 512) fp16
    const half_t* __restrict__ Bh,   // (512, 512) fp16
    const float* __restrict__ bias,  // (512,)
    float* __restrict__ out)         // (16384, 512)
{
  __shared__ half_t As[128 * 32];   // 8 KB
  __shared__ half_t Bs[64 * 32];    // 4 KB

  const int tid  = threadIdx.x;
  const int wave = tid >> 6, lane = tid & 63;
  const int L15  = lane & 15, quad = lane >> 4;
  const int wm = (wave & 1) * 64, wn = (wave >> 1) * 32;
  const int m0 = blockIdx.x * 128;
  const int f0 = blockIdx.y * 64;

  const int srow = lane >> 2;
  const int scolh = (lane & 3) * 8;
  const half_t* Ag = Ah + (size_t)(m0 + wave * 16 + srow) * CC + scolh;
  const half_t* Bg = Bh + (size_t)(f0 + wave * 16 + srow) * CC + scolh;
  half_t* Al = &As[(wave * 16) * 32];
  half_t* Bl = &Bs[(wave * 16) * 32];

  floatx4 acc[4][2];
#pragma unroll
  for (int i = 0; i < 4; ++i)
#pragma unroll
    for (int j = 0; j < 2; ++j) acc[i][j] = (floatx4){0.f, 0.f, 0.f, 0.f};

  for (int k0 = 0; k0 < CC; k0 += 32) {
    __syncthreads();
    gld16(Ag + k0,           Al);
    gld16(Ag + k0 + 64 * CC, Al + 64 * 32);
    gld16(Bg + k0,           Bl);
    __syncthreads();
    half8 af[4], bf[2];
#pragma unroll
    for (int mi = 0; mi < 4; ++mi)
      af[mi] = *(const half8*)&As[(wm + mi * 16 + L15) * 32 + quad * 8];
#pragma unroll
    for (int ni = 0; ni < 2; ++ni)
      bf[ni] = *(const half8*)&Bs[(wn + ni * 16 + L15) * 32 + quad * 8];
#pragma unroll
    for (int mi = 0; mi < 4; ++mi)
#pragma unroll
      for (int ni = 0; ni < 2; ++ni)
        acc[mi][ni] = __builtin_amdgcn_mfma_f32_16x16x32_f16(af[mi], bf[ni], acc[mi][ni], 0, 0, 0);
  }

#pragma unroll
  for (int ni = 0; ni < 2; ++ni) {
    const int f = f0 + wn + ni * 16 + L15;
    const float bv = bias[f];
#pragma unroll
    for (int mi = 0; mi < 4; ++mi)
#pragma unroll
      for (int r = 0; r < 4; ++r)
        out[(size_t)(m0 + wm + mi * 16 + quad * 4 + r) * CC + f] = acc[mi][ni][r] + bv;
  }
}

// ---------------------------------------------------------------------------
extern "C" void kernel_launch(void* const* d_in, const int* in_sizes, int n_in,
                              void* d_out, int out_size, void* d_ws, size_t ws_size,
                              hipStream_t stream) {
  const float* x     = (const float*)d_in[0];
  const float* mask  = (const float*)d_in[1];
  const float* Wqkv  = (const float*)d_in[2];
  const float* Wproj = (const float*)d_in[3];
  const float* bproj = (const float*)d_in[4];
  const int*   ncp   = (const int*)d_in[5];
  float* out = (float*)d_out;

  const size_t per = (size_t)BB * HH * NN * DD;   // 8,388,608
  half_t* xh  = (half_t*)d_ws;
  half_t* Wqh = xh + (size_t)MM * CC;
  half_t* Wph = Wqh + (size_t)FF * CC;
  half_t* Qh  = Wph + (size_t)CC * CC;
  half_t* Kh  = Qh + per;
  half_t* Vt  = Kh + per;
  half_t* Oh  = Vt + per;
  float2* tab = (float2*)(Oh + per);              // 2048*32*8B = 512 KB
  float*  msb = (float*)(tab + (size_t)NN * 32);  // 16384*4B = 64 KB

  prep_kernel<<<dim3(NPREP / 256), 256, 0, stream>>>(x, Wqkv, Wproj, mask, xh, tab, msb);

  qkv_mfma_kernel<<<dim3(MM / 128, FF / 128), 256, 0, stream>>>(xh, Wqh, ncp, tab, Qh, Kh, Vt);
  flash_mfma_kernel<<<dim3(BB * HH * (NN / 128)), 256, 0, stream>>>(Qh, Kh, Vt, msb, Oh);
  proj_mfma_kernel<<<dim3(MM / 128, CC / 64), 256, 0, stream>>>(Oh, Wph, bproj, out);
}

// Round 10
// 252.776 us; speedup vs baseline: 3.4588x; 1.0161x over previous
//
#include <hip/hip_runtime.h>
#include <cmath>

#define BB 8
#define NN 2048
#define CC 512
#define HH 8
#define DD 64
#define FF 1536
#define MM (BB*NN)   // 16384

typedef _Float16 half_t;
typedef __attribute__((ext_vector_type(8))) _Float16 half8;
typedef __attribute__((ext_vector_type(4))) _Float16 half4;
typedef __attribute__((ext_vector_type(2))) __fp16 fp16x2;   // cvt_pkrtz return type
typedef __attribute__((ext_vector_type(4))) float floatx4;
typedef __attribute__((ext_vector_type(16))) float floatx16;
typedef __attribute__((ext_vector_type(4))) float fx4;

#define LOG2E 1.44269504088896f
#define EXP2_OFF 4.3280851f   // 3 * log2(e)

// async global->LDS, 16 B per lane; LDS dest must be wave-uniform base (+lane*16)
typedef const __attribute__((address_space(1))) unsigned int* gas_ptr;
typedef __attribute__((address_space(3))) unsigned int* las_ptr;
__device__ __forceinline__ void gld16(const half_t* g, half_t* l) {
  __builtin_amdgcn_global_load_lds((gas_ptr)g, (las_ptr)l, 16, 0, 0);
}

// ---------------------------------------------------------------------------
// fused prep: fp32->fp16 cvt (x, W_qkv, W_proj) + RoPE table + mask pre-scale
// ---------------------------------------------------------------------------
#define N1 (MM * CC / 8)          // 1,048,576 half8 groups (x)
#define N2 (FF * CC / 8)          // 98,304 (W_qkv)
#define N3 (CC * CC / 8)          // 32,768 (W_proj)
#define NC (N1 + N2 + N3)         // 1,179,648
#define NR (NN * 32)              // 65,536 rope entries
#define NPREP (NC + NR + MM)      // 1,261,568  (/256 = 4928 blocks exactly)
__global__ __launch_bounds__(256) void prep_kernel(
    const float* __restrict__ x, const float* __restrict__ wq,
    const float* __restrict__ wp, const float* __restrict__ mask,
    half_t* __restrict__ d, float2* __restrict__ tab, float* __restrict__ msb) {
  int i = blockIdx.x * 256 + threadIdx.x;
  if (i < NC) {
    const float* s;
    if (i < N1)            s = x  + (size_t)i * 8;
    else if (i < N1 + N2)  s = wq + (size_t)(i - N1) * 8;
    else                   s = wp + (size_t)(i - N1 - N2) * 8;
    float4 a = ((const float4*)s)[0], b = ((const float4*)s)[1];
    half8 h;
    h[0] = (half_t)a.x; h[1] = (half_t)a.y; h[2] = (half_t)a.z; h[3] = (half_t)a.w;
    h[4] = (half_t)b.x; h[5] = (half_t)b.y; h[6] = (half_t)b.z; h[7] = (half_t)b.w;
    ((half8*)d)[i] = h;
  } else if (i < NC + NR) {
    int e = i - NC;
    int p = e >> 5, j = e & 31;
    float ang = (float)p * __powf(10000.0f, -(float)(2 * j) * (1.0f / 64.0f));
    float sv, cv;
    __sincosf(ang, &sv, &cv);
    tab[e] = make_float2(cv, sv);
  } else {
    int k = i - NC - NR;
    msb[k] = mask[k] * LOG2E - EXP2_OFF;
  }
}

// ---------------------------------------------------------------------------
// Kernel 1: qkv = x @ W_qkv^T  (fp16 MFMA, 128x128 tile, BK=32, 4 waves)
// SWAPPED-operand MFMA: acc = mfma(bf, af) -> col(L15)=n, row(quad*4+r)=f.
// Epilogue: RoPE pairs adjacent in-register, 16B tab loads, half4 stores.
// V -> LDS transpose (T[d][n]) -> Vt fp16 (B,H,D,N).   [unchanged]
// ---------------------------------------------------------------------------
__global__ __launch_bounds__(256) void qkv_mfma_kernel(
    const half_t* __restrict__ Ah,   // (16384, 512)
    const half_t* __restrict__ Bh,   // (1536, 512)
    const int*   __restrict__ ncp,
    const float2* __restrict__ tab,  // (2048, 32) cos/sin
    half_t* __restrict__ Qh, half_t* __restrict__ Kh, half_t* __restrict__ Vt)
{
  __shared__ union {
    struct { half_t A[128 * 32]; half_t B[128 * 32]; } s;   // 16 KB
    half_t T[4][64 * 68];                                   // 34.8 KB (V epilogue)
  } sm;

  const int tid  = threadIdx.x;
  const int wave = tid >> 6, lane = tid & 63;
  const int L15  = lane & 15, quad = lane >> 4;
  const int wm = (wave & 1) * 64, wn = (wave >> 1) * 64;
  const int m0 = blockIdx.x * 128;
  const int f0 = blockIdx.y * 128;

  const int srow = lane >> 2;            // 0..15
  const int scolh = (lane & 3) * 8;      // half offset within row
  const half_t* Ag = Ah + (size_t)(m0 + wave * 16 + srow) * CC + scolh;
  const half_t* Bg = Bh + (size_t)(f0 + wave * 16 + srow) * CC + scolh;
  half_t* Al = &sm.s.A[(wave * 16) * 32];
  half_t* Bl = &sm.s.B[(wave * 16) * 32];

  floatx4 acc[4][4];
#pragma unroll
  for (int i = 0; i < 4; ++i)
#pragma unroll
    for (int j = 0; j < 4; ++j) acc[i][j] = (floatx4){0.f, 0.f, 0.f, 0.f};

  for (int k0 = 0; k0 < CC; k0 += 32) {
    __syncthreads();
    gld16(Ag + k0,            Al);
    gld16(Ag + k0 + 64 * CC,  Al + 64 * 32);
    gld16(Bg + k0,            Bl);
    gld16(Bg + k0 + 64 * CC,  Bl + 64 * 32);
    __syncthreads();
    half8 af[4], bf[4];
#pragma unroll
    for (int mi = 0; mi < 4; ++mi)
      af[mi] = *(const half8*)&sm.s.A[(wm + mi * 16 + L15) * 32 + quad * 8];
#pragma unroll
    for (int ni = 0; ni < 4; ++ni)
      bf[ni] = *(const half8*)&sm.s.B[(wn + ni * 16 + L15) * 32 + quad * 8];
#pragma unroll
    for (int mi = 0; mi < 4; ++mi)
#pragma unroll
      for (int ni = 0; ni < 4; ++ni)
        acc[mi][ni] = __builtin_amdgcn_mfma_f32_16x16x32_f16(bf[ni], af[mi], acc[mi][ni], 0, 0, 0);
  }
  // acc[mi][ni][r] = out[n = m0+wm+mi*16+L15][f = f0+wn+ni*16+quad*4+r]

  const int which = f0 >> 9;         // block-uniform (128 | 512)
  const int b     = m0 >> 11;        // block-uniform
  const int n_base = (m0 & 2047) + wm;
  const int h     = ((f0 + wn) >> 6) & 7;   // wave-uniform head

  if (which < 2) {
    const int nc = *ncp;
    half_t* dst = which ? Kh : Qh;
    const float qscale = which ? 1.0f : (0.125f * LOG2E);
    const float* tabf = (const float*)tab;
#pragma unroll
    for (int mi = 0; mi < 4; ++mi) {
      const int n = n_base + mi * 16 + L15;
      const int p = n - nc;
      const size_t rbase = (((size_t)(b * HH + h) * NN + n) << 6) + quad * 4;
#pragma unroll
      for (int ni = 0; ni < 4; ++ni) {
        float o0 = acc[mi][ni][0], o1 = acc[mi][ni][1];
        float o2 = acc[mi][ni][2], o3 = acc[mi][ni][3];
        if (p >= 0) {
          const fx4 c4 = *(const fx4*)(tabf + p * 64 + ni * 16 + quad * 4);
          const float e0 = o0, e1 = o1, e2 = o2, e3 = o3;
          o0 = e0 * c4[0] - e1 * c4[1];
          o1 = e0 * c4[1] + e1 * c4[0];
          o2 = e2 * c4[2] - e3 * c4[3];
          o3 = e2 * c4[3] + e3 * c4[2];
        }
        half4 hv;
        hv[0] = (half_t)(o0 * qscale); hv[1] = (half_t)(o1 * qscale);
        hv[2] = (half_t)(o2 * qscale); hv[3] = (half_t)(o3 * qscale);
        *(half4*)(dst + rbase + ni * 16) = hv;
      }
    }
  } else {
    // V: per-wave 64x64 transpose through LDS -> (B,H,D,N)
    __syncthreads();   // all waves done reading sm.s (union overwrite)
#pragma unroll
    for (int ni = 0; ni < 4; ++ni)
#pragma unroll
      for (int mi = 0; mi < 4; ++mi)
#pragma unroll
        for (int r = 0; r < 4; ++r)
          sm.T[wave][(ni * 16 + quad * 4 + r) * 68 + mi * 16 + L15] = (half_t)acc[mi][ni][r];
    __syncthreads();
    const size_t gbase = ((size_t)(b * HH + h) * DD + lane) * NN + n_base;
#pragma unroll
    for (int c = 0; c < 8; ++c)
      *(half8*)(Vt + gbase + c * 8) = *(const half8*)&sm.T[wave][lane * 68 + c * 8];
  }
}

// ---------------------------------------------------------------------------
// Kernel 2: flash attention, swapped-operand 32x32x16 MFMA.
// Round-8 pipeline (mask as MFMA C-operand). This round, 3 VALU-path cuts:
//  - P routing via inline-asm v_permlane32_swap_b32 (replaces 8 ds_bpermute
//    + 8 cndmask per t-phase with 4 VALU ops; asm form avoids the builtin's
//    int2-aggregate scratch round-trip that killed round 5)
//  - f32->f16 pack via v_cvt_pkrtz (16 cvt + 8 pack -> 8 ops)
//  - l partials in 4 accumulators (serial chain 16 -> 4)
// ---------------------------------------------------------------------------
__global__ __launch_bounds__(256, 4) void flash_mfma_kernel(
    const half_t* __restrict__ Qh,   // (B,H,N,D)  (q pre-scaled by 0.125*log2e)
    const half_t* __restrict__ Kh,   // (B,H,N,D)
    const half_t* __restrict__ Vt,   // (B,H,D,N)
    const float*  __restrict__ ms,   // (B,N) pre-scaled: m*log2e - EXP2_OFF
    half_t* __restrict__ O)          // (B,N,C) fp16
{
  __shared__ half_t KV[2][2][64 * 64];   // [buf][K|V][row*64 + e]  32 KB

  const int tid  = threadIdx.x;
  const int wave = tid >> 6;            // 0..3
  const int lane = tid & 63;
  const int l31  = lane & 31;
  const int hi   = lane >> 5;           // 0/1
  const int l7   = lane & 7;

  // XCD-aware decode: blocks with the same head share blockIdx%8 (same XCD)
  const int bid  = blockIdx.x;          // 0..1023
  const int xcd  = bid & 7;
  const int slot = bid >> 3;            // 0..127
  const int qt   = slot & 15;           // 16 q-tiles of 128 rows
  const int head = (slot >> 4) * 8 + xcd;   // 0..63
  const int b    = head >> 3;
  const int h    = head & 7;

  const half_t* Kt_base = Kh + ((((size_t)b * HH + h) * NN) << 6);
  const half_t* Vt_base = Vt + (((size_t)b * HH + h) * DD) * NN;

  // Q B-fragments: q = qt*128 + wave*32 + l31 ; k-dim elem = kd*16 + hi*8 + j
  half8 qf[4];
  {
    const half_t* Qp =
        Qh + ((((size_t)b * HH + h) * NN + qt * 128 + wave * 32 + l31) << 6) + hi * 8;
#pragma unroll
    for (int kd = 0; kd < 4; ++kd) qf[kd] = *(const half8*)(Qp + kd * 16);
  }

  // staging source pointers, pre-swizzled: LDS linear slot sl of row holds
  // source 16B-group (sl ^ (row&7)); row&7 == lane>>3 here.
  const int r8  = lane >> 3;                 // 0..7
  const int dof = ((l7 ^ r8) << 3);          // halfs
  const half_t* kbase = Kt_base + (((size_t)(wave * 16 + r8)) << 6) + dof;
  const half_t* vbase = Vt_base + (size_t)(wave * 16 + r8) * NN + dof;

  // LDS read addrs (bytes), buffer/t offsets added as immediates at use.
  int adK[4], adV[4];
#pragma unroll
  for (int c = 0; c < 4; ++c) {
    adK[c] = l31 * 128 + ((((c << 1) | hi) ^ l7) << 4);
    adV[c] = 8192 + l31 * 128 + ((((c << 1) | hi) ^ l7) << 4);
  }
  const char* L = (const char*)KV;

  floatx16 acc[2];
#pragma unroll
  for (int dt = 0; dt < 2; ++dt)
#pragma unroll
    for (int r = 0; r < 16; ++r) acc[dt][r] = 0.f;
  float l4[4] = {0.f, 0.f, 0.f, 0.f};

  const float* mkb = ms + (size_t)b * NN + hi * 4;

#define STAGE(c, koff, voff)                                                  \
  {                                                                           \
    gld16(kbase + (koff),          &KV[c][0][wave * 1024]);                   \
    gld16(kbase + (koff) + 512,    &KV[c][0][wave * 1024 + 512]);             \
    gld16(vbase + (voff),          &KV[c][1][wave * 1024]);                   \
    gld16(vbase + (voff) + 8 * NN, &KV[c][1][wave * 1024 + 512]);             \
  }

#define COMPUTE(c, moff)                                                      \
  _Pragma("unroll")                                                           \
  for (int t = 0; t < 2; ++t) {                                               \
    floatx16 S;                                                               \
    _Pragma("unroll")                                                         \
    for (int r2 = 0; r2 < 4; ++r2) {                                          \
      fx4 mv = *(const fx4*)(mkb + (moff) + t * 32 + r2 * 8);                 \
      S[r2 * 4 + 0] = mv[0]; S[r2 * 4 + 1] = mv[1];                           \
      S[r2 * 4 + 2] = mv[2]; S[r2 * 4 + 3] = mv[3];                           \
    }                                                                         \
    __builtin_amdgcn_s_setprio(1);                                            \
    _Pragma("unroll")                                                         \
    for (int kd = 0; kd < 4; ++kd) {                                          \
      half8 kf = *(const half8*)(L + (adK[kd] + (c) * 16384 + t * 4096));     \
      S = __builtin_amdgcn_mfma_f32_32x32x16_f16(kf, qf[kd], S, 0, 0, 0);     \
    }                                                                         \
    __builtin_amdgcn_s_setprio(0);                                            \
    _Pragma("unroll")                                                         \
    for (int r = 0; r < 16; ++r) {                                            \
      float p = __builtin_amdgcn_exp2f(S[r]);                                 \
      l4[r & 3] += p;                                                         \
      S[r] = p;                                                               \
    }                                                                         \
    unsigned W[4][2];                                                         \
    _Pragma("unroll")                                                         \
    for (int r2 = 0; r2 < 4; ++r2)                                            \
      _Pragma("unroll")                                                       \
      for (int u = 0; u < 2; ++u) {                                           \
        union { fp16x2 h; unsigned w; } pk;                                   \
        pk.h = __builtin_amdgcn_cvt_pkrtz(S[r2 * 4 + 2 * u],                  \
                                          S[r2 * 4 + 2 * u + 1]);             \
        W[r2][u] = pk.w;                                                      \
      }                                                                       \
    _Pragma("unroll")                                                         \
    for (int ksl = 0; ksl < 2; ++ksl) {                                       \
      unsigned A0 = W[2 * ksl][0],     A1 = W[2 * ksl][1];                    \
      unsigned B0 = W[2 * ksl + 1][0], B1 = W[2 * ksl + 1][1];                \
      /* swap hi(A)<->lo(B): A becomes {own A | partner B} = pw word u,   */  \
      /* B becomes {partner A | own B} = pw word 2+u (verified algebra).  */  \
      asm("v_permlane32_swap_b32 %0, %1" : "+v"(A0), "+v"(B0));               \
      asm("v_permlane32_swap_b32 %0, %1" : "+v"(A1), "+v"(B1));               \
      union { unsigned u4[4]; half8 v; } pw;                                  \
      pw.u4[0] = A0; pw.u4[1] = A1; pw.u4[2] = B0; pw.u4[3] = B1;             \
      const int ks = t * 2 + ksl;                                             \
      __builtin_amdgcn_s_setprio(1);                                          \
      _Pragma("unroll")                                                       \
      for (int dt = 0; dt < 2; ++dt) {                                        \
        half8 vf = *(const half8*)(L + (adV[ks] + (c) * 16384 + dt * 4096));  \
        acc[dt] = __builtin_amdgcn_mfma_f32_32x32x16_f16(pw.v, vf, acc[dt], 0, 0, 0); \
      }                                                                       \
      __builtin_amdgcn_s_setprio(0);                                          \
    }                                                                         \
  }

  // prologue: stage tiles 0 and 1; wait only for tile 0; barrier.
  STAGE(0, 0, 0)
  STAGE(1, 4096, 64)
  asm volatile("s_waitcnt vmcnt(4)");
  __builtin_amdgcn_s_barrier();
  __builtin_amdgcn_sched_barrier(0);
  kbase += 8192; vbase += 128;   // now pointing at tile 2

#pragma unroll 1
  for (int kt2 = 0; kt2 < 15; ++kt2) {   // tiles 0..29; stages tiles 2..31
    COMPUTE(0, 0)
    __builtin_amdgcn_sched_barrier(0);
    __builtin_amdgcn_s_barrier();        // all waves done reading buf 0
    STAGE(0, 0, 0)                       // tile 2*kt2+2 -> buf 0
    asm volatile("s_waitcnt vmcnt(4)");  // stage(2*kt2+1) landed; fresh 4 in flight
    __builtin_amdgcn_s_barrier();
    __builtin_amdgcn_sched_barrier(0);

    COMPUTE(1, 64)
    __builtin_amdgcn_sched_barrier(0);
    __builtin_amdgcn_s_barrier();        // all waves done reading buf 1
    STAGE(1, 4096, 64)                   // tile 2*kt2+3 -> buf 1
    asm volatile("s_waitcnt vmcnt(4)");  // stage(2*kt2+2) landed
    __builtin_amdgcn_s_barrier();
    __builtin_amdgcn_sched_barrier(0);

    kbase += 8192; vbase += 128;
    mkb += 128;
  }

  // tail: tiles 30 (buf 0) and 31 (buf 1); no more staging
  COMPUTE(0, 0)
  asm volatile("s_waitcnt vmcnt(0)");    // stage(31) fully landed
  __builtin_amdgcn_s_barrier();
  __builtin_amdgcn_sched_barrier(0);
  COMPUTE(1, 64)

#undef STAGE
#undef COMPUTE

  // l: combine 4 partials, then sum the two lane-halves (q = lane&31)
  float l_part = (l4[0] + l4[1]) + (l4[2] + l4[3]);
  l_part += __shfl_xor(l_part, 32, 64);

  const size_t orow = (size_t)b * NN + qt * 128 + wave * 32;
#pragma unroll
  for (int r = 0; r < 16; ++r) {
    const int ql  = (r & 3) + 8 * (r >> 2) + 4 * hi;   // 0..31
    const float iv = 1.0f / __shfl(l_part, ql, 64);
    const size_t ro = ((orow + ql) << 9) + (h << 6) + l31;
    O[ro]      = (half_t)(acc[0][r] * iv);
    O[ro + 32] = (half_t)(acc[1][r] * iv);
  }
}

// ---------------------------------------------------------------------------
// Kernel 3: out = O @ W_proj^T + b_proj  (fp16 MFMA, fp32 out)
// 128x64 tile (grid 1024 = 4 blocks/CU, 16 waves/CU).  [unchanged]
// ---------------------------------------------------------------------------
__global__ __launch_bounds__(256) void proj_mfma_kernel(
    const half_t* __restrict__ Ah,   // (16384, 512) fp16
    const half_t* __restrict__ Bh,   // (512, 512) fp16
    const float* __restrict__ bias,  // (512,)
    float* __restrict__ out)         // (16384, 512)
{
  __shared__ half_t As[128 * 32];   // 8 KB
  __shared__ half_t Bs[64 * 32];    // 4 KB

  const int tid  = threadIdx.x;
  const int wave = tid >> 6, lane = tid & 63;
  const int L15  = lane & 15, quad = lane >> 4;
  const int wm = (wave & 1) * 64, wn = (wave >> 1) * 32;
  const int m0 = blockIdx.x * 128;
  const int f0 = blockIdx.y * 64;

  const int srow = lane >> 2;
  const int scolh = (lane & 3) * 8;
  const half_t* Ag = Ah + (size_t)(m0 + wave * 16 + srow) * CC + scolh;
  const half_t* Bg = Bh + (size_t)(f0 + wave * 16 + srow) * CC + scolh;
  half_t* Al = &As[(wave * 16) * 32];
  half_t* Bl = &Bs[(wave * 16) * 32];

  floatx4 acc[4][2];
#pragma unroll
  for (int i = 0; i < 4; ++i)
#pragma unroll
    for (int j = 0; j < 2; ++j) acc[i][j] = (floatx4){0.f, 0.f, 0.f, 0.f};

  for (int k0 = 0; k0 < CC; k0 += 32) {
    __syncthreads();
    gld16(Ag + k0,           Al);
    gld16(Ag + k0 + 64 * CC, Al + 64 * 32);
    gld16(Bg + k0,           Bl);
    __syncthreads();
    half8 af[4], bf[2];
#pragma unroll
    for (int mi = 0; mi < 4; ++mi)
      af[mi] = *(const half8*)&As[(wm + mi * 16 + L15) * 32 + quad * 8];
#pragma unroll
    for (int ni = 0; ni < 2; ++ni)
      bf[ni] = *(const half8*)&Bs[(wn + ni * 16 + L15) * 32 + quad * 8];
#pragma unroll
    for (int mi = 0; mi < 4; ++mi)
#pragma unroll
      for (int ni = 0; ni < 2; ++ni)
        acc[mi][ni] = __builtin_amdgcn_mfma_f32_16x16x32_f16(af[mi], bf[ni], acc[mi][ni], 0, 0, 0);
  }

#pragma unroll
  for (int ni = 0; ni < 2; ++ni) {
    const int f = f0 + wn + ni * 16 + L15;
    const float bv = bias[f];
#pragma unroll
    for (int mi = 0; mi < 4; ++mi)
#pragma unroll
      for (int r = 0; r < 4; ++r)
        out[(size_t)(m0 + wm + mi * 16 + quad * 4 + r) * CC + f] = acc[mi][ni][r] + bv;
  }
}

// ---------------------------------------------------------------------------
extern "C" void kernel_launch(void* const* d_in, const int* in_sizes, int n_in,
                              void* d_out, int out_size, void* d_ws, size_t ws_size,
                              hipStream_t stream) {
  const float* x     = (const float*)d_in[0];
  const float* mask  = (const float*)d_in[1];
  const float* Wqkv  = (const float*)d_in[2];
  const float* Wproj = (const float*)d_in[3];
  const float* bproj = (const float*)d_in[4];
  const int*   ncp   = (const int*)d_in[5];
  float* out = (float*)d_out;

  const size_t per = (size_t)BB * HH * NN * DD;   // 8,388,608
  half_t* xh  = (half_t*)d_ws;
  half_t* Wqh = xh + (size_t)MM * CC;
  half_t* Wph = Wqh + (size_t)FF * CC;
  half_t* Qh  = Wph + (size_t)CC * CC;
  half_t* Kh  = Qh + per;
  half_t* Vt  = Kh + per;
  half_t* Oh  = Vt + per;
  float2* tab = (float2*)(Oh + per);              // 2048*32*8B = 512 KB
  float*  msb = (float*)(tab + (size_t)NN * 32);  // 16384*4B = 64 KB

  prep_kernel<<<dim3(NPREP / 256), 256, 0, stream>>>(x, Wqkv, Wproj, mask, xh, tab, msb);

  qkv_mfma_kernel<<<dim3(MM / 128, FF / 128), 256, 0, stream>>>(xh, Wqh, ncp, tab, Qh, Kh, Vt);
  flash_mfma_kernel<<<dim3(BB * HH * (NN / 128)), 256, 0, stream>>>(Qh, Kh, Vt, msb, Oh);
  proj_mfma_kernel<<<dim3(MM / 128, CC / 64), 256, 0, stream>>>(Oh, Wph, bproj, out);
}

// Round 11
// 249.245 us; speedup vs baseline: 3.5078x; 1.0142x over previous
//
#include <hip/hip_runtime.h>
#include <cmath>

#define BB 8
#define NN 2048
#define CC 512
#define HH 8
#define DD 64
#define FF 1536
#define MM (BB*NN)   // 16384

typedef _Float16 half_t;
typedef __attribute__((ext_vector_type(8))) _Float16 half8;
typedef __attribute__((ext_vector_type(4))) _Float16 half4;
typedef __attribute__((ext_vector_type(2))) __fp16 fp16x2;   // cvt_pkrtz return type
typedef __attribute__((ext_vector_type(4))) float floatx4;
typedef __attribute__((ext_vector_type(16))) float floatx16;
typedef __attribute__((ext_vector_type(4))) float fx4;

#define LOG2E 1.44269504088896f
#define EXP2_OFF 4.3280851f   // 3 * log2(e)

// async global->LDS, 16 B per lane; LDS dest must be wave-uniform base (+lane*16)
typedef const __attribute__((address_space(1))) unsigned int* gas_ptr;
typedef __attribute__((address_space(3))) unsigned int* las_ptr;
__device__ __forceinline__ void gld16(const half_t* g, half_t* l) {
  __builtin_amdgcn_global_load_lds((gas_ptr)g, (las_ptr)l, 16, 0, 0);
}

// ---------------------------------------------------------------------------
// fused prep: fp32->fp16 cvt (x, W_qkv, W_proj) + RoPE table + mask pre-scale
// ---------------------------------------------------------------------------
#define N1 (MM * CC / 8)          // 1,048,576 half8 groups (x)
#define N2 (FF * CC / 8)          // 98,304 (W_qkv)
#define N3 (CC * CC / 8)          // 32,768 (W_proj)
#define NC (N1 + N2 + N3)         // 1,179,648
#define NR (NN * 32)              // 65,536 rope entries
#define NPREP (NC + NR + MM)      // 1,261,568  (/256 = 4928 blocks exactly)
__global__ __launch_bounds__(256) void prep_kernel(
    const float* __restrict__ x, const float* __restrict__ wq,
    const float* __restrict__ wp, const float* __restrict__ mask,
    half_t* __restrict__ d, float2* __restrict__ tab, float* __restrict__ msb) {
  int i = blockIdx.x * 256 + threadIdx.x;
  if (i < NC) {
    const float* s;
    if (i < N1)            s = x  + (size_t)i * 8;
    else if (i < N1 + N2)  s = wq + (size_t)(i - N1) * 8;
    else                   s = wp + (size_t)(i - N1 - N2) * 8;
    float4 a = ((const float4*)s)[0], b = ((const float4*)s)[1];
    half8 h;
    h[0] = (half_t)a.x; h[1] = (half_t)a.y; h[2] = (half_t)a.z; h[3] = (half_t)a.w;
    h[4] = (half_t)b.x; h[5] = (half_t)b.y; h[6] = (half_t)b.z; h[7] = (half_t)b.w;
    ((half8*)d)[i] = h;
  } else if (i < NC + NR) {
    int e = i - NC;
    int p = e >> 5, j = e & 31;
    float ang = (float)p * __powf(10000.0f, -(float)(2 * j) * (1.0f / 64.0f));
    float sv, cv;
    __sincosf(ang, &sv, &cv);
    tab[e] = make_float2(cv, sv);
  } else {
    int k = i - NC - NR;
    msb[k] = mask[k] * LOG2E - EXP2_OFF;
  }
}

// ---------------------------------------------------------------------------
// Kernel 1: qkv = x @ W_qkv^T  (fp16 MFMA, 128x128 tile, BK=32, 4 waves)
// This round: counted-vmcnt double-buffered staging (flash's proven pipeline)
// replacing the drain-barrier K-loop. Swapped-operand MFMA epilogue unchanged.
// ---------------------------------------------------------------------------
__global__ __launch_bounds__(256) void qkv_mfma_kernel(
    const half_t* __restrict__ Ah,   // (16384, 512)
    const half_t* __restrict__ Bh,   // (1536, 512)
    const int*   __restrict__ ncp,
    const float2* __restrict__ tab,  // (2048, 32) cos/sin
    half_t* __restrict__ Qh, half_t* __restrict__ Kh, half_t* __restrict__ Vt)
{
  __shared__ union {
    struct { half_t A[2][128 * 32]; half_t B[2][128 * 32]; } s;   // 32 KB
    half_t T[4][64 * 68];                                         // 34.8 KB
  } sm;

  const int tid  = threadIdx.x;
  const int wave = tid >> 6, lane = tid & 63;
  const int L15  = lane & 15, quad = lane >> 4;
  const int wm = (wave & 1) * 64, wn = (wave >> 1) * 64;
  const int m0 = blockIdx.x * 128;
  const int f0 = blockIdx.y * 128;

  const int srow = lane >> 2;            // 0..15
  const int scolh = (lane & 3) * 8;      // half offset within row
  const half_t* Ag = Ah + (size_t)(m0 + wave * 16 + srow) * CC + scolh;
  const half_t* Bg = Bh + (size_t)(f0 + wave * 16 + srow) * CC + scolh;

  floatx4 acc[4][4];
#pragma unroll
  for (int i = 0; i < 4; ++i)
#pragma unroll
    for (int j = 0; j < 4; ++j) acc[i][j] = (floatx4){0.f, 0.f, 0.f, 0.f};

#define QSTAGE(c, koff)                                                       \
  {                                                                           \
    gld16(Ag + (koff),           &sm.s.A[c][(wave * 16) * 32]);               \
    gld16(Ag + (koff) + 64 * CC, &sm.s.A[c][(64 + wave * 16) * 32]);          \
    gld16(Bg + (koff),           &sm.s.B[c][(wave * 16) * 32]);               \
    gld16(Bg + (koff) + 64 * CC, &sm.s.B[c][(64 + wave * 16) * 32]);          \
  }

#define QCOMPUTE(c)                                                           \
  {                                                                           \
    half8 af[4], bf[4];                                                       \
    _Pragma("unroll")                                                         \
    for (int mi = 0; mi < 4; ++mi)                                            \
      af[mi] = *(const half8*)&sm.s.A[c][(wm + mi * 16 + L15) * 32 + quad * 8]; \
    _Pragma("unroll")                                                         \
    for (int ni = 0; ni < 4; ++ni)                                            \
      bf[ni] = *(const half8*)&sm.s.B[c][(wn + ni * 16 + L15) * 32 + quad * 8]; \
    __builtin_amdgcn_s_setprio(1);                                            \
    _Pragma("unroll")                                                         \
    for (int mi = 0; mi < 4; ++mi)                                            \
      _Pragma("unroll")                                                       \
      for (int ni = 0; ni < 4; ++ni)                                          \
        acc[mi][ni] = __builtin_amdgcn_mfma_f32_16x16x32_f16(bf[ni], af[mi], acc[mi][ni], 0, 0, 0); \
    __builtin_amdgcn_s_setprio(0);                                            \
  }

  // prologue: stage k-steps 0 and 1; wait only for step 0; barrier.
  QSTAGE(0, 0)
  QSTAGE(1, 32)
  asm volatile("s_waitcnt vmcnt(4)");
  __builtin_amdgcn_s_barrier();
  __builtin_amdgcn_sched_barrier(0);

  int k0 = 64;   // next k-step to stage
#pragma unroll 1
  for (int kk = 0; kk < 7; ++kk) {   // computes steps 0..13; stages steps 2..15
    QCOMPUTE(0)
    __builtin_amdgcn_sched_barrier(0);
    __builtin_amdgcn_s_barrier();        // all waves done reading buf 0
    QSTAGE(0, k0)
    asm volatile("s_waitcnt vmcnt(4)");  // previous stage landed; fresh 4 in flight
    __builtin_amdgcn_s_barrier();
    __builtin_amdgcn_sched_barrier(0);

    QCOMPUTE(1)
    __builtin_amdgcn_sched_barrier(0);
    __builtin_amdgcn_s_barrier();
    QSTAGE(1, k0 + 32)
    asm volatile("s_waitcnt vmcnt(4)");
    __builtin_amdgcn_s_barrier();
    __builtin_amdgcn_sched_barrier(0);
    k0 += 64;
  }
  // tail: steps 14 (buf 0) and 15 (buf 1); no more staging
  QCOMPUTE(0)
  asm volatile("s_waitcnt vmcnt(0)");
  __builtin_amdgcn_s_barrier();
  __builtin_amdgcn_sched_barrier(0);
  QCOMPUTE(1)

#undef QSTAGE
#undef QCOMPUTE
  // acc[mi][ni][r] = out[n = m0+wm+mi*16+L15][f = f0+wn+ni*16+quad*4+r]

  const int which = f0 >> 9;         // block-uniform (128 | 512)
  const int b     = m0 >> 11;        // block-uniform
  const int n_base = (m0 & 2047) + wm;
  const int h     = ((f0 + wn) >> 6) & 7;   // wave-uniform head

  if (which < 2) {
    const int nc = *ncp;
    half_t* dst = which ? Kh : Qh;
    const float qscale = which ? 1.0f : (0.125f * LOG2E);
    const float* tabf = (const float*)tab;
#pragma unroll
    for (int mi = 0; mi < 4; ++mi) {
      const int n = n_base + mi * 16 + L15;
      const int p = n - nc;
      const size_t rbase = (((size_t)(b * HH + h) * NN + n) << 6) + quad * 4;
#pragma unroll
      for (int ni = 0; ni < 4; ++ni) {
        float o0 = acc[mi][ni][0], o1 = acc[mi][ni][1];
        float o2 = acc[mi][ni][2], o3 = acc[mi][ni][3];
        if (p >= 0) {
          const fx4 c4 = *(const fx4*)(tabf + p * 64 + ni * 16 + quad * 4);
          const float e0 = o0, e1 = o1, e2 = o2, e3 = o3;
          o0 = e0 * c4[0] - e1 * c4[1];
          o1 = e0 * c4[1] + e1 * c4[0];
          o2 = e2 * c4[2] - e3 * c4[3];
          o3 = e2 * c4[3] + e3 * c4[2];
        }
        half4 hv;
        hv[0] = (half_t)(o0 * qscale); hv[1] = (half_t)(o1 * qscale);
        hv[2] = (half_t)(o2 * qscale); hv[3] = (half_t)(o3 * qscale);
        *(half4*)(dst + rbase + ni * 16) = hv;
      }
    }
  } else {
    // V: per-wave 64x64 transpose through LDS -> (B,H,D,N)
    __syncthreads();   // all waves done reading sm.s (union overwrite)
#pragma unroll
    for (int ni = 0; ni < 4; ++ni)
#pragma unroll
      for (int mi = 0; mi < 4; ++mi)
#pragma unroll
        for (int r = 0; r < 4; ++r)
          sm.T[wave][(ni * 16 + quad * 4 + r) * 68 + mi * 16 + L15] = (half_t)acc[mi][ni][r];
    __syncthreads();
    const size_t gbase = ((size_t)(b * HH + h) * DD + lane) * NN + n_base;
#pragma unroll
    for (int c = 0; c < 8; ++c)
      *(half8*)(Vt + gbase + c * 8) = *(const half8*)&sm.T[wave][lane * 68 + c * 8];
  }
}

// ---------------------------------------------------------------------------
// Kernel 2: flash attention, swapped-operand 32x32x16 MFMA.
// Round-10 verified body (98 us): mask as MFMA C-operand, cvt_pkrtz pack,
// inline-asm v_permlane32_swap_b32 routing, l4 partials.  [unchanged]
// ---------------------------------------------------------------------------
__global__ __launch_bounds__(256, 4) void flash_mfma_kernel(
    const half_t* __restrict__ Qh,   // (B,H,N,D)  (q pre-scaled by 0.125*log2e)
    const half_t* __restrict__ Kh,   // (B,H,N,D)
    const half_t* __restrict__ Vt,   // (B,H,D,N)
    const float*  __restrict__ ms,   // (B,N) pre-scaled: m*log2e - EXP2_OFF
    half_t* __restrict__ O)          // (B,N,C) fp16
{
  __shared__ half_t KV[2][2][64 * 64];   // [buf][K|V][row*64 + e]  32 KB

  const int tid  = threadIdx.x;
  const int wave = tid >> 6;            // 0..3
  const int lane = tid & 63;
  const int l31  = lane & 31;
  const int hi   = lane >> 5;           // 0/1
  const int l7   = lane & 7;

  // XCD-aware decode: blocks with the same head share blockIdx%8 (same XCD)
  const int bid  = blockIdx.x;          // 0..1023
  const int xcd  = bid & 7;
  const int slot = bid >> 3;            // 0..127
  const int qt   = slot & 15;           // 16 q-tiles of 128 rows
  const int head = (slot >> 4) * 8 + xcd;   // 0..63
  const int b    = head >> 3;
  const int h    = head & 7;

  const half_t* Kt_base = Kh + ((((size_t)b * HH + h) * NN) << 6);
  const half_t* Vt_base = Vt + (((size_t)b * HH + h) * DD) * NN;

  // Q B-fragments: q = qt*128 + wave*32 + l31 ; k-dim elem = kd*16 + hi*8 + j
  half8 qf[4];
  {
    const half_t* Qp =
        Qh + ((((size_t)b * HH + h) * NN + qt * 128 + wave * 32 + l31) << 6) + hi * 8;
#pragma unroll
    for (int kd = 0; kd < 4; ++kd) qf[kd] = *(const half8*)(Qp + kd * 16);
  }

  // staging source pointers, pre-swizzled: LDS linear slot sl of row holds
  // source 16B-group (sl ^ (row&7)); row&7 == lane>>3 here.
  const int r8  = lane >> 3;                 // 0..7
  const int dof = ((l7 ^ r8) << 3);          // halfs
  const half_t* kbase = Kt_base + (((size_t)(wave * 16 + r8)) << 6) + dof;
  const half_t* vbase = Vt_base + (size_t)(wave * 16 + r8) * NN + dof;

  // LDS read addrs (bytes), buffer/t offsets added as immediates at use.
  int adK[4], adV[4];
#pragma unroll
  for (int c = 0; c < 4; ++c) {
    adK[c] = l31 * 128 + ((((c << 1) | hi) ^ l7) << 4);
    adV[c] = 8192 + l31 * 128 + ((((c << 1) | hi) ^ l7) << 4);
  }
  const char* L = (const char*)KV;

  floatx16 acc[2];
#pragma unroll
  for (int dt = 0; dt < 2; ++dt)
#pragma unroll
    for (int r = 0; r < 16; ++r) acc[dt][r] = 0.f;
  float l4[4] = {0.f, 0.f, 0.f, 0.f};

  const float* mkb = ms + (size_t)b * NN + hi * 4;

#define STAGE(c, koff, voff)                                                  \
  {                                                                           \
    gld16(kbase + (koff),          &KV[c][0][wave * 1024]);                   \
    gld16(kbase + (koff) + 512,    &KV[c][0][wave * 1024 + 512]);             \
    gld16(vbase + (voff),          &KV[c][1][wave * 1024]);                   \
    gld16(vbase + (voff) + 8 * NN, &KV[c][1][wave * 1024 + 512]);             \
  }

#define COMPUTE(c, moff)                                                      \
  _Pragma("unroll")                                                           \
  for (int t = 0; t < 2; ++t) {                                               \
    floatx16 S;                                                               \
    _Pragma("unroll")                                                         \
    for (int r2 = 0; r2 < 4; ++r2) {                                          \
      fx4 mv = *(const fx4*)(mkb + (moff) + t * 32 + r2 * 8);                 \
      S[r2 * 4 + 0] = mv[0]; S[r2 * 4 + 1] = mv[1];                           \
      S[r2 * 4 + 2] = mv[2]; S[r2 * 4 + 3] = mv[3];                           \
    }                                                                         \
    __builtin_amdgcn_s_setprio(1);                                            \
    _Pragma("unroll")                                                         \
    for (int kd = 0; kd < 4; ++kd) {                                          \
      half8 kf = *(const half8*)(L + (adK[kd] + (c) * 16384 + t * 4096));     \
      S = __builtin_amdgcn_mfma_f32_32x32x16_f16(kf, qf[kd], S, 0, 0, 0);     \
    }                                                                         \
    __builtin_amdgcn_s_setprio(0);                                            \
    _Pragma("unroll")                                                         \
    for (int r = 0; r < 16; ++r) {                                            \
      float p = __builtin_amdgcn_exp2f(S[r]);                                 \
      l4[r & 3] += p;                                                         \
      S[r] = p;                                                               \
    }                                                                         \
    unsigned W[4][2];                                                         \
    _Pragma("unroll")                                                         \
    for (int r2 = 0; r2 < 4; ++r2)                                            \
      _Pragma("unroll")                                                       \
      for (int u = 0; u < 2; ++u) {                                           \
        union { fp16x2 h; unsigned w; } pk;                                   \
        pk.h = __builtin_amdgcn_cvt_pkrtz(S[r2 * 4 + 2 * u],                  \
                                          S[r2 * 4 + 2 * u + 1]);             \
        W[r2][u] = pk.w;                                                      \
      }                                                                       \
    _Pragma("unroll")                                                         \
    for (int ksl = 0; ksl < 2; ++ksl) {                                       \
      unsigned A0 = W[2 * ksl][0],     A1 = W[2 * ksl][1];                    \
      unsigned B0 = W[2 * ksl + 1][0], B1 = W[2 * ksl + 1][1];                \
      asm("v_permlane32_swap_b32 %0, %1" : "+v"(A0), "+v"(B0));               \
      asm("v_permlane32_swap_b32 %0, %1" : "+v"(A1), "+v"(B1));               \
      union { unsigned u4[4]; half8 v; } pw;                                  \
      pw.u4[0] = A0; pw.u4[1] = A1; pw.u4[2] = B0; pw.u4[3] = B1;             \
      const int ks = t * 2 + ksl;                                             \
      __builtin_amdgcn_s_setprio(1);                                          \
      _Pragma("unroll")                                                       \
      for (int dt = 0; dt < 2; ++dt) {                                        \
        half8 vf = *(const half8*)(L + (adV[ks] + (c) * 16384 + dt * 4096));  \
        acc[dt] = __builtin_amdgcn_mfma_f32_32x32x16_f16(pw.v, vf, acc[dt], 0, 0, 0); \
      }                                                                       \
      __builtin_amdgcn_s_setprio(0);                                          \
    }                                                                         \
  }

  // prologue: stage tiles 0 and 1; wait only for tile 0; barrier.
  STAGE(0, 0, 0)
  STAGE(1, 4096, 64)
  asm volatile("s_waitcnt vmcnt(4)");
  __builtin_amdgcn_s_barrier();
  __builtin_amdgcn_sched_barrier(0);
  kbase += 8192; vbase += 128;   // now pointing at tile 2

#pragma unroll 1
  for (int kt2 = 0; kt2 < 15; ++kt2) {   // tiles 0..29; stages tiles 2..31
    COMPUTE(0, 0)
    __builtin_amdgcn_sched_barrier(0);
    __builtin_amdgcn_s_barrier();        // all waves done reading buf 0
    STAGE(0, 0, 0)                       // tile 2*kt2+2 -> buf 0
    asm volatile("s_waitcnt vmcnt(4)");  // stage(2*kt2+1) landed; fresh 4 in flight
    __builtin_amdgcn_s_barrier();
    __builtin_amdgcn_sched_barrier(0);

    COMPUTE(1, 64)
    __builtin_amdgcn_sched_barrier(0);
    __builtin_amdgcn_s_barrier();        // all waves done reading buf 1
    STAGE(1, 4096, 64)                   // tile 2*kt2+3 -> buf 1
    asm volatile("s_waitcnt vmcnt(4)");  // stage(2*kt2+2) landed
    __builtin_amdgcn_s_barrier();
    __builtin_amdgcn_sched_barrier(0);

    kbase += 8192; vbase += 128;
    mkb += 128;
  }

  // tail: tiles 30 (buf 0) and 31 (buf 1); no more staging
  COMPUTE(0, 0)
  asm volatile("s_waitcnt vmcnt(0)");    // stage(31) fully landed
  __builtin_amdgcn_s_barrier();
  __builtin_amdgcn_sched_barrier(0);
  COMPUTE(1, 64)

#undef STAGE
#undef COMPUTE

  // l: combine 4 partials, then sum the two lane-halves (q = lane&31)
  float l_part = (l4[0] + l4[1]) + (l4[2] + l4[3]);
  l_part += __shfl_xor(l_part, 32, 64);

  const size_t orow = (size_t)b * NN + qt * 128 + wave * 32;
#pragma unroll
  for (int r = 0; r < 16; ++r) {
    const int ql  = (r & 3) + 8 * (r >> 2) + 4 * hi;   // 0..31
    const float iv = 1.0f / __shfl(l_part, ql, 64);
    const size_t ro = ((orow + ql) << 9) + (h << 6) + l31;
    O[ro]      = (half_t)(acc[0][r] * iv);
    O[ro + 32] = (half_t)(acc[1][r] * iv);
  }
}

// ---------------------------------------------------------------------------
// Kernel 3: out = O @ W_proj^T + b_proj  (fp16 MFMA, fp32 out)
// 128x64 tile; this round: counted-vmcnt double-buffered staging.
// ---------------------------------------------------------------------------
__global__ __launch_bounds__(256) void proj_mfma_kernel(
    const half_t* __restrict__ Ah,   // (16384, 512) fp16
    const half_t* __restrict__ Bh,   // (512, 512) fp16
    const float* __restrict__ bias,  // (512,)
    float* __restrict__ out)         // (16384, 512)
{
  __shared__ half_t As[2][128 * 32];   // 16 KB
  __shared__ half_t Bs[2][64 * 32];    // 8 KB

  const int tid  = threadIdx.x;
  const int wave = tid >> 6, lane = tid & 63;
  const int L15  = lane & 15, quad = lane >> 4;
  const int wm = (wave & 1) * 64, wn = (wave >> 1) * 32;
  const int m0 = blockIdx.x * 128;
  const int f0 = blockIdx.y * 64;

  const int srow = lane >> 2;
  const int scolh = (lane & 3) * 8;
  const half_t* Ag = Ah + (size_t)(m0 + wave * 16 + srow) * CC + scolh;
  const half_t* Bg = Bh + (size_t)(f0 + wave * 16 + srow) * CC + scolh;

  floatx4 acc[4][2];
#pragma unroll
  for (int i = 0; i < 4; ++i)
#pragma unroll
    for (int j = 0; j < 2; ++j) acc[i][j] = (floatx4){0.f, 0.f, 0.f, 0.f};

#define PSTAGE(c, koff)                                                       \
  {                                                                           \
    gld16(Ag + (koff),           &As[c][(wave * 16) * 32]);                   \
    gld16(Ag + (koff) + 64 * CC, &As[c][(64 + wave * 16) * 32]);              \
    gld16(Bg + (koff),           &Bs[c][(wave * 16) * 32]);                   \
  }

#define PCOMPUTE(c)                                                           \
  {                                                                           \
    half8 af[4], bf[2];                                                       \
    _Pragma("unroll")                                                         \
    for (int mi = 0; mi < 4; ++mi)                                            \
      af[mi] = *(const half8*)&As[c][(wm + mi * 16 + L15) * 32 + quad * 8];   \
    _Pragma("unroll")                                                         \
    for (int ni = 0; ni < 2; ++ni)                                            \
      bf[ni] = *(const half8*)&Bs[c][(wn + ni * 16 + L15) * 32 + quad * 8];   \
    __builtin_amdgcn_s_setprio(1);                                            \
    _Pragma("unroll")                                                         \
    for (int mi = 0; mi < 4; ++mi)                                            \
      _Pragma("unroll")                                                       \
      for (int ni = 0; ni < 2; ++ni)                                          \
        acc[mi][ni] = __builtin_amdgcn_mfma_f32_16x16x32_f16(af[mi], bf[ni], acc[mi][ni], 0, 0, 0); \
    __builtin_amdgcn_s_setprio(0);                                            \
  }

  PSTAGE(0, 0)
  PSTAGE(1, 32)
  asm volatile("s_waitcnt vmcnt(3)");
  __builtin_amdgcn_s_barrier();
  __builtin_amdgcn_sched_barrier(0);

  int k0 = 64;
#pragma unroll 1
  for (int kk = 0; kk < 7; ++kk) {   // computes steps 0..13; stages steps 2..15
    PCOMPUTE(0)
    __builtin_amdgcn_sched_barrier(0);
    __builtin_amdgcn_s_barrier();
    PSTAGE(0, k0)
    asm volatile("s_waitcnt vmcnt(3)");
    __builtin_amdgcn_s_barrier();
    __builtin_amdgcn_sched_barrier(0);

    PCOMPUTE(1)
    __builtin_amdgcn_sched_barrier(0);
    __builtin_amdgcn_s_barrier();
    PSTAGE(1, k0 + 32)
    asm volatile("s_waitcnt vmcnt(3)");
    __builtin_amdgcn_s_barrier();
    __builtin_amdgcn_sched_barrier(0);
    k0 += 64;
  }
  PCOMPUTE(0)
  asm volatile("s_waitcnt vmcnt(0)");
  __builtin_amdgcn_s_barrier();
  __builtin_amdgcn_sched_barrier(0);
  PCOMPUTE(1)

#undef PSTAGE
#undef PCOMPUTE

#pragma unroll
  for (int ni = 0; ni < 2; ++ni) {
    const int f = f0 + wn + ni * 16 + L15;
    const float bv = bias[f];
#pragma unroll
    for (int mi = 0; mi < 4; ++mi)
#pragma unroll
      for (int r = 0; r < 4; ++r)
        out[(size_t)(m0 + wm + mi * 16 + quad * 4 + r) * CC + f] = acc[mi][ni][r] + bv;
  }
}

// ---------------------------------------------------------------------------
extern "C" void kernel_launch(void* const* d_in, const int* in_sizes, int n_in,
                              void* d_out, int out_size, void* d_ws, size_t ws_size,
                              hipStream_t stream) {
  const float* x     = (const float*)d_in[0];
  const float* mask  = (const float*)d_in[1];
  const float* Wqkv  = (const float*)d_in[2];
  const float* Wproj = (const float*)d_in[3];
  const float* bproj = (const float*)d_in[4];
  const int*   ncp   = (const int*)d_in[5];
  float* out = (float*)d_out;

  const size_t per = (size_t)BB * HH * NN * DD;   // 8,388,608
  half_t* xh  = (half_t*)d_ws;
  half_t* Wqh = xh + (size_t)MM * CC;
  half_t* Wph = Wqh + (size_t)FF * CC;
  half_t* Qh  = Wph + (size_t)CC * CC;
  half_t* Kh  = Qh + per;
  half_t* Vt  = Kh + per;
  half_t* Oh  = Vt + per;
  float2* tab = (float2*)(Oh + per);              // 2048*32*8B = 512 KB
  float*  msb = (float*)(tab + (size_t)NN * 32);  // 16384*4B = 64 KB

  prep_kernel<<<dim3(NPREP / 256), 256, 0, stream>>>(x, Wqkv, Wproj, mask, xh, tab, msb);

  qkv_mfma_kernel<<<dim3(MM / 128, FF / 128), 256, 0, stream>>>(xh, Wqh, ncp, tab, Qh, Kh, Vt);
  flash_mfma_kernel<<<dim3(BB * HH * (NN / 128)), 256, 0, stream>>>(Qh, Kh, Vt, msb, Oh);
  proj_mfma_kernel<<<dim3(MM / 128, CC / 64), 256, 0, stream>>>(Oh, Wph, bproj, out);
}

// Round 12
// 231.662 us; speedup vs baseline: 3.7741x; 1.0759x over previous
//
#include <hip/hip_runtime.h>
#include <cmath>

#define BB 8
#define NN 2048
#define CC 512
#define HH 8
#define DD 64
#define FF 1536
#define MM (BB*NN)   // 16384

typedef _Float16 half_t;
typedef __attribute__((ext_vector_type(8))) _Float16 half8;
typedef __attribute__((ext_vector_type(4))) _Float16 half4;
typedef __attribute__((ext_vector_type(2))) __fp16 fp16x2;   // cvt_pkrtz return type
typedef __attribute__((ext_vector_type(4))) float floatx4;
typedef __attribute__((ext_vector_type(16))) float floatx16;
typedef __attribute__((ext_vector_type(4))) float fx4;

#define LOG2E 1.44269504088896f
#define EXP2_OFF 4.3280851f   // 3 * log2(e)

// async global->LDS, 16 B per lane; LDS dest must be wave-uniform base (+lane*16)
typedef const __attribute__((address_space(1))) unsigned int* gas_ptr;
typedef __attribute__((address_space(3))) unsigned int* las_ptr;
__device__ __forceinline__ void gld16(const half_t* g, half_t* l) {
  __builtin_amdgcn_global_load_lds((gas_ptr)g, (las_ptr)l, 16, 0, 0);
}

// ---------------------------------------------------------------------------
// fused prep: fp32->fp16 cvt (x, W_qkv, W_proj) + RoPE table + mask pre-scale
// ---------------------------------------------------------------------------
#define N1 (MM * CC / 8)          // 1,048,576 half8 groups (x)
#define N2 (FF * CC / 8)          // 98,304 (W_qkv)
#define N3 (CC * CC / 8)          // 32,768 (W_proj)
#define NC (N1 + N2 + N3)         // 1,179,648
#define NR (NN * 32)              // 65,536 rope entries
#define NPREP (NC + NR + MM)      // 1,261,568  (/256 = 4928 blocks exactly)
__global__ __launch_bounds__(256) void prep_kernel(
    const float* __restrict__ x, const float* __restrict__ wq,
    const float* __restrict__ wp, const float* __restrict__ mask,
    half_t* __restrict__ d, float2* __restrict__ tab, float* __restrict__ msb) {
  int i = blockIdx.x * 256 + threadIdx.x;
  if (i < NC) {
    const float* s;
    if (i < N1)            s = x  + (size_t)i * 8;
    else if (i < N1 + N2)  s = wq + (size_t)(i - N1) * 8;
    else                   s = wp + (size_t)(i - N1 - N2) * 8;
    float4 a = ((const float4*)s)[0], b = ((const float4*)s)[1];
    half8 h;
    h[0] = (half_t)a.x; h[1] = (half_t)a.y; h[2] = (half_t)a.z; h[3] = (half_t)a.w;
    h[4] = (half_t)b.x; h[5] = (half_t)b.y; h[6] = (half_t)b.z; h[7] = (half_t)b.w;
    ((half8*)d)[i] = h;
  } else if (i < NC + NR) {
    int e = i - NC;
    int p = e >> 5, j = e & 31;
    float ang = (float)p * __powf(10000.0f, -(float)(2 * j) * (1.0f / 64.0f));
    float sv, cv;
    __sincosf(ang, &sv, &cv);
    tab[e] = make_float2(cv, sv);
  } else {
    int k = i - NC - NR;
    msb[k] = mask[k] * LOG2E - EXP2_OFF;
  }
}

// ---------------------------------------------------------------------------
// Kernel 1: qkv = x @ W_qkv^T  (fp16 MFMA, 128x128 tile, BK=32, 4 waves)
// Counted-vmcnt double-buffered staging; swapped-operand MFMA epilogue.
// This round: __launch_bounds__(256,4) caps VGPR at 128 (was 132) -> 4 blk/CU.
// ---------------------------------------------------------------------------
__global__ __launch_bounds__(256, 4) void qkv_mfma_kernel(
    const half_t* __restrict__ Ah,   // (16384, 512)
    const half_t* __restrict__ Bh,   // (1536, 512)
    const int*   __restrict__ ncp,
    const float2* __restrict__ tab,  // (2048, 32) cos/sin
    half_t* __restrict__ Qh, half_t* __restrict__ Kh, half_t* __restrict__ Vt)
{
  __shared__ union {
    struct { half_t A[2][128 * 32]; half_t B[2][128 * 32]; } s;   // 32 KB
    half_t T[4][64 * 68];                                         // 34.8 KB
  } sm;

  const int tid  = threadIdx.x;
  const int wave = tid >> 6, lane = tid & 63;
  const int L15  = lane & 15, quad = lane >> 4;
  const int wm = (wave & 1) * 64, wn = (wave >> 1) * 64;
  const int m0 = blockIdx.x * 128;
  const int f0 = blockIdx.y * 128;

  const int srow = lane >> 2;            // 0..15
  const int scolh = (lane & 3) * 8;      // half offset within row
  const half_t* Ag = Ah + (size_t)(m0 + wave * 16 + srow) * CC + scolh;
  const half_t* Bg = Bh + (size_t)(f0 + wave * 16 + srow) * CC + scolh;

  floatx4 acc[4][4];
#pragma unroll
  for (int i = 0; i < 4; ++i)
#pragma unroll
    for (int j = 0; j < 4; ++j) acc[i][j] = (floatx4){0.f, 0.f, 0.f, 0.f};

#define QSTAGE(c, koff)                                                       \
  {                                                                           \
    gld16(Ag + (koff),           &sm.s.A[c][(wave * 16) * 32]);               \
    gld16(Ag + (koff) + 64 * CC, &sm.s.A[c][(64 + wave * 16) * 32]);          \
    gld16(Bg + (koff),           &sm.s.B[c][(wave * 16) * 32]);               \
    gld16(Bg + (koff) + 64 * CC, &sm.s.B[c][(64 + wave * 16) * 32]);          \
  }

#define QCOMPUTE(c)                                                           \
  {                                                                           \
    half8 af[4], bf[4];                                                       \
    _Pragma("unroll")                                                         \
    for (int mi = 0; mi < 4; ++mi)                                            \
      af[mi] = *(const half8*)&sm.s.A[c][(wm + mi * 16 + L15) * 32 + quad * 8]; \
    _Pragma("unroll")                                                         \
    for (int ni = 0; ni < 4; ++ni)                                            \
      bf[ni] = *(const half8*)&sm.s.B[c][(wn + ni * 16 + L15) * 32 + quad * 8]; \
    __builtin_amdgcn_s_setprio(1);                                            \
    _Pragma("unroll")                                                         \
    for (int mi = 0; mi < 4; ++mi)                                            \
      _Pragma("unroll")                                                       \
      for (int ni = 0; ni < 4; ++ni)                                          \
        acc[mi][ni] = __builtin_amdgcn_mfma_f32_16x16x32_f16(bf[ni], af[mi], acc[mi][ni], 0, 0, 0); \
    __builtin_amdgcn_s_setprio(0);                                            \
  }

  // prologue: stage k-steps 0 and 1; wait only for step 0; barrier.
  QSTAGE(0, 0)
  QSTAGE(1, 32)
  asm volatile("s_waitcnt vmcnt(4)");
  __builtin_amdgcn_s_barrier();
  __builtin_amdgcn_sched_barrier(0);

  int k0 = 64;   // next k-step to stage
#pragma unroll 1
  for (int kk = 0; kk < 7; ++kk) {   // computes steps 0..13; stages steps 2..15
    QCOMPUTE(0)
    __builtin_amdgcn_sched_barrier(0);
    __builtin_amdgcn_s_barrier();        // all waves done reading buf 0
    QSTAGE(0, k0)
    asm volatile("s_waitcnt vmcnt(4)");  // previous stage landed; fresh 4 in flight
    __builtin_amdgcn_s_barrier();
    __builtin_amdgcn_sched_barrier(0);

    QCOMPUTE(1)
    __builtin_amdgcn_sched_barrier(0);
    __builtin_amdgcn_s_barrier();
    QSTAGE(1, k0 + 32)
    asm volatile("s_waitcnt vmcnt(4)");
    __builtin_amdgcn_s_barrier();
    __builtin_amdgcn_sched_barrier(0);
    k0 += 64;
  }
  // tail: steps 14 (buf 0) and 15 (buf 1); no more staging
  QCOMPUTE(0)
  asm volatile("s_waitcnt vmcnt(0)");
  __builtin_amdgcn_s_barrier();
  __builtin_amdgcn_sched_barrier(0);
  QCOMPUTE(1)

#undef QSTAGE
#undef QCOMPUTE
  // acc[mi][ni][r] = out[n = m0+wm+mi*16+L15][f = f0+wn+ni*16+quad*4+r]

  const int which = f0 >> 9;         // block-uniform (128 | 512)
  const int b     = m0 >> 11;        // block-uniform
  const int n_base = (m0 & 2047) + wm;
  const int h     = ((f0 + wn) >> 6) & 7;   // wave-uniform head

  if (which < 2) {
    const int nc = *ncp;
    half_t* dst = which ? Kh : Qh;
    const float qscale = which ? 1.0f : (0.125f * LOG2E);
    const float* tabf = (const float*)tab;
#pragma unroll
    for (int mi = 0; mi < 4; ++mi) {
      const int n = n_base + mi * 16 + L15;
      const int p = n - nc;
      const size_t rbase = (((size_t)(b * HH + h) * NN + n) << 6) + quad * 4;
#pragma unroll
      for (int ni = 0; ni < 4; ++ni) {
        float o0 = acc[mi][ni][0], o1 = acc[mi][ni][1];
        float o2 = acc[mi][ni][2], o3 = acc[mi][ni][3];
        if (p >= 0) {
          const fx4 c4 = *(const fx4*)(tabf + p * 64 + ni * 16 + quad * 4);
          const float e0 = o0, e1 = o1, e2 = o2, e3 = o3;
          o0 = e0 * c4[0] - e1 * c4[1];
          o1 = e0 * c4[1] + e1 * c4[0];
          o2 = e2 * c4[2] - e3 * c4[3];
          o3 = e2 * c4[3] + e3 * c4[2];
        }
        half4 hv;
        hv[0] = (half_t)(o0 * qscale); hv[1] = (half_t)(o1 * qscale);
        hv[2] = (half_t)(o2 * qscale); hv[3] = (half_t)(o3 * qscale);
        *(half4*)(dst + rbase + ni * 16) = hv;
      }
    }
  } else {
    // V: per-wave 64x64 transpose through LDS -> (B,H,D,N)
    __syncthreads();   // all waves done reading sm.s (union overwrite)
#pragma unroll
    for (int ni = 0; ni < 4; ++ni)
#pragma unroll
      for (int mi = 0; mi < 4; ++mi)
#pragma unroll
        for (int r = 0; r < 4; ++r)
          sm.T[wave][(ni * 16 + quad * 4 + r) * 68 + mi * 16 + L15] = (half_t)acc[mi][ni][r];
    __syncthreads();
    const size_t gbase = ((size_t)(b * HH + h) * DD + lane) * NN + n_base;
#pragma unroll
    for (int c = 0; c < 8; ++c)
      *(half8*)(Vt + gbase + c * 8) = *(const half8*)&sm.T[wave][lane * 68 + c * 8];
  }
}

// ---------------------------------------------------------------------------
// Kernel 2: flash attention, swapped-operand 32x32x16 MFMA.
// This round: mask row staged to LDS ONCE in the prologue (2 gld16), read
// per-phase via ds_read (broadcast). This removes the per-phase global mask
// loads from the vmcnt stream: in-order vmcnt retirement meant every mask
// wait transitively drained the just-issued stage loads, defeating the
// counted-vmcnt pipeline since round 2. LDS 40960 B = exactly 4 blocks/CU.
// ---------------------------------------------------------------------------
__global__ __launch_bounds__(256, 4) void flash_mfma_kernel(
    const half_t* __restrict__ Qh,   // (B,H,N,D)  (q pre-scaled by 0.125*log2e)
    const half_t* __restrict__ Kh,   // (B,H,N,D)
    const half_t* __restrict__ Vt,   // (B,H,D,N)
    const float*  __restrict__ ms,   // (B,N) pre-scaled: m*log2e - EXP2_OFF
    half_t* __restrict__ O)          // (B,N,C) fp16
{
  __shared__ half_t KV[2][2][64 * 64];   // [buf][K|V][row*64 + e]  32 KB
  __shared__ __align__(16) float Ms[2048];   // 8 KB: block's full mask row

  const int tid  = threadIdx.x;
  const int wave = tid >> 6;            // 0..3
  const int lane = tid & 63;
  const int l31  = lane & 31;
  const int hi   = lane >> 5;           // 0/1
  const int l7   = lane & 7;

  // XCD-aware decode: blocks with the same head share blockIdx%8 (same XCD)
  const int bid  = blockIdx.x;          // 0..1023
  const int xcd  = bid & 7;
  const int slot = bid >> 3;            // 0..127
  const int qt   = slot & 15;           // 16 q-tiles of 128 rows
  const int head = (slot >> 4) * 8 + xcd;   // 0..63
  const int b    = head >> 3;
  const int h    = head & 7;

  const half_t* Kt_base = Kh + ((((size_t)b * HH + h) * NN) << 6);
  const half_t* Vt_base = Vt + (((size_t)b * HH + h) * DD) * NN;

  // Q B-fragments: q = qt*128 + wave*32 + l31 ; k-dim elem = kd*16 + hi*8 + j
  half8 qf[4];
  {
    const half_t* Qp =
        Qh + ((((size_t)b * HH + h) * NN + qt * 128 + wave * 32 + l31) << 6) + hi * 8;
#pragma unroll
    for (int kd = 0; kd < 4; ++kd) qf[kd] = *(const half8*)(Qp + kd * 16);
  }

  // staging source pointers, pre-swizzled: LDS linear slot sl of row holds
  // source 16B-group (sl ^ (row&7)); row&7 == lane>>3 here.
  const int r8  = lane >> 3;                 // 0..7
  const int dof = ((l7 ^ r8) << 3);          // halfs
  const half_t* kbase = Kt_base + (((size_t)(wave * 16 + r8)) << 6) + dof;
  const half_t* vbase = Vt_base + (size_t)(wave * 16 + r8) * NN + dof;

  // LDS read addrs (bytes), buffer/t offsets added as immediates at use.
  int adK[4], adV[4];
#pragma unroll
  for (int c = 0; c < 4; ++c) {
    adK[c] = l31 * 128 + ((((c << 1) | hi) ^ l7) << 4);
    adV[c] = 8192 + l31 * 128 + ((((c << 1) | hi) ^ l7) << 4);
  }
  const char* L = (const char*)KV;

  floatx16 acc[2];
#pragma unroll
  for (int dt = 0; dt < 2; ++dt)
#pragma unroll
    for (int r = 0; r < 16; ++r) acc[dt][r] = 0.f;
  float l4[4] = {0.f, 0.f, 0.f, 0.f};

#define STAGE(c, koff, voff)                                                  \
  {                                                                           \
    gld16(kbase + (koff),          &KV[c][0][wave * 1024]);                   \
    gld16(kbase + (koff) + 512,    &KV[c][0][wave * 1024 + 512]);             \
    gld16(vbase + (voff),          &KV[c][1][wave * 1024]);                   \
    gld16(vbase + (voff) + 8 * NN, &KV[c][1][wave * 1024 + 512]);             \
  }

// mask LDS byte offset per t-phase: mls(base,kt) + moffB(0/256) + t*128 + r2*32
#define COMPUTE(c, moffB)                                                     \
  _Pragma("unroll")                                                           \
  for (int t = 0; t < 2; ++t) {                                               \
    floatx16 S;                                                               \
    _Pragma("unroll")                                                         \
    for (int r2 = 0; r2 < 4; ++r2) {                                          \
      fx4 mv = *(const fx4*)((const char*)Ms + mls + (moffB) + t * 128 + r2 * 32); \
      S[r2 * 4 + 0] = mv[0]; S[r2 * 4 + 1] = mv[1];                           \
      S[r2 * 4 + 2] = mv[2]; S[r2 * 4 + 3] = mv[3];                           \
    }                                                                         \
    __builtin_amdgcn_s_setprio(1);                                            \
    _Pragma("unroll")                                                         \
    for (int kd = 0; kd < 4; ++kd) {                                          \
      half8 kf = *(const half8*)(L + (adK[kd] + (c) * 16384 + t * 4096));     \
      S = __builtin_amdgcn_mfma_f32_32x32x16_f16(kf, qf[kd], S, 0, 0, 0);     \
    }                                                                         \
    __builtin_amdgcn_s_setprio(0);                                            \
    _Pragma("unroll")                                                         \
    for (int r = 0; r < 16; ++r) {                                            \
      float p = __builtin_amdgcn_exp2f(S[r]);                                 \
      l4[r & 3] += p;                                                         \
      S[r] = p;                                                               \
    }                                                                         \
    unsigned W[4][2];                                                         \
    _Pragma("unroll")                                                         \
    for (int r2 = 0; r2 < 4; ++r2)                                            \
      _Pragma("unroll")                                                       \
      for (int u = 0; u < 2; ++u) {                                           \
        union { fp16x2 h; unsigned w; } pk;                                   \
        pk.h = __builtin_amdgcn_cvt_pkrtz(S[r2 * 4 + 2 * u],                  \
                                          S[r2 * 4 + 2 * u + 1]);             \
        W[r2][u] = pk.w;                                                      \
      }                                                                       \
    _Pragma("unroll")                                                         \
    for (int ksl = 0; ksl < 2; ++ksl) {                                       \
      unsigned A0 = W[2 * ksl][0],     A1 = W[2 * ksl][1];                    \
      unsigned B0 = W[2 * ksl + 1][0], B1 = W[2 * ksl + 1][1];                \
      asm("v_permlane32_swap_b32 %0, %1" : "+v"(A0), "+v"(B0));               \
      asm("v_permlane32_swap_b32 %0, %1" : "+v"(A1), "+v"(B1));               \
      union { unsigned u4[4]; half8 v; } pw;                                  \
      pw.u4[0] = A0; pw.u4[1] = A1; pw.u4[2] = B0; pw.u4[3] = B1;             \
      const int ks = t * 2 + ksl;                                             \
      __builtin_amdgcn_s_setprio(1);                                          \
      _Pragma("unroll")                                                       \
      for (int dt = 0; dt < 2; ++dt) {                                        \
        half8 vf = *(const half8*)(L + (adV[ks] + (c) * 16384 + dt * 4096));  \
        acc[dt] = __builtin_amdgcn_mfma_f32_32x32x16_f16(pw.v, vf, acc[dt], 0, 0, 0); \
      }                                                                       \
      __builtin_amdgcn_s_setprio(0);                                          \
    }                                                                         \
  }

  // prologue: stage K/V tiles 0,1 AND the full mask row; wait; barrier.
  STAGE(0, 0, 0)
  {
    // mask: 2048 floats = 8 KB; wave stages its 2048-B chunk with 2 gld16
    const half_t* msrc = (const half_t*)(ms + (size_t)b * NN + wave * 512 + lane * 4);
    gld16(msrc,                    (half_t*)Ms + wave * 1024);
    gld16(msrc + 512,              (half_t*)Ms + wave * 1024 + 512);  // +256 floats
  }
  STAGE(1, 4096, 64)
  asm volatile("s_waitcnt vmcnt(4)");   // STAGE(0)+mask retired; STAGE(1) in flight
  __builtin_amdgcn_s_barrier();
  __builtin_amdgcn_sched_barrier(0);
  kbase += 8192; vbase += 128;   // now pointing at tile 2

  int mls = hi * 16;   // mask LDS byte base (walks 512 B per kt2 iter)
#pragma unroll 1
  for (int kt2 = 0; kt2 < 15; ++kt2) {   // tiles 0..29; stages tiles 2..31
    COMPUTE(0, 0)
    __builtin_amdgcn_sched_barrier(0);
    __builtin_amdgcn_s_barrier();        // all waves done reading buf 0
    STAGE(0, 0, 0)                       // tile 2*kt2+2 -> buf 0
    asm volatile("s_waitcnt vmcnt(4)");  // stage(2*kt2+1) landed; fresh 4 in flight
    __builtin_amdgcn_s_barrier();
    __builtin_amdgcn_sched_barrier(0);

    COMPUTE(1, 256)
    __builtin_amdgcn_sched_barrier(0);
    __builtin_amdgcn_s_barrier();        // all waves done reading buf 1
    STAGE(1, 4096, 64)                   // tile 2*kt2+3 -> buf 1
    asm volatile("s_waitcnt vmcnt(4)");  // stage(2*kt2+2) landed
    __builtin_amdgcn_s_barrier();
    __builtin_amdgcn_sched_barrier(0);

    kbase += 8192; vbase += 128;
    mls += 512;
  }

  // tail: tiles 30 (buf 0) and 31 (buf 1); no more staging
  COMPUTE(0, 0)
  asm volatile("s_waitcnt vmcnt(0)");    // stage(31) fully landed
  __builtin_amdgcn_s_barrier();
  __builtin_amdgcn_sched_barrier(0);
  COMPUTE(1, 256)

#undef STAGE
#undef COMPUTE

  // l: combine 4 partials, then sum the two lane-halves (q = lane&31)
  float l_part = (l4[0] + l4[1]) + (l4[2] + l4[3]);
  l_part += __shfl_xor(l_part, 32, 64);

  const size_t orow = (size_t)b * NN + qt * 128 + wave * 32;
#pragma unroll
  for (int r = 0; r < 16; ++r) {
    const int ql  = (r & 3) + 8 * (r >> 2) + 4 * hi;   // 0..31
    const float iv = 1.0f / __shfl(l_part, ql, 64);
    const size_t ro = ((orow + ql) << 9) + (h << 6) + l31;
    O[ro]      = (half_t)(acc[0][r] * iv);
    O[ro + 32] = (half_t)(acc[1][r] * iv);
  }
}

// ---------------------------------------------------------------------------
// Kernel 3: out = O @ W_proj^T + b_proj  (fp16 MFMA, fp32 out)
// 128x64 tile, counted-vmcnt double-buffered staging.  [unchanged]
// ---------------------------------------------------------------------------
__global__ __launch_bounds__(256) void proj_mfma_kernel(
    const half_t* __restrict__ Ah,   // (16384, 512) fp16
    const half_t* __restrict__ Bh,   // (512, 512) fp16
    const float* __restrict__ bias,  // (512,)
    float* __restrict__ out)         // (16384, 512)
{
  __shared__ half_t As[2][128 * 32];   // 16 KB
  __shared__ half_t Bs[2][64 * 32];    // 8 KB

  const int tid  = threadIdx.x;
  const int wave = tid >> 6, lane = tid & 63;
  const int L15  = lane & 15, quad = lane >> 4;
  const int wm = (wave & 1) * 64, wn = (wave >> 1) * 32;
  const int m0 = blockIdx.x * 128;
  const int f0 = blockIdx.y * 64;

  const int srow = lane >> 2;
  const int scolh = (lane & 3) * 8;
  const half_t* Ag = Ah + (size_t)(m0 + wave * 16 + srow) * CC + scolh;
  const half_t* Bg = Bh + (size_t)(f0 + wave * 16 + srow) * CC + scolh;

  floatx4 acc[4][2];
#pragma unroll
  for (int i = 0; i < 4; ++i)
#pragma unroll
    for (int j = 0; j < 2; ++j) acc[i][j] = (floatx4){0.f, 0.f, 0.f, 0.f};

#define PSTAGE(c, koff)                                                       \
  {                                                                           \
    gld16(Ag + (koff),           &As[c][(wave * 16) * 32]);                   \
    gld16(Ag + (koff) + 64 * CC, &As[c][(64 + wave * 16) * 32]);              \
    gld16(Bg + (koff),           &Bs[c][(wave * 16) * 32]);                   \
  }

#define PCOMPUTE(c)                                                           \
  {                                                                           \
    half8 af[4], bf[2];                                                       \
    _Pragma("unroll")                                                         \
    for (int mi = 0; mi < 4; ++mi)                                            \
      af[mi] = *(const half8*)&As[c][(wm + mi * 16 + L15) * 32 + quad * 8];   \
    _Pragma("unroll")                                                         \
    for (int ni = 0; ni < 2; ++ni)                                            \
      bf[ni] = *(const half8*)&Bs[c][(wn + ni * 16 + L15) * 32 + quad * 8];   \
    __builtin_amdgcn_s_setprio(1);                                            \
    _Pragma("unroll")                                                         \
    for (int mi = 0; mi < 4; ++mi)                                            \
      _Pragma("unroll")                                                       \
      for (int ni = 0; ni < 2; ++ni)                                          \
        acc[mi][ni] = __builtin_amdgcn_mfma_f32_16x16x32_f16(af[mi], bf[ni], acc[mi][ni], 0, 0, 0); \
    __builtin_amdgcn_s_setprio(0);                                            \
  }

  PSTAGE(0, 0)
  PSTAGE(1, 32)
  asm volatile("s_waitcnt vmcnt(3)");
  __builtin_amdgcn_s_barrier();
  __builtin_amdgcn_sched_barrier(0);

  int k0 = 64;
#pragma unroll 1
  for (int kk = 0; kk < 7; ++kk) {   // computes steps 0..13; stages steps 2..15
    PCOMPUTE(0)
    __builtin_amdgcn_sched_barrier(0);
    __builtin_amdgcn_s_barrier();
    PSTAGE(0, k0)
    asm volatile("s_waitcnt vmcnt(3)");
    __builtin_amdgcn_s_barrier();
    __builtin_amdgcn_sched_barrier(0);

    PCOMPUTE(1)
    __builtin_amdgcn_sched_barrier(0);
    __builtin_amdgcn_s_barrier();
    PSTAGE(1, k0 + 32)
    asm volatile("s_waitcnt vmcnt(3)");
    __builtin_amdgcn_s_barrier();
    __builtin_amdgcn_sched_barrier(0);
    k0 += 64;
  }
  PCOMPUTE(0)
  asm volatile("s_waitcnt vmcnt(0)");
  __builtin_amdgcn_s_barrier();
  __builtin_amdgcn_sched_barrier(0);
  PCOMPUTE(1)

#undef PSTAGE
#undef PCOMPUTE

#pragma unroll
  for (int ni = 0; ni < 2; ++ni) {
    const int f = f0 + wn + ni * 16 + L15;
    const float bv = bias[f];
#pragma unroll
    for (int mi = 0; mi < 4; ++mi)
#pragma unroll
      for (int r = 0; r < 4; ++r)
        out[(size_t)(m0 + wm + mi * 16 + quad * 4 + r) * CC + f] = acc[mi][ni][r] + bv;
  }
}

// ---------------------------------------------------------------------------
extern "C" void kernel_launch(void* const* d_in, const int* in_sizes, int n_in,
                              void* d_out, int out_size, void* d_ws, size_t ws_size,
                              hipStream_t stream) {
  const float* x     = (const float*)d_in[0];
  const float* mask  = (const float*)d_in[1];
  const float* Wqkv  = (const float*)d_in[2];
  const float* Wproj = (const float*)d_in[3];
  const float* bproj = (const float*)d_in[4];
  const int*   ncp   = (const int*)d_in[5];
  float* out = (float*)d_out;

  const size_t per = (size_t)BB * HH * NN * DD;   // 8,388,608
  half_t* xh  = (half_t*)d_ws;
  half_t* Wqh = xh + (size_t)MM * CC;
  half_t* Wph = Wqh + (size_t)FF * CC;
  half_t* Qh  = Wph + (size_t)CC * CC;
  half_t* Kh  = Qh + per;
  half_t* Vt  = Kh + per;
  half_t* Oh  = Vt + per;
  float2* tab = (float2*)(Oh + per);              // 2048*32*8B = 512 KB
  float*  msb = (float*)(tab + (size_t)NN * 32);  // 16384*4B = 64 KB

  prep_kernel<<<dim3(NPREP / 256), 256, 0, stream>>>(x, Wqkv, Wproj, mask, xh, tab, msb);

  qkv_mfma_kernel<<<dim3(MM / 128, FF / 128), 256, 0, stream>>>(xh, Wqh, ncp, tab, Qh, Kh, Vt);
  flash_mfma_kernel<<<dim3(BB * HH * (NN / 128)), 256, 0, stream>>>(Qh, Kh, Vt, msb, Oh);
  proj_mfma_kernel<<<dim3(MM / 128, CC / 64), 256, 0, stream>>>(Oh, Wph, bproj, out);
}

// Round 13
// 231.565 us; speedup vs baseline: 3.7757x; 1.0004x over previous
//
#include <hip/hip_runtime.h>
#include <cmath>

#define BB 8
#define NN 2048
#define CC 512
#define HH 8
#define DD 64
#define FF 1536
#define MM (BB*NN)   // 16384

typedef _Float16 half_t;
typedef __attribute__((ext_vector_type(8))) _Float16 half8;
typedef __attribute__((ext_vector_type(4))) _Float16 half4;
typedef __attribute__((ext_vector_type(2))) __fp16 fp16x2;   // cvt_pkrtz return type
typedef __attribute__((ext_vector_type(4))) float floatx4;
typedef __attribute__((ext_vector_type(16))) float floatx16;
typedef __attribute__((ext_vector_type(4))) float fx4;

#define LOG2E 1.44269504088896f
#define EXP2_OFF 4.3280851f   // 3 * log2(e)

// async global->LDS, 16 B per lane; LDS dest must be wave-uniform base (+lane*16)
typedef const __attribute__((address_space(1))) unsigned int* gas_ptr;
typedef __attribute__((address_space(3))) unsigned int* las_ptr;
__device__ __forceinline__ void gld16(const half_t* g, half_t* l) {
  __builtin_amdgcn_global_load_lds((gas_ptr)g, (las_ptr)l, 16, 0, 0);
}

// ---------------------------------------------------------------------------
// fused prep: fp32->fp16 cvt (x, W_qkv, W_proj) + RoPE table + mask pre-scale
// ---------------------------------------------------------------------------
#define N1 (MM * CC / 8)          // 1,048,576 half8 groups (x)
#define N2 (FF * CC / 8)          // 98,304 (W_qkv)
#define N3 (CC * CC / 8)          // 32,768 (W_proj)
#define NC (N1 + N2 + N3)         // 1,179,648
#define NR (NN * 32)              // 65,536 rope entries
#define NPREP (NC + NR + MM)      // 1,261,568  (/256 = 4928 blocks exactly)
__global__ __launch_bounds__(256) void prep_kernel(
    const float* __restrict__ x, const float* __restrict__ wq,
    const float* __restrict__ wp, const float* __restrict__ mask,
    half_t* __restrict__ d, float2* __restrict__ tab, float* __restrict__ msb) {
  int i = blockIdx.x * 256 + threadIdx.x;
  if (i < NC) {
    const float* s;
    if (i < N1)            s = x  + (size_t)i * 8;
    else if (i < N1 + N2)  s = wq + (size_t)(i - N1) * 8;
    else                   s = wp + (size_t)(i - N1 - N2) * 8;
    float4 a = ((const float4*)s)[0], b = ((const float4*)s)[1];
    half8 h;
    h[0] = (half_t)a.x; h[1] = (half_t)a.y; h[2] = (half_t)a.z; h[3] = (half_t)a.w;
    h[4] = (half_t)b.x; h[5] = (half_t)b.y; h[6] = (half_t)b.z; h[7] = (half_t)b.w;
    ((half8*)d)[i] = h;
  } else if (i < NC + NR) {
    int e = i - NC;
    int p = e >> 5, j = e & 31;
    float ang = (float)p * __powf(10000.0f, -(float)(2 * j) * (1.0f / 64.0f));
    float sv, cv;
    __sincosf(ang, &sv, &cv);
    tab[e] = make_float2(cv, sv);
  } else {
    int k = i - NC - NR;
    msb[k] = mask[k] * LOG2E - EXP2_OFF;
  }
}

// ---------------------------------------------------------------------------
// Kernel 1: qkv = x @ W_qkv^T  (fp16 MFMA, 128x128 tile, BK=32, 4 waves)
// Counted-vmcnt double-buffered staging; swapped-operand MFMA epilogue.
// __launch_bounds__(256,4) caps VGPR at 128 -> 4 blk/CU.  [unchanged]
// ---------------------------------------------------------------------------
__global__ __launch_bounds__(256, 4) void qkv_mfma_kernel(
    const half_t* __restrict__ Ah,   // (16384, 512)
    const half_t* __restrict__ Bh,   // (1536, 512)
    const int*   __restrict__ ncp,
    const float2* __restrict__ tab,  // (2048, 32) cos/sin
    half_t* __restrict__ Qh, half_t* __restrict__ Kh, half_t* __restrict__ Vt)
{
  __shared__ union {
    struct { half_t A[2][128 * 32]; half_t B[2][128 * 32]; } s;   // 32 KB
    half_t T[4][64 * 68];                                         // 34.8 KB
  } sm;

  const int tid  = threadIdx.x;
  const int wave = tid >> 6, lane = tid & 63;
  const int L15  = lane & 15, quad = lane >> 4;
  const int wm = (wave & 1) * 64, wn = (wave >> 1) * 64;
  const int m0 = blockIdx.x * 128;
  const int f0 = blockIdx.y * 128;

  const int srow = lane >> 2;            // 0..15
  const int scolh = (lane & 3) * 8;      // half offset within row
  const half_t* Ag = Ah + (size_t)(m0 + wave * 16 + srow) * CC + scolh;
  const half_t* Bg = Bh + (size_t)(f0 + wave * 16 + srow) * CC + scolh;

  floatx4 acc[4][4];
#pragma unroll
  for (int i = 0; i < 4; ++i)
#pragma unroll
    for (int j = 0; j < 4; ++j) acc[i][j] = (floatx4){0.f, 0.f, 0.f, 0.f};

#define QSTAGE(c, koff)                                                       \
  {                                                                           \
    gld16(Ag + (koff),           &sm.s.A[c][(wave * 16) * 32]);               \
    gld16(Ag + (koff) + 64 * CC, &sm.s.A[c][(64 + wave * 16) * 32]);          \
    gld16(Bg + (koff),           &sm.s.B[c][(wave * 16) * 32]);               \
    gld16(Bg + (koff) + 64 * CC, &sm.s.B[c][(64 + wave * 16) * 32]);          \
  }

#define QCOMPUTE(c)                                                           \
  {                                                                           \
    half8 af[4], bf[4];                                                       \
    _Pragma("unroll")                                                         \
    for (int mi = 0; mi < 4; ++mi)                                            \
      af[mi] = *(const half8*)&sm.s.A[c][(wm + mi * 16 + L15) * 32 + quad * 8]; \
    _Pragma("unroll")                                                         \
    for (int ni = 0; ni < 4; ++ni)                                            \
      bf[ni] = *(const half8*)&sm.s.B[c][(wn + ni * 16 + L15) * 32 + quad * 8]; \
    __builtin_amdgcn_s_setprio(1);                                            \
    _Pragma("unroll")                                                         \
    for (int mi = 0; mi < 4; ++mi)                                            \
      _Pragma("unroll")                                                       \
      for (int ni = 0; ni < 4; ++ni)                                          \
        acc[mi][ni] = __builtin_amdgcn_mfma_f32_16x16x32_f16(bf[ni], af[mi], acc[mi][ni], 0, 0, 0); \
    __builtin_amdgcn_s_setprio(0);                                            \
  }

  // prologue: stage k-steps 0 and 1; wait only for step 0; barrier.
  QSTAGE(0, 0)
  QSTAGE(1, 32)
  asm volatile("s_waitcnt vmcnt(4)");
  __builtin_amdgcn_s_barrier();
  __builtin_amdgcn_sched_barrier(0);

  int k0 = 64;   // next k-step to stage
#pragma unroll 1
  for (int kk = 0; kk < 7; ++kk) {   // computes steps 0..13; stages steps 2..15
    QCOMPUTE(0)
    __builtin_amdgcn_sched_barrier(0);
    __builtin_amdgcn_s_barrier();        // all waves done reading buf 0
    QSTAGE(0, k0)
    asm volatile("s_waitcnt vmcnt(4)");  // previous stage landed; fresh 4 in flight
    __builtin_amdgcn_s_barrier();
    __builtin_amdgcn_sched_barrier(0);

    QCOMPUTE(1)
    __builtin_amdgcn_sched_barrier(0);
    __builtin_amdgcn_s_barrier();
    QSTAGE(1, k0 + 32)
    asm volatile("s_waitcnt vmcnt(4)");
    __builtin_amdgcn_s_barrier();
    __builtin_amdgcn_sched_barrier(0);
    k0 += 64;
  }
  // tail: steps 14 (buf 0) and 15 (buf 1); no more staging
  QCOMPUTE(0)
  asm volatile("s_waitcnt vmcnt(0)");
  __builtin_amdgcn_s_barrier();
  __builtin_amdgcn_sched_barrier(0);
  QCOMPUTE(1)

#undef QSTAGE
#undef QCOMPUTE
  // acc[mi][ni][r] = out[n = m0+wm+mi*16+L15][f = f0+wn+ni*16+quad*4+r]

  const int which = f0 >> 9;         // block-uniform (128 | 512)
  const int b     = m0 >> 11;        // block-uniform
  const int n_base = (m0 & 2047) + wm;
  const int h     = ((f0 + wn) >> 6) & 7;   // wave-uniform head

  if (which < 2) {
    const int nc = *ncp;
    half_t* dst = which ? Kh : Qh;
    const float qscale = which ? 1.0f : (0.125f * LOG2E);
    const float* tabf = (const float*)tab;
#pragma unroll
    for (int mi = 0; mi < 4; ++mi) {
      const int n = n_base + mi * 16 + L15;
      const int p = n - nc;
      const size_t rbase = (((size_t)(b * HH + h) * NN + n) << 6) + quad * 4;
#pragma unroll
      for (int ni = 0; ni < 4; ++ni) {
        float o0 = acc[mi][ni][0], o1 = acc[mi][ni][1];
        float o2 = acc[mi][ni][2], o3 = acc[mi][ni][3];
        if (p >= 0) {
          const fx4 c4 = *(const fx4*)(tabf + p * 64 + ni * 16 + quad * 4);
          const float e0 = o0, e1 = o1, e2 = o2, e3 = o3;
          o0 = e0 * c4[0] - e1 * c4[1];
          o1 = e0 * c4[1] + e1 * c4[0];
          o2 = e2 * c4[2] - e3 * c4[3];
          o3 = e2 * c4[3] + e3 * c4[2];
        }
        half4 hv;
        hv[0] = (half_t)(o0 * qscale); hv[1] = (half_t)(o1 * qscale);
        hv[2] = (half_t)(o2 * qscale); hv[3] = (half_t)(o3 * qscale);
        *(half4*)(dst + rbase + ni * 16) = hv;
      }
    }
  } else {
    // V: per-wave 64x64 transpose through LDS -> (B,H,D,N)
    __syncthreads();   // all waves done reading sm.s (union overwrite)
#pragma unroll
    for (int ni = 0; ni < 4; ++ni)
#pragma unroll
      for (int mi = 0; mi < 4; ++mi)
#pragma unroll
        for (int r = 0; r < 4; ++r)
          sm.T[wave][(ni * 16 + quad * 4 + r) * 68 + mi * 16 + L15] = (half_t)acc[mi][ni][r];
    __syncthreads();
    const size_t gbase = ((size_t)(b * HH + h) * DD + lane) * NN + n_base;
#pragma unroll
    for (int c = 0; c < 8; ++c)
      *(half8*)(Vt + gbase + c * 8) = *(const half8*)&sm.T[wave][lane * 68 + c * 8];
  }
}

// ---------------------------------------------------------------------------
// Kernel 2: flash attention, swapped-operand 32x32x16 MFMA.
// This round: 2-wave (128-thread) blocks, each wave owns 64 q-rows as
// 2 q-blocks of 32. Every K/V fragment read from LDS now feeds 2 MFMAs
// (was 1): per-CU LDS b128 reads/tile drop 384 -> 192 (the ~70%-busy LDS
// read pipe was the binding resource). Grid 1024, LDS 40 KB -> 4 blocks/CU
// = 8 waves/CU; __launch_bounds__(128,2) -> 256-VGPR budget, no spill.
// Pipeline (counted vmcnt, LDS-resident mask) carried over; vmcnt depth 8.
// ---------------------------------------------------------------------------
__global__ __launch_bounds__(128, 2) void flash_mfma_kernel(
    const half_t* __restrict__ Qh,   // (B,H,N,D)  (q pre-scaled by 0.125*log2e)
    const half_t* __restrict__ Kh,   // (B,H,N,D)
    const half_t* __restrict__ Vt,   // (B,H,D,N)
    const float*  __restrict__ ms,   // (B,N) pre-scaled: m*log2e - EXP2_OFF
    half_t* __restrict__ O)          // (B,N,C) fp16
{
  __shared__ half_t KV[2][2][64 * 64];   // [buf][K|V][row*64 + e]  32 KB
  __shared__ __align__(16) float Ms[2048];   // 8 KB: block's full mask row

  const int tid  = threadIdx.x;
  const int wave = tid >> 6;            // 0..1
  const int lane = tid & 63;
  const int l31  = lane & 31;
  const int hi   = lane >> 5;           // 0/1
  const int l7   = lane & 7;

  // XCD-aware decode: blocks with the same head share blockIdx%8 (same XCD)
  const int bid  = blockIdx.x;          // 0..1023
  const int xcd  = bid & 7;
  const int slot = bid >> 3;            // 0..127
  const int qt   = slot & 15;           // 16 q-tiles of 128 rows
  const int head = (slot >> 4) * 8 + xcd;   // 0..63
  const int b    = head >> 3;
  const int h    = head & 7;

  const half_t* Kt_base = Kh + ((((size_t)b * HH + h) * NN) << 6);
  const half_t* Vt_base = Vt + (((size_t)b * HH + h) * DD) * NN;

  // Q B-fragments, 2 q-blocks: q = qt*128 + wave*64 + qb*32 + l31
  half8 qf0[4], qf1[4];
  {
    const half_t* Qp0 =
        Qh + ((((size_t)b * HH + h) * NN + qt * 128 + wave * 64 + l31) << 6) + hi * 8;
#pragma unroll
    for (int kd = 0; kd < 4; ++kd) {
      qf0[kd] = *(const half8*)(Qp0 + kd * 16);
      qf1[kd] = *(const half8*)(Qp0 + 32 * 64 + kd * 16);
    }
  }

  // staging source pointers, pre-swizzled: LDS linear slot sl of row holds
  // source 16B-group (sl ^ (row&7)); row&7 == lane>>3 here.
  const int r8  = lane >> 3;                 // 0..7
  const int dof = ((l7 ^ r8) << 3);          // halfs
  const half_t* kbase = Kt_base + (((size_t)(wave * 32 + r8)) << 6) + dof;
  const half_t* vbase = Vt_base + (size_t)(wave * 32 + r8) * NN + dof;

  // LDS read addrs (bytes), buffer/t offsets added as immediates at use.
  int adK[4], adV[4];
#pragma unroll
  for (int c = 0; c < 4; ++c) {
    adK[c] = l31 * 128 + ((((c << 1) | hi) ^ l7) << 4);
    adV[c] = 8192 + l31 * 128 + ((((c << 1) | hi) ^ l7) << 4);
  }
  const char* L = (const char*)KV;

  floatx16 acc[2][2];
#pragma unroll
  for (int qb = 0; qb < 2; ++qb)
#pragma unroll
    for (int dt = 0; dt < 2; ++dt)
#pragma unroll
      for (int r = 0; r < 16; ++r) acc[qb][dt][r] = 0.f;
  float l4[2][4] = {{0.f, 0.f, 0.f, 0.f}, {0.f, 0.f, 0.f, 0.f}};

#define STAGE(c, koff, voff)                                                  \
  {                                                                           \
    gld16(kbase + (koff),           &KV[c][0][wave * 2048]);                  \
    gld16(kbase + (koff) + 512,     &KV[c][0][wave * 2048 + 512]);            \
    gld16(kbase + (koff) + 1024,    &KV[c][0][wave * 2048 + 1024]);           \
    gld16(kbase + (koff) + 1536,    &KV[c][0][wave * 2048 + 1536]);           \
    gld16(vbase + (voff),           &KV[c][1][wave * 2048]);                  \
    gld16(vbase + (voff) + 8 * NN,  &KV[c][1][wave * 2048 + 512]);            \
    gld16(vbase + (voff) + 16 * NN, &KV[c][1][wave * 2048 + 1024]);           \
    gld16(vbase + (voff) + 24 * NN, &KV[c][1][wave * 2048 + 1536]);           \
  }

// mask LDS byte offset per t-phase: mls(base,kt) + moffB(0/256) + t*128 + r2*32
#define COMPUTE(c, moffB)                                                     \
  _Pragma("unroll")                                                           \
  for (int t = 0; t < 2; ++t) {                                               \
    floatx16 S0, S1;                                                          \
    _Pragma("unroll")                                                         \
    for (int r2 = 0; r2 < 4; ++r2) {                                          \
      fx4 mv = *(const fx4*)((const char*)Ms + mls + (moffB) + t * 128 + r2 * 32); \
      S0[r2 * 4 + 0] = mv[0]; S0[r2 * 4 + 1] = mv[1];                         \
      S0[r2 * 4 + 2] = mv[2]; S0[r2 * 4 + 3] = mv[3];                         \
      S1[r2 * 4 + 0] = mv[0]; S1[r2 * 4 + 1] = mv[1];                         \
      S1[r2 * 4 + 2] = mv[2]; S1[r2 * 4 + 3] = mv[3];                         \
    }                                                                         \
    __builtin_amdgcn_s_setprio(1);                                            \
    _Pragma("unroll")                                                         \
    for (int kd = 0; kd < 4; ++kd) {                                          \
      half8 kf = *(const half8*)(L + (adK[kd] + (c) * 16384 + t * 4096));     \
      S0 = __builtin_amdgcn_mfma_f32_32x32x16_f16(kf, qf0[kd], S0, 0, 0, 0);  \
      S1 = __builtin_amdgcn_mfma_f32_32x32x16_f16(kf, qf1[kd], S1, 0, 0, 0);  \
    }                                                                         \
    __builtin_amdgcn_s_setprio(0);                                            \
    _Pragma("unroll")                                                         \
    for (int r = 0; r < 16; ++r) {                                            \
      float p0 = __builtin_amdgcn_exp2f(S0[r]);                               \
      l4[0][r & 3] += p0;  S0[r] = p0;                                        \
      float p1 = __builtin_amdgcn_exp2f(S1[r]);                               \
      l4[1][r & 3] += p1;  S1[r] = p1;                                        \
    }                                                                         \
    unsigned W0[4][2], W1[4][2];                                              \
    _Pragma("unroll")                                                         \
    for (int r2 = 0; r2 < 4; ++r2)                                            \
      _Pragma("unroll")                                                       \
      for (int u = 0; u < 2; ++u) {                                           \
        union { fp16x2 h; unsigned w; } pk;                                   \
        pk.h = __builtin_amdgcn_cvt_pkrtz(S0[r2 * 4 + 2 * u],                 \
                                          S0[r2 * 4 + 2 * u + 1]);            \
        W0[r2][u] = pk.w;                                                     \
        pk.h = __builtin_amdgcn_cvt_pkrtz(S1[r2 * 4 + 2 * u],                 \
                                          S1[r2 * 4 + 2 * u + 1]);            \
        W1[r2][u] = pk.w;                                                     \
      }                                                                       \
    _Pragma("unroll")                                                         \
    for (int ksl = 0; ksl < 2; ++ksl) {                                       \
      unsigned A0 = W0[2 * ksl][0],     A1 = W0[2 * ksl][1];                  \
      unsigned B0 = W0[2 * ksl + 1][0], B1 = W0[2 * ksl + 1][1];              \
      asm("v_permlane32_swap_b32 %0, %1" : "+v"(A0), "+v"(B0));               \
      asm("v_permlane32_swap_b32 %0, %1" : "+v"(A1), "+v"(B1));               \
      union { unsigned u4[4]; half8 v; } pw0;                                 \
      pw0.u4[0] = A0; pw0.u4[1] = A1; pw0.u4[2] = B0; pw0.u4[3] = B1;         \
      unsigned C0 = W1[2 * ksl][0],     C1 = W1[2 * ksl][1];                  \
      unsigned D0 = W1[2 * ksl + 1][0], D1 = W1[2 * ksl + 1][1];              \
      asm("v_permlane32_swap_b32 %0, %1" : "+v"(C0), "+v"(D0));               \
      asm("v_permlane32_swap_b32 %0, %1" : "+v"(C1), "+v"(D1));               \
      union { unsigned u4[4]; half8 v; } pw1;                                 \
      pw1.u4[0] = C0; pw1.u4[1] = C1; pw1.u4[2] = D0; pw1.u4[3] = D1;         \
      const int ks = t * 2 + ksl;                                             \
      __builtin_amdgcn_s_setprio(1);                                          \
      _Pragma("unroll")                                                       \
      for (int dt = 0; dt < 2; ++dt) {                                        \
        half8 vf = *(const half8*)(L + (adV[ks] + (c) * 16384 + dt * 4096));  \
        acc[0][dt] = __builtin_amdgcn_mfma_f32_32x32x16_f16(pw0.v, vf, acc[0][dt], 0, 0, 0); \
        acc[1][dt] = __builtin_amdgcn_mfma_f32_32x32x16_f16(pw1.v, vf, acc[1][dt], 0, 0, 0); \
      }                                                                       \
      __builtin_amdgcn_s_setprio(0);                                          \
    }                                                                         \
  }

  // prologue: stage K/V tiles 0,1 AND the full mask row; wait; barrier.
  STAGE(0, 0, 0)
  {
    // mask: 2048 floats = 8 KB; wave stages its 4096-B chunk with 4 gld16
    const half_t* msrc = (const half_t*)(ms + (size_t)b * NN) + wave * 2048 + lane * 8;
    gld16(msrc,        (half_t*)Ms + wave * 2048);
    gld16(msrc + 512,  (half_t*)Ms + wave * 2048 + 512);
    gld16(msrc + 1024, (half_t*)Ms + wave * 2048 + 1024);
    gld16(msrc + 1536, (half_t*)Ms + wave * 2048 + 1536);
  }
  STAGE(1, 4096, 64)
  asm volatile("s_waitcnt vmcnt(8)");   // STAGE(0)+mask retired; STAGE(1) in flight
  __builtin_amdgcn_s_barrier();
  __builtin_amdgcn_sched_barrier(0);
  kbase += 8192; vbase += 128;   // now pointing at tile 2

  int mls = hi * 16;   // mask LDS byte base (walks 512 B per kt2 iter)
#pragma unroll 1
  for (int kt2 = 0; kt2 < 15; ++kt2) {   // tiles 0..29; stages tiles 2..31
    COMPUTE(0, 0)
    __builtin_amdgcn_sched_barrier(0);
    __builtin_amdgcn_s_barrier();        // all waves done reading buf 0
    STAGE(0, 0, 0)                       // tile 2*kt2+2 -> buf 0
    asm volatile("s_waitcnt vmcnt(8)");  // stage(2*kt2+1) landed; fresh 8 in flight
    __builtin_amdgcn_s_barrier();
    __builtin_amdgcn_sched_barrier(0);

    COMPUTE(1, 256)
    __builtin_amdgcn_sched_barrier(0);
    __builtin_amdgcn_s_barrier();        // all waves done reading buf 1
    STAGE(1, 4096, 64)                   // tile 2*kt2+3 -> buf 1
    asm volatile("s_waitcnt vmcnt(8)");  // stage(2*kt2+2) landed
    __builtin_amdgcn_s_barrier();
    __builtin_amdgcn_sched_barrier(0);

    kbase += 8192; vbase += 128;
    mls += 512;
  }

  // tail: tiles 30 (buf 0) and 31 (buf 1); no more staging
  COMPUTE(0, 0)
  asm volatile("s_waitcnt vmcnt(0)");    // stage(31) fully landed
  __builtin_amdgcn_s_barrier();
  __builtin_amdgcn_sched_barrier(0);
  COMPUTE(1, 256)

#undef STAGE
#undef COMPUTE

  // epilogue per q-block: l reduce + normalized O store
#pragma unroll
  for (int qb = 0; qb < 2; ++qb) {
    float l_part = (l4[qb][0] + l4[qb][1]) + (l4[qb][2] + l4[qb][3]);
    l_part += __shfl_xor(l_part, 32, 64);
    const size_t orow = (size_t)b * NN + qt * 128 + wave * 64 + qb * 32;
#pragma unroll
    for (int r = 0; r < 16; ++r) {
      const int ql  = (r & 3) + 8 * (r >> 2) + 4 * hi;   // 0..31
      const float iv = 1.0f / __shfl(l_part, ql, 64);
      const size_t ro = ((orow + ql) << 9) + (h << 6) + l31;
      O[ro]      = (half_t)(acc[qb][0][r] * iv);
      O[ro + 32] = (half_t)(acc[qb][1][r] * iv);
    }
  }
}

// ---------------------------------------------------------------------------
// Kernel 3: out = O @ W_proj^T + b_proj  (fp16 MFMA, fp32 out)
// 128x64 tile, counted-vmcnt double-buffered staging.  [unchanged]
// ---------------------------------------------------------------------------
__global__ __launch_bounds__(256) void proj_mfma_kernel(
    const half_t* __restrict__ Ah,   // (16384, 512) fp16
    const half_t* __restrict__ Bh,   // (512, 512) fp16
    const float* __restrict__ bias,  // (512,)
    float* __restrict__ out)         // (16384, 512)
{
  __shared__ half_t As[2][128 * 32];   // 16 KB
  __shared__ half_t Bs[2][64 * 32];    // 8 KB

  const int tid  = threadIdx.x;
  const int wave = tid >> 6, lane = tid & 63;
  const int L15  = lane & 15, quad = lane >> 4;
  const int wm = (wave & 1) * 64, wn = (wave >> 1) * 32;
  const int m0 = blockIdx.x * 128;
  const int f0 = blockIdx.y * 64;

  const int srow = lane >> 2;
  const int scolh = (lane & 3) * 8;
  const half_t* Ag = Ah + (size_t)(m0 + wave * 16 + srow) * CC + scolh;
  const half_t* Bg = Bh + (size_t)(f0 + wave * 16 + srow) * CC + scolh;

  floatx4 acc[4][2];
#pragma unroll
  for (int i = 0; i < 4; ++i)
#pragma unroll
    for (int j = 0; j < 2; ++j) acc[i][j] = (floatx4){0.f, 0.f, 0.f, 0.f};

#define PSTAGE(c, koff)                                                       \
  {                                                                           \
    gld16(Ag + (koff),           &As[c][(wave * 16) * 32]);                   \
    gld16(Ag + (koff) + 64 * CC, &As[c][(64 + wave * 16) * 32]);              \
    gld16(Bg + (koff),           &Bs[c][(wave * 16) * 32]);                   \
  }

#define PCOMPUTE(c)                                                           \
  {                                                                           \
    half8 af[4], bf[2];                                                       \
    _Pragma("unroll")                                                         \
    for (int mi = 0; mi < 4; ++mi)                                            \
      af[mi] = *(const half8*)&As[c][(wm + mi * 16 + L15) * 32 + quad * 8];   \
    _Pragma("unroll")                                                         \
    for (int ni = 0; ni < 2; ++ni)                                            \
      bf[ni] = *(const half8*)&Bs[c][(wn + ni * 16 + L15) * 32 + quad * 8];   \
    __builtin_amdgcn_s_setprio(1);                                            \
    _Pragma("unroll")                                                         \
    for (int mi = 0; mi < 4; ++mi)                                            \
      _Pragma("unroll")                                                       \
      for (int ni = 0; ni < 2; ++ni)                                          \
        acc[mi][ni] = __builtin_amdgcn_mfma_f32_16x16x32_f16(af[mi], bf[ni], acc[mi][ni], 0, 0, 0); \
    __builtin_amdgcn_s_setprio(0);                                            \
  }

  PSTAGE(0, 0)
  PSTAGE(1, 32)
  asm volatile("s_waitcnt vmcnt(3)");
  __builtin_amdgcn_s_barrier();
  __builtin_amdgcn_sched_barrier(0);

  int k0 = 64;
#pragma unroll 1
  for (int kk = 0; kk < 7; ++kk) {   // computes steps 0..13; stages steps 2..15
    PCOMPUTE(0)
    __builtin_amdgcn_sched_barrier(0);
    __builtin_amdgcn_s_barrier();
    PSTAGE(0, k0)
    asm volatile("s_waitcnt vmcnt(3)");
    __builtin_amdgcn_s_barrier();
    __builtin_amdgcn_sched_barrier(0);

    PCOMPUTE(1)
    __builtin_amdgcn_sched_barrier(0);
    __builtin_amdgcn_s_barrier();
    PSTAGE(1, k0 + 32)
    asm volatile("s_waitcnt vmcnt(3)");
    __builtin_amdgcn_s_barrier();
    __builtin_amdgcn_sched_barrier(0);
    k0 += 64;
  }
  PCOMPUTE(0)
  asm volatile("s_waitcnt vmcnt(0)");
  __builtin_amdgcn_s_barrier();
  __builtin_amdgcn_sched_barrier(0);
  PCOMPUTE(1)

#undef PSTAGE
#undef PCOMPUTE

#pragma unroll
  for (int ni = 0; ni < 2; ++ni) {
    const int f = f0 + wn + ni * 16 + L15;
    const float bv = bias[f];
#pragma unroll
    for (int mi = 0; mi < 4; ++mi)
#pragma unroll
      for (int r = 0; r < 4; ++r)
        out[(size_t)(m0 + wm + mi * 16 + quad * 4 + r) * CC + f] = acc[mi][ni][r] + bv;
  }
}

// ---------------------------------------------------------------------------
extern "C" void kernel_launch(void* const* d_in, const int* in_sizes, int n_in,
                              void* d_out, int out_size, void* d_ws, size_t ws_size,
                              hipStream_t stream) {
  const float* x     = (const float*)d_in[0];
  const float* mask  = (const float*)d_in[1];
  const float* Wqkv  = (const float*)d_in[2];
  const float* Wproj = (const float*)d_in[3];
  const float* bproj = (const float*)d_in[4];
  const int*   ncp   = (const int*)d_in[5];
  float* out = (float*)d_out;

  const size_t per = (size_t)BB * HH * NN * DD;   // 8,388,608
  half_t* xh  = (half_t*)d_ws;
  half_t* Wqh = xh + (size_t)MM * CC;
  half_t* Wph = Wqh + (size_t)FF * CC;
  half_t* Qh  = Wph + (size_t)CC * CC;
  half_t* Kh  = Qh + per;
  half_t* Vt  = Kh + per;
  half_t* Oh  = Vt + per;
  float2* tab = (float2*)(Oh + per);              // 2048*32*8B = 512 KB
  float*  msb = (float*)(tab + (size_t)NN * 32);  // 16384*4B = 64 KB

  prep_kernel<<<dim3(NPREP / 256), 256, 0, stream>>>(x, Wqkv, Wproj, mask, xh, tab, msb);

  qkv_mfma_kernel<<<dim3(MM / 128, FF / 128), 256, 0, stream>>>(xh, Wqh, ncp, tab, Qh, Kh, Vt);
  flash_mfma_kernel<<<dim3(BB * HH * (NN / 128)), 128, 0, stream>>>(Qh, Kh, Vt, msb, Oh);
  proj_mfma_kernel<<<dim3(MM / 128, CC / 64), 256, 0, stream>>>(Oh, Wph, bproj, out);
}